// Round 5
// baseline (495.225 us; speedup 1.0000x reference)
//
#include <hip/hip_runtime.h>
#include <hip/hip_bf16.h>
#include <math.h>

#define B_G   128
#define N0    512
#define DEG   8
#define CCH   128
#define EPG   (N0*DEG)            // 4096 edges per graph (fixed slab)
#define E_TOTAL (B_G*EPG)
#define K1    410
#define K2    328
#define K3    263
#define NCLS  10

using bf16x8 = __attribute__((ext_vector_type(8))) __bf16;
using f32x4  = __attribute__((ext_vector_type(4))) float;
typedef unsigned short ushort;
typedef unsigned int uint;

__device__ __forceinline__ ushort f2b(float f) {
    uint u = __float_as_uint(f);
    u += 0x7fffu + ((u >> 16) & 1u);      // RNE
    return (ushort)(u >> 16);
}
__device__ __forceinline__ float b2f(ushort h) {
    return __uint_as_float(((uint)h) << 16);
}
// split fp32 -> (hi, lo) bf16 pair;  v ~= hi + lo  (error ~2^-17 rel)
__device__ __forceinline__ void split2(float v, ushort& hi, ushort& lo) {
    hi = f2b(v);
    lo = f2b(v - b2f(hi));
}

// ---------------- convert x0 fp32 -> hi/lo bf16 pair arrays ----------------
__global__ void convert_x(const float* __restrict__ x0, ushort* __restrict__ xh,
                          ushort* __restrict__ xl, int n4) {
    int i = blockIdx.x * 256 + threadIdx.x;   // one float4 per thread
    if (i >= n4) return;
    float4 v = ((const float4*)x0)[i];
    ushort h0, l0, h1, l1, h2, l2, h3, l3;
    split2(v.x, h0, l0); split2(v.y, h1, l1);
    split2(v.z, h2, l2); split2(v.w, h3, l3);
    ((uint2*)xh)[i] = make_uint2((uint)h0 | ((uint)h1 << 16), (uint)h2 | ((uint)h3 << 16));
    ((uint2*)xl)[i] = make_uint2((uint)l0 | ((uint)l1 << 16), (uint)l2 | ((uint)l3 << 16));
}

// ---------------- pack weights into per-lane MFMA fragment layout (hi/lo) ----------------
// Bp[layer][ks][cf][lane][j] ; k = ks*32 + (lane>>4)*8 + j ; c = cf*16 + (lane&15)
__global__ void pack_weights(const float* __restrict__ Wrel0, const float* __restrict__ Wroot0,
                             const float* __restrict__ Wrel1, const float* __restrict__ Wroot1,
                             const float* __restrict__ Wrel2, const float* __restrict__ Wroot2,
                             ushort* __restrict__ Bph, ushort* __restrict__ Bpl) {
    int idx = blockIdx.x * 256 + threadIdx.x;
    if (idx >= 3 * 32768) return;
    int layer = idx >> 15, rem = idx & 32767;
    int j = rem & 7, lane = (rem >> 3) & 63, cf = (rem >> 9) & 7, ks = rem >> 12;
    int k = ks * 32 + (lane >> 4) * 8 + j;
    int c = cf * 16 + (lane & 15);
    const float* Wrel  = layer == 0 ? Wrel0  : layer == 1 ? Wrel1  : Wrel2;
    const float* Wroot = layer == 0 ? Wroot0 : layer == 1 ? Wroot1 : Wroot2;
    float v = (k < 128) ? Wrel[k * 128 + c] : Wroot[(k - 128) * 128 + c];
    ushort hi, lo; split2(v, hi, lo);
    Bph[idx] = hi; Bpl[idx] = lo;
}

// ---------------- init: mapT identity, inv0 = -1, g = 0 ----------------
__global__ void init_all(int* __restrict__ mapT, int* __restrict__ inv0, float* __restrict__ g) {
    int i = blockIdx.x * 256 + threadIdx.x;
    if (i < B_G * N0) { mapT[i] = i; inv0[i] = -1; }
    if (i < B_G * 256) g[i] = 0.f;
}

// ---------------- per-graph CSR build (count+scan+fill, all in LDS, mapT-remapped) ----------------
__global__ __launch_bounds__(512) void csr_build(
        const int* __restrict__ es, const int* __restrict__ ed, const int* __restrict__ mapT,
        int* __restrict__ indptr, int* __restrict__ counts, ushort* __restrict__ srclist,
        int n_cur) {
    int b = blockIdx.x, tid = threadIdx.x;
    __shared__ int mloc[512];
    __shared__ int cnt[512];
    __shared__ int pref[512];
    __shared__ int curs[512];
    __shared__ uint epk[EPG];     // 16 KB packed edges
    mloc[tid] = mapT[b * N0 + tid];
    cnt[tid] = 0;
    __syncthreads();
    int base = b * EPG;
    int nb = b * n_cur;
    for (int i = tid; i < EPG; i += 512) {
        int s = es[base + i] & (N0 - 1);
        int d = ed[base + i] & (N0 - 1);
        int sg = mloc[s], dg = mloc[d];
        uint wv = 0xFFFFFFFFu;
        if ((sg | dg) >= 0) {
            int sl = sg - nb, dl = dg - nb;
            wv = (uint)sl | ((uint)dl << 16);
            atomicAdd(&cnt[dl], 1);
        }
        epk[i] = wv;
    }
    __syncthreads();
    pref[tid] = cnt[tid];
    __syncthreads();
    for (int off = 1; off < 512; off <<= 1) {
        int v = (tid >= off) ? pref[tid - off] : 0;
        __syncthreads();
        pref[tid] += v;
        __syncthreads();
    }
    int excl = tid ? pref[tid - 1] : 0;
    if (tid < n_cur) {
        indptr[nb + tid] = base + excl;
        counts[nb + tid] = cnt[tid];
    }
    curs[tid] = excl;
    __syncthreads();
    for (int i = tid; i < EPG; i += 512) {
        uint wv = epk[i];
        if (wv != 0xFFFFFFFFu) {
            int dl = wv >> 16;
            int pos = atomicAdd(&curs[dl], 1);
            srclist[base + pos] = (ushort)(wv & 0xFFFFu);
        }
    }
}

// ---------------- aggregation: per-(graph, channel-half) LDS-staged ----------------
// block = 512 thr (8 waves). LDS slab[node][64 words]: w<32 hi-packed ch pair, w>=32 lo-packed.
__global__ __launch_bounds__(512) void aggregate(
        const ushort* __restrict__ xh, const ushort* __restrict__ xl,
        const int* __restrict__ indptr, const int* __restrict__ counts,
        const ushort* __restrict__ srclist,
        ushort* __restrict__ agg_h, ushort* __restrict__ agg_l, int n) {
    extern __shared__ uint slab[];       // 512*64 uints = 128 KB
    int b = blockIdx.x >> 1, hf = blockIdx.x & 1;
    int tid = threadIdx.x;
    const uint* xh32 = (const uint*)xh;  // row = 64 uints (128 ch packed)
    const uint* xl32 = (const uint*)xl;
    int w = tid & 63;
    for (int nd = tid >> 6; nd < n; nd += 8) {
        size_t row = (size_t)(b * n + nd) * 64;
        uint u = (w < 32) ? xh32[row + hf * 32 + w] : xl32[row + hf * 32 + (w - 32)];
        slab[nd * 64 + w] = u;
    }
    __syncthreads();
    int wave = tid >> 6, lane = tid & 63;
    for (int d = wave; d < n; d += 8) {
        int beg = indptr[b * n + d];
        int cnt = counts[b * n + d];
        float f0 = 0.f, f1 = 0.f;
        for (int j = 0; j < cnt; j++) {
            int s = srclist[beg + j];
            uint u = slab[s * 64 + lane];
            f0 += __uint_as_float(u << 16);
            f1 += __uint_as_float(u & 0xffff0000u);
        }
        float g0 = f0 + __shfl_xor(f0, 32);   // hi part + lo part of same channel pair
        float g1 = f1 + __shfl_xor(f1, 32);
        ushort h0, l0, h1, l1;
        split2(g0, h0, l0); split2(g1, h1, l1);
        size_t orow = (size_t)(b * n + d) * 64;
        if (lane < 32)
            ((uint*)agg_h)[orow + hf * 32 + lane] = (uint)h0 | ((uint)h1 << 16);
        else
            ((uint*)agg_l)[orow + hf * 32 + (lane - 32)] = (uint)l0 | ((uint)l1 << 16);
    }
}

// ---------------- bf16x3 MFMA transform + fused score ----------------
//   h = relu([agg|x] @ [Wrel;Wroot] + brel) ; score = tanh(h.p/||p||)
// block = 256 thr (4 waves); each wave owns 32 rows (2 frags) x 128 cols. No LDS.
// A*B ~= Ah*Bh + Ah*Bl + Al*Bh  (fp32 accumulate)
__global__ __launch_bounds__(256) void transform_mfma(
        const ushort* __restrict__ agg_hi, const ushort* __restrict__ agg_lo,
        const ushort* __restrict__ x_hi, const ushort* __restrict__ x_lo,
        const ushort* __restrict__ Bph, const ushort* __restrict__ Bpl,
        const float* __restrict__ brel, const float* __restrict__ pvec,
        ushort* __restrict__ h_hi, ushort* __restrict__ h_lo, float* __restrict__ score) {
    int tid = threadIdx.x;
    int wave = tid >> 6, lane = tid & 63;
    int r = lane & 15, kb = lane >> 4;
    int rows0 = blockIdx.x * 128 + wave * 32;

    f32x4 acc[2][8];
#pragma unroll
    for (int rf = 0; rf < 2; rf++)
#pragma unroll
        for (int cf = 0; cf < 8; cf++) acc[rf][cf] = (f32x4)(0.f);

    const bf16x8* Bh = (const bf16x8*)Bph;
    const bf16x8* Bl = (const bf16x8*)Bpl;

#pragma unroll
    for (int ks = 0; ks < 8; ks++) {
        const ushort* Ah = (ks < 4) ? agg_hi : x_hi;
        const ushort* Al = (ks < 4) ? agg_lo : x_lo;
        int kofs = (ks & 3) * 32 + kb * 8;
        bf16x8 a_hi[2], a_lo[2];
#pragma unroll
        for (int rf = 0; rf < 2; rf++) {
            size_t rowbase = (size_t)(rows0 + rf * 16 + r) * CCH + kofs;
            a_hi[rf] = *(const bf16x8*)&Ah[rowbase];
            a_lo[rf] = *(const bf16x8*)&Al[rowbase];
        }
#pragma unroll
        for (int cf = 0; cf < 8; cf++) {
            bf16x8 bh = Bh[(ks * 8 + cf) * 64 + lane];
            bf16x8 bl = Bl[(ks * 8 + cf) * 64 + lane];
#pragma unroll
            for (int rf = 0; rf < 2; rf++) {
                acc[rf][cf] = __builtin_amdgcn_mfma_f32_16x16x32_bf16(a_hi[rf], bl, acc[rf][cf], 0, 0, 0);
                acc[rf][cf] = __builtin_amdgcn_mfma_f32_16x16x32_bf16(a_lo[rf], bh, acc[rf][cf], 0, 0, 0);
                acc[rf][cf] = __builtin_amdgcn_mfma_f32_16x16x32_bf16(a_hi[rf], bh, acc[rf][cf], 0, 0, 0);
            }
        }
    }

    // epilogue: bias+relu (fp32), hi/lo store, fused score
    float pv[8], bb[8], q = 0.f;
#pragma unroll
    for (int cf = 0; cf < 8; cf++) {
        pv[cf] = pvec[cf * 16 + r];
        bb[cf] = brel[cf * 16 + r];
        q += pv[cf] * pv[cf];
    }
    float dots[2][4] = {{0.f,0.f,0.f,0.f},{0.f,0.f,0.f,0.f}};
#pragma unroll
    for (int rf = 0; rf < 2; rf++) {
#pragma unroll
        for (int cf = 0; cf < 8; cf++) {
#pragma unroll
            for (int reg = 0; reg < 4; reg++) {
                float v = acc[rf][cf][reg] + bb[cf];
                v = v > 0.f ? v : 0.f;
                int row = rows0 + rf * 16 + kb * 4 + reg;
                ushort hi, lo; split2(v, hi, lo);
                h_hi[(size_t)row * CCH + cf * 16 + r] = hi;
                h_lo[(size_t)row * CCH + cf * 16 + r] = lo;
                dots[rf][reg] += v * pv[cf];
            }
        }
    }
#pragma unroll
    for (int off = 1; off < 16; off <<= 1) {
        q += __shfl_xor(q, off);
#pragma unroll
        for (int rf = 0; rf < 2; rf++)
#pragma unroll
            for (int reg = 0; reg < 4; reg++)
                dots[rf][reg] += __shfl_xor(dots[rf][reg], off);
    }
    if (r == 0) {
        float inv_norm = rsqrtf(q);
#pragma unroll
        for (int rf = 0; rf < 2; rf++)
#pragma unroll
            for (int reg = 0; reg < 4; reg++)
                score[rows0 + rf * 16 + kb * 4 + reg] = tanhf(dots[rf][reg] * inv_norm);
    }
}

// ---------------- top-k per graph: bitonic sort of 512 packed keys ----------------
__global__ __launch_bounds__(256) void topk_kernel(const float* __restrict__ score,
                                                   int* __restrict__ inv,
                                                   int* __restrict__ kglob,
                                                   float* __restrict__ kval, int n, int k) {
    int b = blockIdx.x;
    __shared__ unsigned long long keys[512];
    int tid = threadIdx.x;
    for (int s = tid; s < 512; s += 256) {
        unsigned long long key = 0ull;   // sorts below all real scores
        if (s < n) {
            float v = score[b * n + s];
            unsigned u = __float_as_uint(v);
            u = (u & 0x80000000u) ? ~u : (u | 0x80000000u);   // orderable
            key = ((unsigned long long)u << 32) | (unsigned)(~s); // ties -> lower idx first
        }
        keys[s] = key;
    }
    __syncthreads();
    for (int kk2 = 2; kk2 <= 512; kk2 <<= 1) {
        for (int j = kk2 >> 1; j > 0; j >>= 1) {
            for (int s = tid; s < 512; s += 256) {
                int sxj = s ^ j;
                if (sxj > s) {
                    unsigned long long a = keys[s], c = keys[sxj];
                    bool descRegion = ((s & kk2) == 0);
                    bool doSwap = descRegion ? (a < c) : (a > c);
                    if (doSwap) { keys[s] = c; keys[sxj] = a; }
                }
            }
            __syncthreads();
        }
    }
    for (int j = tid; j < k; j += 256) {
        unsigned long long key = keys[j];
        int node = (int)(~(unsigned)key);
        float v = score[b * n + node];
        int newid = b * k + j;
        kglob[newid] = b * n + node;
        kval[newid] = v;
        inv[b * n + node] = newid;
    }
}

// ---------------- gather+scale kept rows (hi/lo -> hi/lo) ----------------
__global__ void gather_kernel(const ushort* __restrict__ hh, const ushort* __restrict__ hl,
                              const int* __restrict__ kglob, const float* __restrict__ kval,
                              ushort* __restrict__ xh, ushort* __restrict__ xl, int nk) {
    int wid = (blockIdx.x * 256 + threadIdx.x) >> 6;
    int lane = threadIdx.x & 63;
    if (wid >= nk) return;
    int gsrc = kglob[wid];
    float v = kval[wid];
    uint h = ((const uint*)(hh + (size_t)gsrc * CCH))[lane];
    uint l = ((const uint*)(hl + (size_t)gsrc * CCH))[lane];
    float c0 = (__uint_as_float(h << 16) + __uint_as_float(l << 16)) * v;
    float c1 = (__uint_as_float(h & 0xffff0000u) + __uint_as_float(l & 0xffff0000u)) * v;
    ushort h0, l0, h1, l1;
    split2(c0, h0, l0); split2(c1, h1, l1);
    ((uint*)(xh + (size_t)wid * CCH))[lane] = (uint)h0 | ((uint)h1 << 16);
    ((uint*)(xl + (size_t)wid * CCH))[lane] = (uint)l0 | ((uint)l1 << 16);
}

// ---------------- compose mapT through this layer's inv; reset other inv buffer ----------------
__global__ void compose_map(int* __restrict__ mapT, const int* __restrict__ invA,
                            int* __restrict__ invB, int bk) {
    int i = blockIdx.x * 256 + threadIdx.x;
    if (i < B_G * N0) {
        int m = mapT[i];
        mapT[i] = (m >= 0) ? invA[m] : -1;
    }
    if (i < bk) invB[i] = -1;
}

// ---------------- readout: gmp || gap (hi/lo input), accumulated into g ----------------
__global__ __launch_bounds__(512) void readout_kernel(const ushort* __restrict__ xh,
                                                      const ushort* __restrict__ xl,
                                                      float* __restrict__ g, int k) {
    int b = blockIdx.x;
    int c = threadIdx.x & 127;
    int q = threadIdx.x >> 7;
    float mx = -1e30f, sm = 0.f;
    for (int j = q; j < k; j += 4) {
        size_t idx = ((size_t)b * k + j) * CCH + c;
        float v = b2f(xh[idx]) + b2f(xl[idx]);
        mx = fmaxf(mx, v); sm += v;
    }
    __shared__ float smx[4][128], ssm[4][128];
    smx[q][c] = mx; ssm[q][c] = sm;
    __syncthreads();
    if (q == 0) {
        mx = fmaxf(fmaxf(smx[0][c], smx[1][c]), fmaxf(smx[2][c], smx[3][c]));
        sm = ssm[0][c] + ssm[1][c] + ssm[2][c] + ssm[3][c];
        g[b * 256 + c] += mx;
        g[b * 256 + 128 + c] += sm / (float)k;
    }
}

// ---------------- final MLP + log_softmax ----------------
__global__ __launch_bounds__(128) void mlp_kernel(const float* __restrict__ g,
        const float* __restrict__ W1, const float* __restrict__ b1,
        const float* __restrict__ W2, const float* __restrict__ b2,
        const float* __restrict__ W3, const float* __restrict__ b3,
        float* __restrict__ out) {
    int b = blockIdx.x, t = threadIdx.x;
    __shared__ float gs[256], h1[128], h2[64], lg[10];
    gs[t] = g[b * 256 + t];
    gs[128 + t] = g[b * 256 + 128 + t];
    __syncthreads();
    {
        float a = b1[t];
        for (int c = 0; c < 256; c++) a += gs[c] * W1[c * 128 + t];
        h1[t] = fmaxf(a, 0.f);
    }
    __syncthreads();
    if (t < 64) {
        float a = b2[t];
        for (int c = 0; c < 128; c++) a += h1[c] * W2[c * 64 + t];
        h2[t] = fmaxf(a, 0.f);
    }
    __syncthreads();
    if (t < 10) {
        float a = b3[t];
        for (int c = 0; c < 64; c++) a += h2[c] * W3[c * 10 + t];
        lg[t] = a;
    }
    __syncthreads();
    if (t < 10) {
        float m = lg[0];
        for (int i = 1; i < 10; i++) m = fmaxf(m, lg[i]);
        float s = 0.f;
        for (int i = 0; i < 10; i++) s += expf(lg[i] - m);
        out[b * 10 + t] = lg[t] - m - logf(s);
    }
}

// ---------------- host ----------------
extern "C" void kernel_launch(void* const* d_in, const int* in_sizes, int n_in,
                              void* d_out, int out_size, void* d_ws, size_t ws_size,
                              hipStream_t stream) {
    (void)in_sizes; (void)n_in; (void)out_size; (void)ws_size;
    const float* x0 = (const float*)d_in[0];
    const int* es = (const int*)d_in[1];
    const int* ed = (const int*)d_in[2];
    const float* Wroot[3] = {(const float*)d_in[3], (const float*)d_in[7], (const float*)d_in[11]};
    const float* Wrel[3]  = {(const float*)d_in[4], (const float*)d_in[8], (const float*)d_in[12]};
    const float* brel[3]  = {(const float*)d_in[5], (const float*)d_in[9], (const float*)d_in[13]};
    const float* pvec[3]  = {(const float*)d_in[6], (const float*)d_in[10], (const float*)d_in[14]};
    const float* W1 = (const float*)d_in[15];
    const float* b1 = (const float*)d_in[16];
    const float* W2 = (const float*)d_in[17];
    const float* b2 = (const float*)d_in[18];
    const float* W3 = (const float*)d_in[19];
    const float* b3 = (const float*)d_in[20];

    size_t off = 0;
    char* base = (char*)d_ws;
    auto alloc = [&](size_t bytes) -> void* {
        void* p = base + off;
        off += (bytes + 255) & ~(size_t)255;
        return p;
    };
    const size_t FEAT = (size_t)(B_G * N0) * CCH * 2;   // bf16 plane
    ushort* xb_hi  = (ushort*)alloc(FEAT);   // layer-input features hi
    ushort* xb_lo  = (ushort*)alloc(FEAT);   // layer-input features lo
    ushort* agg_hi = (ushort*)alloc(FEAT);   // aggregation hi (reused as h hi)
    ushort* agg_lo = (ushort*)alloc(FEAT);   // aggregation lo (reused as h lo)
    ushort* Bph = (ushort*)alloc((size_t)3 * 32768 * 2); // packed weights hi
    ushort* Bpl = (ushort*)alloc((size_t)3 * 32768 * 2); // packed weights lo
    int* mapT   = (int*)alloc((size_t)(B_G * N0) * 4);   // orig node -> current id / -1
    int* counts = (int*)alloc((size_t)(B_G * N0) * 4);
    int* indptr = (int*)alloc((size_t)(B_G * N0) * 4);
    ushort* srclist = (ushort*)alloc((size_t)E_TOTAL * 2);
    float* score = (float*)alloc((size_t)(B_G * N0) * 4);
    int* invbuf[2] = {(int*)alloc((size_t)(B_G * N0) * 4), (int*)alloc((size_t)(B_G * N0) * 4)};
    int* kglob = (int*)alloc((size_t)(B_G * K1) * 4);
    float* kval = (float*)alloc((size_t)(B_G * K1) * 4);
    float* g = (float*)alloc((size_t)B_G * 256 * 4);

    convert_x<<<(B_G * N0 * CCH / 4 + 255) / 256, 256, 0, stream>>>(x0, xb_hi, xb_lo,
                                                                    B_G * N0 * CCH / 4);
    pack_weights<<<(3 * 32768 + 255) / 256, 256, 0, stream>>>(
        Wrel[0], Wroot[0], Wrel[1], Wroot[1], Wrel[2], Wroot[2], Bph, Bpl);
    init_all<<<(B_G * N0 + 255) / 256, 256, 0, stream>>>(mapT, invbuf[0], g);

    int nper[4] = {N0, K1, K2, K3};
    for (int l = 0; l < 3; l++) {
        int n = nper[l], k = nper[l + 1];
        int n_nodes = B_G * n;
        int nk = B_G * k;
        int* invA = invbuf[l & 1];
        int* invB = invbuf[(l + 1) & 1];
        csr_build<<<B_G, 512, 0, stream>>>(es, ed, mapT, indptr, counts, srclist, n);
        aggregate<<<2 * B_G, 512, 131072, stream>>>(xb_hi, xb_lo, indptr, counts, srclist,
                                                    agg_hi, agg_lo, n);
        // h overwrites agg in place (each wave reads its 32 rows fully before writing them)
        transform_mfma<<<n_nodes / 128, 256, 0, stream>>>(
            agg_hi, agg_lo, xb_hi, xb_lo,
            Bph + (size_t)l * 32768, Bpl + (size_t)l * 32768,
            brel[l], pvec[l], agg_hi, agg_lo, score);
        topk_kernel<<<B_G, 256, 0, stream>>>(score, invA, kglob, kval, n, k);
        gather_kernel<<<(nk + 3) / 4, 256, 0, stream>>>(agg_hi, agg_lo, kglob, kval,
                                                        xb_hi, xb_lo, nk);
        readout_kernel<<<B_G, 512, 0, stream>>>(xb_hi, xb_lo, g, k);
        if (l < 2)
            compose_map<<<(B_G * N0 + 255) / 256, 256, 0, stream>>>(mapT, invA, invB, B_G * k);
    }
    mlp_kernel<<<B_G, 128, 0, stream>>>(g, W1, b1, W2, b2, W3, b3, (float*)d_out);
}

// Round 6
// 424.247 us; speedup vs baseline: 1.1673x; 1.1673x over previous
//
#include <hip/hip_runtime.h>
#include <hip/hip_bf16.h>
#include <math.h>

#define B_G   128
#define N0    512
#define DEG   8
#define CCH   128
#define EPG   (N0*DEG)            // 4096 edges per graph (fixed slab)
#define E_TOTAL (B_G*EPG)
#define K1    410
#define K2    328
#define K3    263
#define NCLS  10

using bf16x8 = __attribute__((ext_vector_type(8))) __bf16;
using f32x4  = __attribute__((ext_vector_type(4))) float;
typedef unsigned short ushort;
typedef unsigned int uint;

__device__ __forceinline__ ushort f2b(float f) {
    uint u = __float_as_uint(f);
    u += 0x7fffu + ((u >> 16) & 1u);      // RNE
    return (ushort)(u >> 16);
}
__device__ __forceinline__ float b2f(ushort h) {
    return __uint_as_float(((uint)h) << 16);
}
// split fp32 -> (hi, lo) bf16 pair;  v ~= hi + lo  (error ~2^-17 rel)
__device__ __forceinline__ void split2(float v, ushort& hi, ushort& lo) {
    hi = f2b(v);
    lo = f2b(v - b2f(hi));
}

// ---------------- convert x0 fp32 -> hi/lo bf16 pair arrays ----------------
__global__ void convert_x(const float* __restrict__ x0, ushort* __restrict__ xh,
                          ushort* __restrict__ xl, int n4) {
    int i = blockIdx.x * 256 + threadIdx.x;   // one float4 per thread
    if (i >= n4) return;
    float4 v = ((const float4*)x0)[i];
    ushort h0, l0, h1, l1, h2, l2, h3, l3;
    split2(v.x, h0, l0); split2(v.y, h1, l1);
    split2(v.z, h2, l2); split2(v.w, h3, l3);
    ((uint2*)xh)[i] = make_uint2((uint)h0 | ((uint)h1 << 16), (uint)h2 | ((uint)h3 << 16));
    ((uint2*)xl)[i] = make_uint2((uint)l0 | ((uint)l1 << 16), (uint)l2 | ((uint)l3 << 16));
}

// ---------------- pack weights into per-lane MFMA fragment layout (hi/lo) ----------------
// Bp[layer][ks][cf][lane][j] ; k = ks*32 + (lane>>4)*8 + j ; c = cf*16 + (lane&15)
__global__ void pack_weights(const float* __restrict__ Wrel0, const float* __restrict__ Wroot0,
                             const float* __restrict__ Wrel1, const float* __restrict__ Wroot1,
                             const float* __restrict__ Wrel2, const float* __restrict__ Wroot2,
                             ushort* __restrict__ Bph, ushort* __restrict__ Bpl) {
    int idx = blockIdx.x * 256 + threadIdx.x;
    if (idx >= 3 * 32768) return;
    int layer = idx >> 15, rem = idx & 32767;
    int j = rem & 7, lane = (rem >> 3) & 63, cf = (rem >> 9) & 7, ks = rem >> 12;
    int k = ks * 32 + (lane >> 4) * 8 + j;
    int c = cf * 16 + (lane & 15);
    const float* Wrel  = layer == 0 ? Wrel0  : layer == 1 ? Wrel1  : Wrel2;
    const float* Wroot = layer == 0 ? Wroot0 : layer == 1 ? Wroot1 : Wroot2;
    float v = (k < 128) ? Wrel[k * 128 + c] : Wroot[(k - 128) * 128 + c];
    ushort hi, lo; split2(v, hi, lo);
    Bph[idx] = hi; Bpl[idx] = lo;
}

// ---------------- init: mapT identity, inv0 = -1, g = 0 ----------------
__global__ void init_all(int* __restrict__ mapT, int* __restrict__ inv0, float* __restrict__ g) {
    int i = blockIdx.x * 256 + threadIdx.x;
    if (i < B_G * N0) { mapT[i] = i; inv0[i] = -1; }
    if (i < B_G * 256) g[i] = 0.f;
}

// ---------------- per-graph CSR build (count+scan+fill, all in LDS, mapT-remapped) ----------------
__global__ __launch_bounds__(512) void csr_build(
        const int* __restrict__ es, const int* __restrict__ ed, const int* __restrict__ mapT,
        int* __restrict__ indptr, int* __restrict__ counts, ushort* __restrict__ srclist,
        int n_cur) {
    int b = blockIdx.x, tid = threadIdx.x;
    __shared__ int mloc[512];
    __shared__ int cnt[512];
    __shared__ int pref[512];
    __shared__ int curs[512];
    __shared__ uint epk[EPG];     // 16 KB packed edges
    mloc[tid] = mapT[b * N0 + tid];
    cnt[tid] = 0;
    __syncthreads();
    int base = b * EPG;
    int nb = b * n_cur;
    for (int i = tid; i < EPG; i += 512) {
        int s = es[base + i] & (N0 - 1);
        int d = ed[base + i] & (N0 - 1);
        int sg = mloc[s], dg = mloc[d];
        uint wv = 0xFFFFFFFFu;
        if ((sg | dg) >= 0) {
            int sl = sg - nb, dl = dg - nb;
            wv = (uint)sl | ((uint)dl << 16);
            atomicAdd(&cnt[dl], 1);
        }
        epk[i] = wv;
    }
    __syncthreads();
    pref[tid] = cnt[tid];
    __syncthreads();
    for (int off = 1; off < 512; off <<= 1) {
        int v = (tid >= off) ? pref[tid - off] : 0;
        __syncthreads();
        pref[tid] += v;
        __syncthreads();
    }
    int excl = tid ? pref[tid - 1] : 0;
    if (tid < n_cur) {
        indptr[nb + tid] = base + excl;
        counts[nb + tid] = cnt[tid];
    }
    curs[tid] = excl;
    __syncthreads();
    for (int i = tid; i < EPG; i += 512) {
        uint wv = epk[i];
        if (wv != 0xFFFFFFFFu) {
            int dl = wv >> 16;
            int pos = atomicAdd(&curs[dl], 1);
            srclist[base + pos] = (ushort)(wv & 0xFFFFu);
        }
    }
}

// ---------------- aggregation v3: per-(graph, channel-quarter) LDS-staged fp32 slab ----------------
// grid = 4*B_G blocks, 1024 thr (16 waves), dynamic LDS = n*32 floats (<=64 KB -> 2 blocks/CU).
// Wave handles nodes d = wave, wave+16, ...; lane-halves process 2 edges/iter over 32 channels.
__global__ __launch_bounds__(1024) void aggregate(
        const ushort* __restrict__ xh, const ushort* __restrict__ xl,
        const int* __restrict__ indptr, const int* __restrict__ counts,
        const ushort* __restrict__ srclist,
        ushort* __restrict__ agg_h, ushort* __restrict__ agg_l, int n) {
    extern __shared__ float slab[];            // [n][32] fp32 (hi+lo combined)
    int b = blockIdx.x >> 2, q = blockIdx.x & 3;
    int tid = threadIdx.x;
    const uint* xh32 = (const uint*)xh;        // row = 64 uints (128 ch packed 2/uint)
    const uint* xl32 = (const uint*)xl;
    // stage: channels [32q, 32q+32) of every node, hi+lo combined to fp32
    for (int t = tid; t < n * 16; t += 1024) {
        int nd = t >> 4, cp = t & 15;
        size_t idx = (size_t)(b * n + nd) * 64 + q * 16 + cp;
        uint h = xh32[idx], l = xl32[idx];
        float v0 = __uint_as_float(h << 16) + __uint_as_float(l << 16);
        float v1 = __uint_as_float(h & 0xffff0000u) + __uint_as_float(l & 0xffff0000u);
        ((float2*)slab)[nd * 16 + cp] = make_float2(v0, v1);
    }
    __syncthreads();
    int wave = tid >> 6, lane = tid & 63, half = lane >> 5, ch = lane & 31;
    // prefetch this wave's indptr/counts: lanes 0-31 hold beg, lanes 32-63 hold cnt
    int pre = 0;
    {
        int i = lane & 31;
        int d_i = wave + i * 16;
        if (d_i < n) pre = (lane < 32) ? indptr[b * n + d_i] : counts[b * n + d_i];
    }
    int nIter = (n - wave + 15) >> 4;
    for (int i = 0; i < nIter; i++) {
        int d = wave + i * 16;
        int beg = __shfl(pre, i);
        int cnt = __shfl(pre, 32 + i);
        float acc = 0.f;
        for (int base = 0; base < cnt; base += 64) {
            int m = cnt - base; m = m > 64 ? 64 : m;
            int sv = (lane < m) ? (int)srclist[beg + base + lane] : 0;
            int j = 0;
            for (; j + 2 <= m; j += 2) {
                int s0 = __shfl(sv, j);
                int s1 = __shfl(sv, j + 1);
                acc += slab[(half ? s1 : s0) * 32 + ch];
            }
            if (j < m) {
                int s0 = __shfl(sv, j);
                if (!half) acc += slab[s0 * 32 + ch];
            }
        }
        acc += __shfl_xor(acc, 32);
        if (lane < 32) {
            ushort hh, ll; split2(acc, hh, ll);
            size_t o = (size_t)(b * n + d) * CCH + q * 32 + ch;
            agg_h[o] = hh; agg_l[o] = ll;
        }
    }
}

// ---------------- bf16x3 MFMA transform + fused score ----------------
//   h = relu([agg|x] @ [Wrel;Wroot] + brel) ; score = tanh(h.p/||p||)
// block = 256 thr (4 waves); each wave owns 32 rows (2 frags) x 128 cols. No LDS.
// A*B ~= Ah*Bh + Ah*Bl + Al*Bh  (fp32 accumulate)
__global__ __launch_bounds__(256) void transform_mfma(
        const ushort* __restrict__ agg_hi, const ushort* __restrict__ agg_lo,
        const ushort* __restrict__ x_hi, const ushort* __restrict__ x_lo,
        const ushort* __restrict__ Bph, const ushort* __restrict__ Bpl,
        const float* __restrict__ brel, const float* __restrict__ pvec,
        ushort* __restrict__ h_hi, ushort* __restrict__ h_lo, float* __restrict__ score) {
    int tid = threadIdx.x;
    int wave = tid >> 6, lane = tid & 63;
    int r = lane & 15, kb = lane >> 4;
    int rows0 = blockIdx.x * 128 + wave * 32;

    f32x4 acc[2][8];
#pragma unroll
    for (int rf = 0; rf < 2; rf++)
#pragma unroll
        for (int cf = 0; cf < 8; cf++) acc[rf][cf] = (f32x4)(0.f);

    const bf16x8* Bh = (const bf16x8*)Bph;
    const bf16x8* Bl = (const bf16x8*)Bpl;

#pragma unroll
    for (int ks = 0; ks < 8; ks++) {
        const ushort* Ah = (ks < 4) ? agg_hi : x_hi;
        const ushort* Al = (ks < 4) ? agg_lo : x_lo;
        int kofs = (ks & 3) * 32 + kb * 8;
        bf16x8 a_hi[2], a_lo[2];
#pragma unroll
        for (int rf = 0; rf < 2; rf++) {
            size_t rowbase = (size_t)(rows0 + rf * 16 + r) * CCH + kofs;
            a_hi[rf] = *(const bf16x8*)&Ah[rowbase];
            a_lo[rf] = *(const bf16x8*)&Al[rowbase];
        }
#pragma unroll
        for (int cf = 0; cf < 8; cf++) {
            bf16x8 bh = Bh[(ks * 8 + cf) * 64 + lane];
            bf16x8 bl = Bl[(ks * 8 + cf) * 64 + lane];
#pragma unroll
            for (int rf = 0; rf < 2; rf++) {
                acc[rf][cf] = __builtin_amdgcn_mfma_f32_16x16x32_bf16(a_hi[rf], bl, acc[rf][cf], 0, 0, 0);
                acc[rf][cf] = __builtin_amdgcn_mfma_f32_16x16x32_bf16(a_lo[rf], bh, acc[rf][cf], 0, 0, 0);
                acc[rf][cf] = __builtin_amdgcn_mfma_f32_16x16x32_bf16(a_hi[rf], bh, acc[rf][cf], 0, 0, 0);
            }
        }
    }

    // epilogue: bias+relu (fp32), hi/lo store, fused score
    float pv[8], bb[8], q = 0.f;
#pragma unroll
    for (int cf = 0; cf < 8; cf++) {
        pv[cf] = pvec[cf * 16 + r];
        bb[cf] = brel[cf * 16 + r];
        q += pv[cf] * pv[cf];
    }
    float dots[2][4] = {{0.f,0.f,0.f,0.f},{0.f,0.f,0.f,0.f}};
#pragma unroll
    for (int rf = 0; rf < 2; rf++) {
#pragma unroll
        for (int cf = 0; cf < 8; cf++) {
#pragma unroll
            for (int reg = 0; reg < 4; reg++) {
                float v = acc[rf][cf][reg] + bb[cf];
                v = v > 0.f ? v : 0.f;
                int row = rows0 + rf * 16 + kb * 4 + reg;
                ushort hi, lo; split2(v, hi, lo);
                h_hi[(size_t)row * CCH + cf * 16 + r] = hi;
                h_lo[(size_t)row * CCH + cf * 16 + r] = lo;
                dots[rf][reg] += v * pv[cf];
            }
        }
    }
#pragma unroll
    for (int off = 1; off < 16; off <<= 1) {
        q += __shfl_xor(q, off);
#pragma unroll
        for (int rf = 0; rf < 2; rf++)
#pragma unroll
            for (int reg = 0; reg < 4; reg++)
                dots[rf][reg] += __shfl_xor(dots[rf][reg], off);
    }
    if (r == 0) {
        float inv_norm = rsqrtf(q);
#pragma unroll
        for (int rf = 0; rf < 2; rf++)
#pragma unroll
            for (int reg = 0; reg < 4; reg++)
                score[rows0 + rf * 16 + kb * 4 + reg] = tanhf(dots[rf][reg] * inv_norm);
    }
}

// ---------------- top-k per graph: bitonic sort of 512 packed keys ----------------
__global__ __launch_bounds__(256) void topk_kernel(const float* __restrict__ score,
                                                   int* __restrict__ inv,
                                                   int* __restrict__ kglob,
                                                   float* __restrict__ kval, int n, int k) {
    int b = blockIdx.x;
    __shared__ unsigned long long keys[512];
    int tid = threadIdx.x;
    for (int s = tid; s < 512; s += 256) {
        unsigned long long key = 0ull;   // sorts below all real scores
        if (s < n) {
            float v = score[b * n + s];
            unsigned u = __float_as_uint(v);
            u = (u & 0x80000000u) ? ~u : (u | 0x80000000u);   // orderable
            key = ((unsigned long long)u << 32) | (unsigned)(~s); // ties -> lower idx first
        }
        keys[s] = key;
    }
    __syncthreads();
    for (int kk2 = 2; kk2 <= 512; kk2 <<= 1) {
        for (int j = kk2 >> 1; j > 0; j >>= 1) {
            for (int s = tid; s < 512; s += 256) {
                int sxj = s ^ j;
                if (sxj > s) {
                    unsigned long long a = keys[s], c = keys[sxj];
                    bool descRegion = ((s & kk2) == 0);
                    bool doSwap = descRegion ? (a < c) : (a > c);
                    if (doSwap) { keys[s] = c; keys[sxj] = a; }
                }
            }
            __syncthreads();
        }
    }
    for (int j = tid; j < k; j += 256) {
        unsigned long long key = keys[j];
        int node = (int)(~(unsigned)key);
        float v = score[b * n + node];
        int newid = b * k + j;
        kglob[newid] = b * n + node;
        kval[newid] = v;
        inv[b * n + node] = newid;
    }
}

// ---------------- gather+scale kept rows (hi/lo -> hi/lo) ----------------
__global__ void gather_kernel(const ushort* __restrict__ hh, const ushort* __restrict__ hl,
                              const int* __restrict__ kglob, const float* __restrict__ kval,
                              ushort* __restrict__ xh, ushort* __restrict__ xl, int nk) {
    int wid = (blockIdx.x * 256 + threadIdx.x) >> 6;
    int lane = threadIdx.x & 63;
    if (wid >= nk) return;
    int gsrc = kglob[wid];
    float v = kval[wid];
    uint h = ((const uint*)(hh + (size_t)gsrc * CCH))[lane];
    uint l = ((const uint*)(hl + (size_t)gsrc * CCH))[lane];
    float c0 = (__uint_as_float(h << 16) + __uint_as_float(l << 16)) * v;
    float c1 = (__uint_as_float(h & 0xffff0000u) + __uint_as_float(l & 0xffff0000u)) * v;
    ushort h0, l0, h1, l1;
    split2(c0, h0, l0); split2(c1, h1, l1);
    ((uint*)(xh + (size_t)wid * CCH))[lane] = (uint)h0 | ((uint)h1 << 16);
    ((uint*)(xl + (size_t)wid * CCH))[lane] = (uint)l0 | ((uint)l1 << 16);
}

// ---------------- compose mapT through this layer's inv; reset other inv buffer ----------------
__global__ void compose_map(int* __restrict__ mapT, const int* __restrict__ invA,
                            int* __restrict__ invB, int bk) {
    int i = blockIdx.x * 256 + threadIdx.x;
    if (i < B_G * N0) {
        int m = mapT[i];
        mapT[i] = (m >= 0) ? invA[m] : -1;
    }
    if (i < bk) invB[i] = -1;
}

// ---------------- readout: gmp || gap (hi/lo input), accumulated into g ----------------
__global__ __launch_bounds__(512) void readout_kernel(const ushort* __restrict__ xh,
                                                      const ushort* __restrict__ xl,
                                                      float* __restrict__ g, int k) {
    int b = blockIdx.x;
    int c = threadIdx.x & 127;
    int q = threadIdx.x >> 7;
    float mx = -1e30f, sm = 0.f;
    for (int j = q; j < k; j += 4) {
        size_t idx = ((size_t)b * k + j) * CCH + c;
        float v = b2f(xh[idx]) + b2f(xl[idx]);
        mx = fmaxf(mx, v); sm += v;
    }
    __shared__ float smx[4][128], ssm[4][128];
    smx[q][c] = mx; ssm[q][c] = sm;
    __syncthreads();
    if (q == 0) {
        mx = fmaxf(fmaxf(smx[0][c], smx[1][c]), fmaxf(smx[2][c], smx[3][c]));
        sm = ssm[0][c] + ssm[1][c] + ssm[2][c] + ssm[3][c];
        g[b * 256 + c] += mx;
        g[b * 256 + 128 + c] += sm / (float)k;
    }
}

// ---------------- final MLP + log_softmax ----------------
__global__ __launch_bounds__(128) void mlp_kernel(const float* __restrict__ g,
        const float* __restrict__ W1, const float* __restrict__ b1,
        const float* __restrict__ W2, const float* __restrict__ b2,
        const float* __restrict__ W3, const float* __restrict__ b3,
        float* __restrict__ out) {
    int b = blockIdx.x, t = threadIdx.x;
    __shared__ float gs[256], h1[128], h2[64], lg[10];
    gs[t] = g[b * 256 + t];
    gs[128 + t] = g[b * 256 + 128 + t];
    __syncthreads();
    {
        float a = b1[t];
        for (int c = 0; c < 256; c++) a += gs[c] * W1[c * 128 + t];
        h1[t] = fmaxf(a, 0.f);
    }
    __syncthreads();
    if (t < 64) {
        float a = b2[t];
        for (int c = 0; c < 128; c++) a += h1[c] * W2[c * 64 + t];
        h2[t] = fmaxf(a, 0.f);
    }
    __syncthreads();
    if (t < 10) {
        float a = b3[t];
        for (int c = 0; c < 64; c++) a += h2[c] * W3[c * 10 + t];
        lg[t] = a;
    }
    __syncthreads();
    if (t < 10) {
        float m = lg[0];
        for (int i = 1; i < 10; i++) m = fmaxf(m, lg[i]);
        float s = 0.f;
        for (int i = 0; i < 10; i++) s += expf(lg[i] - m);
        out[b * 10 + t] = lg[t] - m - logf(s);
    }
}

// ---------------- host ----------------
extern "C" void kernel_launch(void* const* d_in, const int* in_sizes, int n_in,
                              void* d_out, int out_size, void* d_ws, size_t ws_size,
                              hipStream_t stream) {
    (void)in_sizes; (void)n_in; (void)out_size; (void)ws_size;
    const float* x0 = (const float*)d_in[0];
    const int* es = (const int*)d_in[1];
    const int* ed = (const int*)d_in[2];
    const float* Wroot[3] = {(const float*)d_in[3], (const float*)d_in[7], (const float*)d_in[11]};
    const float* Wrel[3]  = {(const float*)d_in[4], (const float*)d_in[8], (const float*)d_in[12]};
    const float* brel[3]  = {(const float*)d_in[5], (const float*)d_in[9], (const float*)d_in[13]};
    const float* pvec[3]  = {(const float*)d_in[6], (const float*)d_in[10], (const float*)d_in[14]};
    const float* W1 = (const float*)d_in[15];
    const float* b1 = (const float*)d_in[16];
    const float* W2 = (const float*)d_in[17];
    const float* b2 = (const float*)d_in[18];
    const float* W3 = (const float*)d_in[19];
    const float* b3 = (const float*)d_in[20];

    size_t off = 0;
    char* base = (char*)d_ws;
    auto alloc = [&](size_t bytes) -> void* {
        void* p = base + off;
        off += (bytes + 255) & ~(size_t)255;
        return p;
    };
    const size_t FEAT = (size_t)(B_G * N0) * CCH * 2;   // bf16 plane
    ushort* xb_hi  = (ushort*)alloc(FEAT);   // layer-input features hi
    ushort* xb_lo  = (ushort*)alloc(FEAT);   // layer-input features lo
    ushort* agg_hi = (ushort*)alloc(FEAT);   // aggregation hi (reused as h hi)
    ushort* agg_lo = (ushort*)alloc(FEAT);   // aggregation lo (reused as h lo)
    ushort* Bph = (ushort*)alloc((size_t)3 * 32768 * 2); // packed weights hi
    ushort* Bpl = (ushort*)alloc((size_t)3 * 32768 * 2); // packed weights lo
    int* mapT   = (int*)alloc((size_t)(B_G * N0) * 4);   // orig node -> current id / -1
    int* counts = (int*)alloc((size_t)(B_G * N0) * 4);
    int* indptr = (int*)alloc((size_t)(B_G * N0) * 4);
    ushort* srclist = (ushort*)alloc((size_t)E_TOTAL * 2);
    float* score = (float*)alloc((size_t)(B_G * N0) * 4);
    int* invbuf[2] = {(int*)alloc((size_t)(B_G * N0) * 4), (int*)alloc((size_t)(B_G * N0) * 4)};
    int* kglob = (int*)alloc((size_t)(B_G * K1) * 4);
    float* kval = (float*)alloc((size_t)(B_G * K1) * 4);
    float* g = (float*)alloc((size_t)B_G * 256 * 4);

    convert_x<<<(B_G * N0 * CCH / 4 + 255) / 256, 256, 0, stream>>>(x0, xb_hi, xb_lo,
                                                                    B_G * N0 * CCH / 4);
    pack_weights<<<(3 * 32768 + 255) / 256, 256, 0, stream>>>(
        Wrel[0], Wroot[0], Wrel[1], Wroot[1], Wrel[2], Wroot[2], Bph, Bpl);
    init_all<<<(B_G * N0 + 255) / 256, 256, 0, stream>>>(mapT, invbuf[0], g);

    int nper[4] = {N0, K1, K2, K3};
    for (int l = 0; l < 3; l++) {
        int n = nper[l], k = nper[l + 1];
        int n_nodes = B_G * n;
        int nk = B_G * k;
        int* invA = invbuf[l & 1];
        int* invB = invbuf[(l + 1) & 1];
        csr_build<<<B_G, 512, 0, stream>>>(es, ed, mapT, indptr, counts, srclist, n);
        aggregate<<<4 * B_G, 1024, (size_t)n * 32 * 4, stream>>>(
            xb_hi, xb_lo, indptr, counts, srclist, agg_hi, agg_lo, n);
        // h overwrites agg in place (each wave reads its 32 rows fully before writing them)
        transform_mfma<<<n_nodes / 128, 256, 0, stream>>>(
            agg_hi, agg_lo, xb_hi, xb_lo,
            Bph + (size_t)l * 32768, Bpl + (size_t)l * 32768,
            brel[l], pvec[l], agg_hi, agg_lo, score);
        topk_kernel<<<B_G, 256, 0, stream>>>(score, invA, kglob, kval, n, k);
        gather_kernel<<<(nk + 3) / 4, 256, 0, stream>>>(agg_hi, agg_lo, kglob, kval,
                                                        xb_hi, xb_lo, nk);
        readout_kernel<<<B_G, 512, 0, stream>>>(xb_hi, xb_lo, g, k);
        if (l < 2)
            compose_map<<<(B_G * N0 + 255) / 256, 256, 0, stream>>>(mapT, invA, invB, B_G * k);
    }
    mlp_kernel<<<B_G, 128, 0, stream>>>(g, W1, b1, W2, b2, W3, b3, (float*)d_out);
}

// Round 7
// 378.274 us; speedup vs baseline: 1.3092x; 1.1215x over previous
//
#include <hip/hip_runtime.h>
#include <hip/hip_bf16.h>
#include <math.h>

#define B_G   128
#define N0    512
#define DEG   8
#define CCH   128
#define EPG   (N0*DEG)            // 4096 edges per graph (fixed slab)
#define E_TOTAL (B_G*EPG)
#define K1    410
#define K2    328
#define K3    263
#define NCLS  10

using bf16x8 = __attribute__((ext_vector_type(8))) __bf16;
using f32x4  = __attribute__((ext_vector_type(4))) float;
typedef unsigned short ushort;
typedef unsigned int uint;

__device__ __forceinline__ ushort f2b(float f) {
    uint u = __float_as_uint(f);
    u += 0x7fffu + ((u >> 16) & 1u);      // RNE
    return (ushort)(u >> 16);
}
__device__ __forceinline__ float b2f(ushort h) {
    return __uint_as_float(((uint)h) << 16);
}
// split fp32 -> (hi, lo) bf16 pair;  v ~= hi + lo  (error ~2^-17 rel)
__device__ __forceinline__ void split2(float v, ushort& hi, ushort& lo) {
    hi = f2b(v);
    lo = f2b(v - b2f(hi));
}

// ---------------- convert x0 fp32 -> hi/lo bf16 pair arrays ----------------
__global__ void convert_x(const float* __restrict__ x0, ushort* __restrict__ xh,
                          ushort* __restrict__ xl, int n4) {
    int i = blockIdx.x * 256 + threadIdx.x;   // one float4 per thread
    if (i >= n4) return;
    float4 v = ((const float4*)x0)[i];
    ushort h0, l0, h1, l1, h2, l2, h3, l3;
    split2(v.x, h0, l0); split2(v.y, h1, l1);
    split2(v.z, h2, l2); split2(v.w, h3, l3);
    ((uint2*)xh)[i] = make_uint2((uint)h0 | ((uint)h1 << 16), (uint)h2 | ((uint)h3 << 16));
    ((uint2*)xl)[i] = make_uint2((uint)l0 | ((uint)l1 << 16), (uint)l2 | ((uint)l3 << 16));
}

// ---------------- pack weights into per-lane MFMA fragment layout (hi/lo) ----------------
// Bp[layer][ks][cf][lane][j] ; k = ks*32 + (lane>>4)*8 + j ; c = cf*16 + (lane&15)
__global__ void pack_weights(const float* __restrict__ Wrel0, const float* __restrict__ Wroot0,
                             const float* __restrict__ Wrel1, const float* __restrict__ Wroot1,
                             const float* __restrict__ Wrel2, const float* __restrict__ Wroot2,
                             ushort* __restrict__ Bph, ushort* __restrict__ Bpl) {
    int idx = blockIdx.x * 256 + threadIdx.x;
    if (idx >= 3 * 32768) return;
    int layer = idx >> 15, rem = idx & 32767;
    int j = rem & 7, lane = (rem >> 3) & 63, cf = (rem >> 9) & 7, ks = rem >> 12;
    int k = ks * 32 + (lane >> 4) * 8 + j;
    int c = cf * 16 + (lane & 15);
    const float* Wrel  = layer == 0 ? Wrel0  : layer == 1 ? Wrel1  : Wrel2;
    const float* Wroot = layer == 0 ? Wroot0 : layer == 1 ? Wroot1 : Wroot2;
    float v = (k < 128) ? Wrel[k * 128 + c] : Wroot[(k - 128) * 128 + c];
    ushort hi, lo; split2(v, hi, lo);
    Bph[idx] = hi; Bpl[idx] = lo;
}

// ---------------- init: mapT identity, inv0 = -1, g = 0 ----------------
__global__ void init_all(int* __restrict__ mapT, int* __restrict__ inv0, float* __restrict__ g) {
    int i = blockIdx.x * 256 + threadIdx.x;
    if (i < B_G * N0) { mapT[i] = i; inv0[i] = -1; }
    if (i < B_G * 256) g[i] = 0.f;
}

// ---------------- per-graph CSR build (count+scan+fill, all in LDS, mapT-remapped) ----------------
__global__ __launch_bounds__(512) void csr_build(
        const int* __restrict__ es, const int* __restrict__ ed, const int* __restrict__ mapT,
        int* __restrict__ indptr, int* __restrict__ counts, int* __restrict__ srclist,
        int n_cur) {
    int b = blockIdx.x, tid = threadIdx.x;
    __shared__ int mloc[512];
    __shared__ int cnt[512];
    __shared__ int pref[512];
    __shared__ int curs[512];
    __shared__ uint epk[EPG];     // 16 KB packed edges
    mloc[tid] = mapT[b * N0 + tid];
    cnt[tid] = 0;
    __syncthreads();
    int base = b * EPG;
    int nb = b * n_cur;
    for (int i = tid; i < EPG; i += 512) {
        int s = es[base + i] & (N0 - 1);
        int d = ed[base + i] & (N0 - 1);
        int sg = mloc[s], dg = mloc[d];
        uint wv = 0xFFFFFFFFu;
        if ((sg | dg) >= 0) {
            int sl = sg - nb, dl = dg - nb;
            wv = (uint)sl | ((uint)dl << 16);
            atomicAdd(&cnt[dl], 1);
        }
        epk[i] = wv;
    }
    __syncthreads();
    pref[tid] = cnt[tid];
    __syncthreads();
    for (int off = 1; off < 512; off <<= 1) {
        int v = (tid >= off) ? pref[tid - off] : 0;
        __syncthreads();
        pref[tid] += v;
        __syncthreads();
    }
    int excl = tid ? pref[tid - 1] : 0;
    if (tid < n_cur) {
        indptr[nb + tid] = base + excl;
        counts[nb + tid] = cnt[tid];
    }
    curs[tid] = excl;
    __syncthreads();
    for (int i = tid; i < EPG; i += 512) {
        uint wv = epk[i];
        if (wv != 0xFFFFFFFFu) {
            int dl = wv >> 16;
            int pos = atomicAdd(&curs[dl], 1);
            srclist[base + pos] = (int)(wv & 0xFFFFu);
        }
    }
}

// ---------------- aggregation v4: per-(graph, channel-quarter) LDS-staged fp32 slab ----------------
// grid = 4*B_G blocks, 1024 thr (16 waves), dynamic LDS = n*32 floats (<=64 KB -> 2 blocks/CU).
// Lane layout: 8 node-groups x 8 lanes; each lane reads float4 (4 ch) per edge via ds_read_b128.
// No cross-lane ops at all; edge ids are 8-lane broadcast loads from int srclist.
__global__ __launch_bounds__(1024) void aggregate(
        const ushort* __restrict__ xh, const ushort* __restrict__ xl,
        const int* __restrict__ indptr, const int* __restrict__ counts,
        const int* __restrict__ srclist,
        ushort* __restrict__ agg_h, ushort* __restrict__ agg_l, int n) {
    extern __shared__ float slab[];            // [n][32] fp32 (hi+lo combined)
    int b = blockIdx.x >> 2, q = blockIdx.x & 3;
    int tid = threadIdx.x;
    const uint* xh32 = (const uint*)xh;        // row = 64 uints (128 ch packed 2/uint)
    const uint* xl32 = (const uint*)xl;
    // stage: channels [32q, 32q+32) of every node, hi+lo combined to fp32
    for (int t = tid; t < n * 16; t += 1024) {
        int nd = t >> 4, cp = t & 15;
        size_t idx = (size_t)(b * n + nd) * 64 + q * 16 + cp;
        uint h = xh32[idx], l = xl32[idx];
        float v0 = __uint_as_float(h << 16) + __uint_as_float(l << 16);
        float v1 = __uint_as_float(h & 0xffff0000u) + __uint_as_float(l & 0xffff0000u);
        ((float2*)slab)[nd * 16 + cp] = make_float2(v0, v1);
    }
    __syncthreads();
    int wave = tid >> 6, lane = tid & 63;
    int gl = lane >> 3;           // node slot within wave (0..7)
    int sub = lane & 7;           // float4 slot (4 channels)
    int ngroups = (n + 7) >> 3;
    for (int g = wave; g < ngroups; g += 16) {
        int d = g * 8 + gl;
        bool act = d < n;
        int beg = 0, cnt = 0;
        if (act) { beg = indptr[b * n + d]; cnt = counts[b * n + d]; }
        float4 acc = make_float4(0.f, 0.f, 0.f, 0.f);
        int id_next = (cnt > 0) ? srclist[beg] : 0;
        for (int j = 0; j < cnt; j++) {
            int id = id_next;
            if (j + 1 < cnt) id_next = srclist[beg + j + 1];
            const float4 v = *(const float4*)&slab[id * 32 + sub * 4];
            acc.x += v.x; acc.y += v.y; acc.z += v.z; acc.w += v.w;
        }
        if (act) {
            ushort h0, l0, h1, l1, h2, l2, h3, l3;
            split2(acc.x, h0, l0); split2(acc.y, h1, l1);
            split2(acc.z, h2, l2); split2(acc.w, h3, l3);
            size_t o = ((size_t)(b * n + d) * CCH + q * 32 + sub * 4) >> 1;  // uint index
            ((uint*)agg_h)[o]     = (uint)h0 | ((uint)h1 << 16);
            ((uint*)agg_h)[o + 1] = (uint)h2 | ((uint)h3 << 16);
            ((uint*)agg_l)[o]     = (uint)l0 | ((uint)l1 << 16);
            ((uint*)agg_l)[o + 1] = (uint)l2 | ((uint)l3 << 16);
        }
    }
}

// ---------------- bf16x3 MFMA transform + fused score ----------------
//   h = relu([agg|x] @ [Wrel;Wroot] + brel) ; score = tanh(h.p/||p||)
// block = 256 thr (4 waves); each wave owns 32 rows (2 frags) x 128 cols. No LDS.
// A*B ~= Ah*Bh + Ah*Bl + Al*Bh  (fp32 accumulate)
__global__ __launch_bounds__(256) void transform_mfma(
        const ushort* __restrict__ agg_hi, const ushort* __restrict__ agg_lo,
        const ushort* __restrict__ x_hi, const ushort* __restrict__ x_lo,
        const ushort* __restrict__ Bph, const ushort* __restrict__ Bpl,
        const float* __restrict__ brel, const float* __restrict__ pvec,
        ushort* __restrict__ h_hi, ushort* __restrict__ h_lo, float* __restrict__ score) {
    int tid = threadIdx.x;
    int wave = tid >> 6, lane = tid & 63;
    int r = lane & 15, kb = lane >> 4;
    int rows0 = blockIdx.x * 128 + wave * 32;

    f32x4 acc[2][8];
#pragma unroll
    for (int rf = 0; rf < 2; rf++)
#pragma unroll
        for (int cf = 0; cf < 8; cf++) acc[rf][cf] = (f32x4)(0.f);

    const bf16x8* Bh = (const bf16x8*)Bph;
    const bf16x8* Bl = (const bf16x8*)Bpl;

#pragma unroll
    for (int ks = 0; ks < 8; ks++) {
        const ushort* Ah = (ks < 4) ? agg_hi : x_hi;
        const ushort* Al = (ks < 4) ? agg_lo : x_lo;
        int kofs = (ks & 3) * 32 + kb * 8;
        bf16x8 a_hi[2], a_lo[2];
#pragma unroll
        for (int rf = 0; rf < 2; rf++) {
            size_t rowbase = (size_t)(rows0 + rf * 16 + r) * CCH + kofs;
            a_hi[rf] = *(const bf16x8*)&Ah[rowbase];
            a_lo[rf] = *(const bf16x8*)&Al[rowbase];
        }
#pragma unroll
        for (int cf = 0; cf < 8; cf++) {
            bf16x8 bh = Bh[(ks * 8 + cf) * 64 + lane];
            bf16x8 bl = Bl[(ks * 8 + cf) * 64 + lane];
#pragma unroll
            for (int rf = 0; rf < 2; rf++) {
                acc[rf][cf] = __builtin_amdgcn_mfma_f32_16x16x32_bf16(a_hi[rf], bl, acc[rf][cf], 0, 0, 0);
                acc[rf][cf] = __builtin_amdgcn_mfma_f32_16x16x32_bf16(a_lo[rf], bh, acc[rf][cf], 0, 0, 0);
                acc[rf][cf] = __builtin_amdgcn_mfma_f32_16x16x32_bf16(a_hi[rf], bh, acc[rf][cf], 0, 0, 0);
            }
        }
    }

    // epilogue: bias+relu (fp32), hi/lo store, fused score
    float pv[8], bb[8], q = 0.f;
#pragma unroll
    for (int cf = 0; cf < 8; cf++) {
        pv[cf] = pvec[cf * 16 + r];
        bb[cf] = brel[cf * 16 + r];
        q += pv[cf] * pv[cf];
    }
    float dots[2][4] = {{0.f,0.f,0.f,0.f},{0.f,0.f,0.f,0.f}};
#pragma unroll
    for (int rf = 0; rf < 2; rf++) {
#pragma unroll
        for (int cf = 0; cf < 8; cf++) {
#pragma unroll
            for (int reg = 0; reg < 4; reg++) {
                float v = acc[rf][cf][reg] + bb[cf];
                v = v > 0.f ? v : 0.f;
                int row = rows0 + rf * 16 + kb * 4 + reg;
                ushort hi, lo; split2(v, hi, lo);
                h_hi[(size_t)row * CCH + cf * 16 + r] = hi;
                h_lo[(size_t)row * CCH + cf * 16 + r] = lo;
                dots[rf][reg] += v * pv[cf];
            }
        }
    }
#pragma unroll
    for (int off = 1; off < 16; off <<= 1) {
        q += __shfl_xor(q, off);
#pragma unroll
        for (int rf = 0; rf < 2; rf++)
#pragma unroll
            for (int reg = 0; reg < 4; reg++)
                dots[rf][reg] += __shfl_xor(dots[rf][reg], off);
    }
    if (r == 0) {
        float inv_norm = rsqrtf(q);
#pragma unroll
        for (int rf = 0; rf < 2; rf++)
#pragma unroll
            for (int reg = 0; reg < 4; reg++)
                score[rows0 + rf * 16 + kb * 4 + reg] = tanhf(dots[rf][reg] * inv_norm);
    }
}

// ---------------- top-k per graph: bitonic sort of 512 packed keys ----------------
__global__ __launch_bounds__(256) void topk_kernel(const float* __restrict__ score,
                                                   int* __restrict__ inv,
                                                   int* __restrict__ kglob,
                                                   float* __restrict__ kval, int n, int k) {
    int b = blockIdx.x;
    __shared__ unsigned long long keys[512];
    int tid = threadIdx.x;
    for (int s = tid; s < 512; s += 256) {
        unsigned long long key = 0ull;   // sorts below all real scores
        if (s < n) {
            float v = score[b * n + s];
            unsigned u = __float_as_uint(v);
            u = (u & 0x80000000u) ? ~u : (u | 0x80000000u);   // orderable
            key = ((unsigned long long)u << 32) | (unsigned)(~s); // ties -> lower idx first
        }
        keys[s] = key;
    }
    __syncthreads();
    for (int kk2 = 2; kk2 <= 512; kk2 <<= 1) {
        for (int j = kk2 >> 1; j > 0; j >>= 1) {
            for (int s = tid; s < 512; s += 256) {
                int sxj = s ^ j;
                if (sxj > s) {
                    unsigned long long a = keys[s], c = keys[sxj];
                    bool descRegion = ((s & kk2) == 0);
                    bool doSwap = descRegion ? (a < c) : (a > c);
                    if (doSwap) { keys[s] = c; keys[sxj] = a; }
                }
            }
            __syncthreads();
        }
    }
    for (int j = tid; j < k; j += 256) {
        unsigned long long key = keys[j];
        int node = (int)(~(unsigned)key);
        float v = score[b * n + node];
        int newid = b * k + j;
        kglob[newid] = b * n + node;
        kval[newid] = v;
        inv[b * n + node] = newid;
    }
}

// ---------------- gather+scale kept rows (hi/lo -> hi/lo) ----------------
__global__ void gather_kernel(const ushort* __restrict__ hh, const ushort* __restrict__ hl,
                              const int* __restrict__ kglob, const float* __restrict__ kval,
                              ushort* __restrict__ xh, ushort* __restrict__ xl, int nk) {
    int wid = (blockIdx.x * 256 + threadIdx.x) >> 6;
    int lane = threadIdx.x & 63;
    if (wid >= nk) return;
    int gsrc = kglob[wid];
    float v = kval[wid];
    uint h = ((const uint*)(hh + (size_t)gsrc * CCH))[lane];
    uint l = ((const uint*)(hl + (size_t)gsrc * CCH))[lane];
    float c0 = (__uint_as_float(h << 16) + __uint_as_float(l << 16)) * v;
    float c1 = (__uint_as_float(h & 0xffff0000u) + __uint_as_float(l & 0xffff0000u)) * v;
    ushort h0, l0, h1, l1;
    split2(c0, h0, l0); split2(c1, h1, l1);
    ((uint*)(xh + (size_t)wid * CCH))[lane] = (uint)h0 | ((uint)h1 << 16);
    ((uint*)(xl + (size_t)wid * CCH))[lane] = (uint)l0 | ((uint)l1 << 16);
}

// ---------------- compose mapT through this layer's inv; reset other inv buffer ----------------
__global__ void compose_map(int* __restrict__ mapT, const int* __restrict__ invA,
                            int* __restrict__ invB, int bk) {
    int i = blockIdx.x * 256 + threadIdx.x;
    if (i < B_G * N0) {
        int m = mapT[i];
        mapT[i] = (m >= 0) ? invA[m] : -1;
    }
    if (i < bk) invB[i] = -1;
}

// ---------------- readout: gmp || gap (hi/lo input), accumulated into g ----------------
__global__ __launch_bounds__(512) void readout_kernel(const ushort* __restrict__ xh,
                                                      const ushort* __restrict__ xl,
                                                      float* __restrict__ g, int k) {
    int b = blockIdx.x;
    int c = threadIdx.x & 127;
    int q = threadIdx.x >> 7;
    float mx = -1e30f, sm = 0.f;
    for (int j = q; j < k; j += 4) {
        size_t idx = ((size_t)b * k + j) * CCH + c;
        float v = b2f(xh[idx]) + b2f(xl[idx]);
        mx = fmaxf(mx, v); sm += v;
    }
    __shared__ float smx[4][128], ssm[4][128];
    smx[q][c] = mx; ssm[q][c] = sm;
    __syncthreads();
    if (q == 0) {
        mx = fmaxf(fmaxf(smx[0][c], smx[1][c]), fmaxf(smx[2][c], smx[3][c]));
        sm = ssm[0][c] + ssm[1][c] + ssm[2][c] + ssm[3][c];
        g[b * 256 + c] += mx;
        g[b * 256 + 128 + c] += sm / (float)k;
    }
}

// ---------------- final MLP + log_softmax ----------------
__global__ __launch_bounds__(128) void mlp_kernel(const float* __restrict__ g,
        const float* __restrict__ W1, const float* __restrict__ b1,
        const float* __restrict__ W2, const float* __restrict__ b2,
        const float* __restrict__ W3, const float* __restrict__ b3,
        float* __restrict__ out) {
    int b = blockIdx.x, t = threadIdx.x;
    __shared__ float gs[256], h1[128], h2[64], lg[10];
    gs[t] = g[b * 256 + t];
    gs[128 + t] = g[b * 256 + 128 + t];
    __syncthreads();
    {
        float a = b1[t];
        for (int c = 0; c < 256; c++) a += gs[c] * W1[c * 128 + t];
        h1[t] = fmaxf(a, 0.f);
    }
    __syncthreads();
    if (t < 64) {
        float a = b2[t];
        for (int c = 0; c < 128; c++) a += h1[c] * W2[c * 64 + t];
        h2[t] = fmaxf(a, 0.f);
    }
    __syncthreads();
    if (t < 10) {
        float a = b3[t];
        for (int c = 0; c < 64; c++) a += h2[c] * W3[c * 10 + t];
        lg[t] = a;
    }
    __syncthreads();
    if (t < 10) {
        float m = lg[0];
        for (int i = 1; i < 10; i++) m = fmaxf(m, lg[i]);
        float s = 0.f;
        for (int i = 0; i < 10; i++) s += expf(lg[i] - m);
        out[b * 10 + t] = lg[t] - m - logf(s);
    }
}

// ---------------- host ----------------
extern "C" void kernel_launch(void* const* d_in, const int* in_sizes, int n_in,
                              void* d_out, int out_size, void* d_ws, size_t ws_size,
                              hipStream_t stream) {
    (void)in_sizes; (void)n_in; (void)out_size; (void)ws_size;
    const float* x0 = (const float*)d_in[0];
    const int* es = (const int*)d_in[1];
    const int* ed = (const int*)d_in[2];
    const float* Wroot[3] = {(const float*)d_in[3], (const float*)d_in[7], (const float*)d_in[11]};
    const float* Wrel[3]  = {(const float*)d_in[4], (const float*)d_in[8], (const float*)d_in[12]};
    const float* brel[3]  = {(const float*)d_in[5], (const float*)d_in[9], (const float*)d_in[13]};
    const float* pvec[3]  = {(const float*)d_in[6], (const float*)d_in[10], (const float*)d_in[14]};
    const float* W1 = (const float*)d_in[15];
    const float* b1 = (const float*)d_in[16];
    const float* W2 = (const float*)d_in[17];
    const float* b2 = (const float*)d_in[18];
    const float* W3 = (const float*)d_in[19];
    const float* b3 = (const float*)d_in[20];

    size_t off = 0;
    char* base = (char*)d_ws;
    auto alloc = [&](size_t bytes) -> void* {
        void* p = base + off;
        off += (bytes + 255) & ~(size_t)255;
        return p;
    };
    const size_t FEAT = (size_t)(B_G * N0) * CCH * 2;   // bf16 plane
    ushort* xb_hi  = (ushort*)alloc(FEAT);   // layer-input features hi
    ushort* xb_lo  = (ushort*)alloc(FEAT);   // layer-input features lo
    ushort* agg_hi = (ushort*)alloc(FEAT);   // aggregation hi (reused as h hi)
    ushort* agg_lo = (ushort*)alloc(FEAT);   // aggregation lo (reused as h lo)
    ushort* Bph = (ushort*)alloc((size_t)3 * 32768 * 2); // packed weights hi
    ushort* Bpl = (ushort*)alloc((size_t)3 * 32768 * 2); // packed weights lo
    int* mapT   = (int*)alloc((size_t)(B_G * N0) * 4);   // orig node -> current id / -1
    int* counts = (int*)alloc((size_t)(B_G * N0) * 4);
    int* indptr = (int*)alloc((size_t)(B_G * N0) * 4);
    int* srclist = (int*)alloc((size_t)E_TOTAL * 4);
    float* score = (float*)alloc((size_t)(B_G * N0) * 4);
    int* invbuf[2] = {(int*)alloc((size_t)(B_G * N0) * 4), (int*)alloc((size_t)(B_G * N0) * 4)};
    int* kglob = (int*)alloc((size_t)(B_G * K1) * 4);
    float* kval = (float*)alloc((size_t)(B_G * K1) * 4);
    float* g = (float*)alloc((size_t)B_G * 256 * 4);

    convert_x<<<(B_G * N0 * CCH / 4 + 255) / 256, 256, 0, stream>>>(x0, xb_hi, xb_lo,
                                                                    B_G * N0 * CCH / 4);
    pack_weights<<<(3 * 32768 + 255) / 256, 256, 0, stream>>>(
        Wrel[0], Wroot[0], Wrel[1], Wroot[1], Wrel[2], Wroot[2], Bph, Bpl);
    init_all<<<(B_G * N0 + 255) / 256, 256, 0, stream>>>(mapT, invbuf[0], g);

    int nper[4] = {N0, K1, K2, K3};
    for (int l = 0; l < 3; l++) {
        int n = nper[l], k = nper[l + 1];
        int n_nodes = B_G * n;
        int nk = B_G * k;
        int* invA = invbuf[l & 1];
        int* invB = invbuf[(l + 1) & 1];
        csr_build<<<B_G, 512, 0, stream>>>(es, ed, mapT, indptr, counts, srclist, n);
        aggregate<<<4 * B_G, 1024, (size_t)n * 32 * 4, stream>>>(
            xb_hi, xb_lo, indptr, counts, srclist, agg_hi, agg_lo, n);
        // h overwrites agg in place (each wave reads its 32 rows fully before writing them)
        transform_mfma<<<n_nodes / 128, 256, 0, stream>>>(
            agg_hi, agg_lo, xb_hi, xb_lo,
            Bph + (size_t)l * 32768, Bpl + (size_t)l * 32768,
            brel[l], pvec[l], agg_hi, agg_lo, score);
        topk_kernel<<<B_G, 256, 0, stream>>>(score, invA, kglob, kval, n, k);
        gather_kernel<<<(nk + 3) / 4, 256, 0, stream>>>(agg_hi, agg_lo, kglob, kval,
                                                        xb_hi, xb_lo, nk);
        readout_kernel<<<B_G, 512, 0, stream>>>(xb_hi, xb_lo, g, k);
        if (l < 2)
            compose_map<<<(B_G * N0 + 255) / 256, 256, 0, stream>>>(mapT, invA, invB, B_G * k);
    }
    mlp_kernel<<<B_G, 128, 0, stream>>>(g, W1, b1, W2, b2, W3, b3, (float*)d_out);
}

// Round 8
// 340.038 us; speedup vs baseline: 1.4564x; 1.1124x over previous
//
#include <hip/hip_runtime.h>
#include <hip/hip_bf16.h>
#include <math.h>

#define B_G   128
#define N0    512
#define DEG   8
#define CCH   128
#define EPG   (N0*DEG)            // 4096 edges per graph (fixed slab)
#define E_TOTAL (B_G*EPG)
#define K1    410
#define K2    328
#define K3    263
#define NCLS  10

using bf16x8 = __attribute__((ext_vector_type(8))) __bf16;
using f32x4  = __attribute__((ext_vector_type(4))) float;
typedef unsigned short ushort;
typedef unsigned int uint;

__device__ __forceinline__ ushort f2b(float f) {
    uint u = __float_as_uint(f);
    u += 0x7fffu + ((u >> 16) & 1u);      // RNE
    return (ushort)(u >> 16);
}
__device__ __forceinline__ float b2f(ushort h) {
    return __uint_as_float(((uint)h) << 16);
}
// split fp32 -> (hi, lo) bf16 pair;  v ~= hi + lo  (error ~2^-17 rel)
__device__ __forceinline__ void split2(float v, ushort& hi, ushort& lo) {
    hi = f2b(v);
    lo = f2b(v - b2f(hi));
}
// packed channel word: hi | lo<<16
__device__ __forceinline__ uint pksplit(float v) {
    ushort h, l; split2(v, h, l);
    return (uint)h | ((uint)l << 16);
}
__device__ __forceinline__ float unpk(uint u) {
    return __uint_as_float(u << 16) + __uint_as_float(u & 0xffff0000u);
}

// ---------------- convert x0 fp32 -> packed uint (hi|lo<<16) per channel ----------------
__global__ void convert_x(const float* __restrict__ x0, uint* __restrict__ xp, int n4) {
    int i = blockIdx.x * 256 + threadIdx.x;   // one float4 per thread
    if (i >= n4) return;
    float4 v = ((const float4*)x0)[i];
    uint4 o;
    o.x = pksplit(v.x); o.y = pksplit(v.y); o.z = pksplit(v.z); o.w = pksplit(v.w);
    ((uint4*)xp)[i] = o;
}

// ---------------- pack weights into per-lane MFMA fragment layout (hi/lo) ----------------
// Bp[layer][ks][cf][lane][j] ; k = ks*32 + (lane>>4)*8 + j ; c = cf*16 + (lane&15)
__global__ void pack_weights(const float* __restrict__ Wrel0, const float* __restrict__ Wroot0,
                             const float* __restrict__ Wrel1, const float* __restrict__ Wroot1,
                             const float* __restrict__ Wrel2, const float* __restrict__ Wroot2,
                             ushort* __restrict__ Bph, ushort* __restrict__ Bpl) {
    int idx = blockIdx.x * 256 + threadIdx.x;
    if (idx >= 3 * 32768) return;
    int layer = idx >> 15, rem = idx & 32767;
    int j = rem & 7, lane = (rem >> 3) & 63, cf = (rem >> 9) & 7, ks = rem >> 12;
    int k = ks * 32 + (lane >> 4) * 8 + j;
    int c = cf * 16 + (lane & 15);
    const float* Wrel  = layer == 0 ? Wrel0  : layer == 1 ? Wrel1  : Wrel2;
    const float* Wroot = layer == 0 ? Wroot0 : layer == 1 ? Wroot1 : Wroot2;
    float v = (k < 128) ? Wrel[k * 128 + c] : Wroot[(k - 128) * 128 + c];
    ushort hi, lo; split2(v, hi, lo);
    Bph[idx] = hi; Bpl[idx] = lo;
}

// ---------------- init: mapT identity, inv0 = -1, g = 0 ----------------
__global__ void init_all(int* __restrict__ mapT, int* __restrict__ inv0, float* __restrict__ g) {
    int i = blockIdx.x * 256 + threadIdx.x;
    if (i < B_G * N0) { mapT[i] = i; inv0[i] = -1; }
    if (i < B_G * 256) g[i] = 0.f;
}

// ---------------- per-graph CSR build (count+scan+fill, all in LDS, mapT-remapped) ----------------
__global__ __launch_bounds__(512) void csr_build(
        const int* __restrict__ es, const int* __restrict__ ed, const int* __restrict__ mapT,
        int* __restrict__ indptr, int* __restrict__ counts, int* __restrict__ srclist,
        int n_cur) {
    int b = blockIdx.x, tid = threadIdx.x;
    __shared__ int mloc[512];
    __shared__ int cnt[512];
    __shared__ int pref[512];
    __shared__ int curs[512];
    __shared__ uint epk[EPG];     // 16 KB packed edges
    mloc[tid] = mapT[b * N0 + tid];
    cnt[tid] = 0;
    __syncthreads();
    int base = b * EPG;
    int nb = b * n_cur;
    for (int i = tid; i < EPG; i += 512) {
        int s = es[base + i] & (N0 - 1);
        int d = ed[base + i] & (N0 - 1);
        int sg = mloc[s], dg = mloc[d];
        uint wv = 0xFFFFFFFFu;
        if ((sg | dg) >= 0) {
            int sl = sg - nb, dl = dg - nb;
            wv = (uint)sl | ((uint)dl << 16);
            atomicAdd(&cnt[dl], 1);
        }
        epk[i] = wv;
    }
    __syncthreads();
    pref[tid] = cnt[tid];
    __syncthreads();
    for (int off = 1; off < 512; off <<= 1) {
        int v = (tid >= off) ? pref[tid - off] : 0;
        __syncthreads();
        pref[tid] += v;
        __syncthreads();
    }
    int excl = tid ? pref[tid - 1] : 0;
    if (tid < n_cur) {
        indptr[nb + tid] = base + excl;
        counts[nb + tid] = cnt[tid];
    }
    curs[tid] = excl;
    __syncthreads();
    for (int i = tid; i < EPG; i += 512) {
        uint wv = epk[i];
        if (wv != 0xFFFFFFFFu) {
            int dl = wv >> 16;
            int pos = atomicAdd(&curs[dl], 1);
            srclist[base + pos] = (int)(wv & 0xFFFFu);
        }
    }
}

// ---------------- aggregation: per-(graph, channel-quarter) LDS-staged fp32 slab ----------------
// grid = 4*B_G blocks, 1024 thr (16 waves), dynamic LDS = n*32 floats (<=64 KB -> 2 blocks/CU).
// Lane layout: 8 node-groups x 8 lanes; each lane reads float4 (4 ch) per edge via ds_read_b128.
__global__ __launch_bounds__(1024) void aggregate(
        const uint* __restrict__ xp,
        const int* __restrict__ indptr, const int* __restrict__ counts,
        const int* __restrict__ srclist,
        uint* __restrict__ aggp, int n) {
    extern __shared__ float slab[];            // [n][32] fp32 (hi+lo combined)
    int b = blockIdx.x >> 2, q = blockIdx.x & 3;
    int tid = threadIdx.x;
    // stage: channels [32q, 32q+32) of every node, hi+lo combined to fp32
    for (int t = tid; t < n * 32; t += 1024) {
        int nd = t >> 5, ch = t & 31;
        uint u = xp[(size_t)(b * n + nd) * CCH + q * 32 + ch];
        slab[nd * 32 + ch] = unpk(u);
    }
    __syncthreads();
    int wave = tid >> 6, lane = tid & 63;
    int gl = lane >> 3;           // node slot within wave (0..7)
    int sub = lane & 7;           // float4 slot (4 channels)
    int ngroups = (n + 7) >> 3;
    for (int g = wave; g < ngroups; g += 16) {
        int d = g * 8 + gl;
        bool act = d < n;
        int beg = 0, cnt = 0;
        if (act) { beg = indptr[b * n + d]; cnt = counts[b * n + d]; }
        float4 acc = make_float4(0.f, 0.f, 0.f, 0.f);
        int id_next = (cnt > 0) ? srclist[beg] : 0;
        for (int j = 0; j < cnt; j++) {
            int id = id_next;
            if (j + 1 < cnt) id_next = srclist[beg + j + 1];
            const float4 v = *(const float4*)&slab[id * 32 + sub * 4];
            acc.x += v.x; acc.y += v.y; acc.z += v.z; acc.w += v.w;
        }
        if (act) {
            uint4 o;
            o.x = pksplit(acc.x); o.y = pksplit(acc.y);
            o.z = pksplit(acc.z); o.w = pksplit(acc.w);
            *(uint4*)&aggp[(size_t)(b * n + d) * CCH + q * 32 + sub * 4] = o;
        }
    }
}

// ---------------- bf16x3 MFMA transform + fused score (LDS-staged B) ----------------
//   h = relu([agg|x] @ [Wrel;Wroot] + brel) ; score = tanh(h.p/||p||)
// block = 512 thr (8 waves), 128 rows/block (16/wave), full 128 cols.
// B staged in LDS in two 32KB ks-halves; A loaded packed and unpacked in VALU.
__global__ __launch_bounds__(512, 4) void transform_mfma(
        const uint* __restrict__ aggp, const uint* __restrict__ xp,
        const ushort* __restrict__ Bph, const ushort* __restrict__ Bpl,
        const float* __restrict__ brel, const float* __restrict__ pvec,
        uint* __restrict__ hp, float* __restrict__ score) {
    __shared__ ushort ldsBh[16384];   // 32 KB: [4 ks][8 cf][64 lane][8]
    __shared__ ushort ldsBl[16384];   // 32 KB
    int tid = threadIdx.x;
    int wave = tid >> 6, lane = tid & 63;
    int r = lane & 15, kb = lane >> 4;
    int rows0 = blockIdx.x * 128 + wave * 16;

    f32x4 acc[8];
#pragma unroll
    for (int cf = 0; cf < 8; cf++) acc[cf] = (f32x4)(0.f);

    union U16 { uint u[4]; bf16x8 v; };

#pragma unroll
    for (int half = 0; half < 2; half++) {
        if (half) __syncthreads();
        // stage this ks-half of B (linear copy, 2048 uint4 per plane)
#pragma unroll
        for (int i = 0; i < 4; i++) {
            int idx = tid + i * 512;
            ((uint4*)ldsBh)[idx] = ((const uint4*)(Bph + half * 16384))[idx];
            ((uint4*)ldsBl)[idx] = ((const uint4*)(Bpl + half * 16384))[idx];
        }
        __syncthreads();
        const uint* A = half ? xp : aggp;
#pragma unroll
        for (int ks4 = 0; ks4 < 4; ks4++) {
            size_t rowbase = (size_t)(rows0 + r) * CCH + ks4 * 32 + kb * 8;
            uint4 ua = *(const uint4*)&A[rowbase];
            uint4 ub = *(const uint4*)&A[rowbase + 4];
            U16 ah, al;
            ah.u[0] = (ua.x & 0xffffu) | (ua.y << 16);
            ah.u[1] = (ua.z & 0xffffu) | (ua.w << 16);
            ah.u[2] = (ub.x & 0xffffu) | (ub.y << 16);
            ah.u[3] = (ub.z & 0xffffu) | (ub.w << 16);
            al.u[0] = (ua.x >> 16) | (ua.y & 0xffff0000u);
            al.u[1] = (ua.z >> 16) | (ua.w & 0xffff0000u);
            al.u[2] = (ub.x >> 16) | (ub.y & 0xffff0000u);
            al.u[3] = (ub.z >> 16) | (ub.w & 0xffff0000u);
#pragma unroll
            for (int cf = 0; cf < 8; cf++) {
                bf16x8 bh = *(const bf16x8*)&ldsBh[((ks4 * 8 + cf) * 64 + lane) * 8];
                bf16x8 bl = *(const bf16x8*)&ldsBl[((ks4 * 8 + cf) * 64 + lane) * 8];
                acc[cf] = __builtin_amdgcn_mfma_f32_16x16x32_bf16(ah.v, bl, acc[cf], 0, 0, 0);
                acc[cf] = __builtin_amdgcn_mfma_f32_16x16x32_bf16(al.v, bh, acc[cf], 0, 0, 0);
                acc[cf] = __builtin_amdgcn_mfma_f32_16x16x32_bf16(ah.v, bh, acc[cf], 0, 0, 0);
            }
        }
    }

    // epilogue: bias+relu (fp32), packed store, fused score
    float pv[8], bb[8], q = 0.f;
#pragma unroll
    for (int cf = 0; cf < 8; cf++) {
        pv[cf] = pvec[cf * 16 + r];
        bb[cf] = brel[cf * 16 + r];
        q += pv[cf] * pv[cf];
    }
    float dots[4] = {0.f, 0.f, 0.f, 0.f};
#pragma unroll
    for (int cf = 0; cf < 8; cf++) {
#pragma unroll
        for (int reg = 0; reg < 4; reg++) {
            float v = acc[cf][reg] + bb[cf];
            v = v > 0.f ? v : 0.f;
            hp[(size_t)(rows0 + kb * 4 + reg) * CCH + cf * 16 + r] = pksplit(v);
            dots[reg] += v * pv[cf];
        }
    }
#pragma unroll
    for (int off = 1; off < 16; off <<= 1) {
        q += __shfl_xor(q, off);
#pragma unroll
        for (int reg = 0; reg < 4; reg++) dots[reg] += __shfl_xor(dots[reg], off);
    }
    if (r == 0) {
        float inv_norm = rsqrtf(q);
#pragma unroll
        for (int reg = 0; reg < 4; reg++)
            score[rows0 + kb * 4 + reg] = tanhf(dots[reg] * inv_norm);
    }
}

// ---------------- top-k per graph: bitonic sort of 512 packed keys ----------------
__global__ __launch_bounds__(256) void topk_kernel(const float* __restrict__ score,
                                                   int* __restrict__ inv,
                                                   int* __restrict__ kglob,
                                                   float* __restrict__ kval, int n, int k) {
    int b = blockIdx.x;
    __shared__ unsigned long long keys[512];
    int tid = threadIdx.x;
    for (int s = tid; s < 512; s += 256) {
        unsigned long long key = 0ull;   // sorts below all real scores
        if (s < n) {
            float v = score[b * n + s];
            unsigned u = __float_as_uint(v);
            u = (u & 0x80000000u) ? ~u : (u | 0x80000000u);   // orderable
            key = ((unsigned long long)u << 32) | (unsigned)(~s); // ties -> lower idx first
        }
        keys[s] = key;
    }
    __syncthreads();
    for (int kk2 = 2; kk2 <= 512; kk2 <<= 1) {
        for (int j = kk2 >> 1; j > 0; j >>= 1) {
            for (int s = tid; s < 512; s += 256) {
                int sxj = s ^ j;
                if (sxj > s) {
                    unsigned long long a = keys[s], c = keys[sxj];
                    bool descRegion = ((s & kk2) == 0);
                    bool doSwap = descRegion ? (a < c) : (a > c);
                    if (doSwap) { keys[s] = c; keys[sxj] = a; }
                }
            }
            __syncthreads();
        }
    }
    for (int j = tid; j < k; j += 256) {
        unsigned long long key = keys[j];
        int node = (int)(~(unsigned)key);
        float v = score[b * n + node];
        int newid = b * k + j;
        kglob[newid] = b * n + node;
        kval[newid] = v;
        inv[b * n + node] = newid;
    }
}

// ---------------- gather+scale kept rows (packed -> packed) ----------------
__global__ void gather_kernel(const uint* __restrict__ hp, const int* __restrict__ kglob,
                              const float* __restrict__ kval, uint* __restrict__ xp, int nk) {
    int wid = (blockIdx.x * 256 + threadIdx.x) >> 6;
    int lane = threadIdx.x & 63;
    if (wid >= nk) return;
    int gsrc = kglob[wid];
    float v = kval[wid];
    uint2 u = ((const uint2*)(hp + (size_t)gsrc * CCH))[lane];
    uint2 o;
    o.x = pksplit(unpk(u.x) * v);
    o.y = pksplit(unpk(u.y) * v);
    ((uint2*)(xp + (size_t)wid * CCH))[lane] = o;
}

// ---------------- compose mapT through this layer's inv; reset other inv buffer ----------------
__global__ void compose_map(int* __restrict__ mapT, const int* __restrict__ invA,
                            int* __restrict__ invB, int bk) {
    int i = blockIdx.x * 256 + threadIdx.x;
    if (i < B_G * N0) {
        int m = mapT[i];
        mapT[i] = (m >= 0) ? invA[m] : -1;
    }
    if (i < bk) invB[i] = -1;
}

// ---------------- readout: gmp || gap (packed input), accumulated into g ----------------
__global__ __launch_bounds__(512) void readout_kernel(const uint* __restrict__ xp,
                                                      float* __restrict__ g, int k) {
    int b = blockIdx.x;
    int c = threadIdx.x & 127;
    int q = threadIdx.x >> 7;
    float mx = -1e30f, sm = 0.f;
    for (int j = q; j < k; j += 4) {
        float v = unpk(xp[((size_t)b * k + j) * CCH + c]);
        mx = fmaxf(mx, v); sm += v;
    }
    __shared__ float smx[4][128], ssm[4][128];
    smx[q][c] = mx; ssm[q][c] = sm;
    __syncthreads();
    if (q == 0) {
        mx = fmaxf(fmaxf(smx[0][c], smx[1][c]), fmaxf(smx[2][c], smx[3][c]));
        sm = ssm[0][c] + ssm[1][c] + ssm[2][c] + ssm[3][c];
        g[b * 256 + c] += mx;
        g[b * 256 + 128 + c] += sm / (float)k;
    }
}

// ---------------- final MLP + log_softmax ----------------
__global__ __launch_bounds__(128) void mlp_kernel(const float* __restrict__ g,
        const float* __restrict__ W1, const float* __restrict__ b1,
        const float* __restrict__ W2, const float* __restrict__ b2,
        const float* __restrict__ W3, const float* __restrict__ b3,
        float* __restrict__ out) {
    int b = blockIdx.x, t = threadIdx.x;
    __shared__ float gs[256], h1[128], h2[64], lg[10];
    gs[t] = g[b * 256 + t];
    gs[128 + t] = g[b * 256 + 128 + t];
    __syncthreads();
    {
        float a = b1[t];
        for (int c = 0; c < 256; c++) a += gs[c] * W1[c * 128 + t];
        h1[t] = fmaxf(a, 0.f);
    }
    __syncthreads();
    if (t < 64) {
        float a = b2[t];
        for (int c = 0; c < 128; c++) a += h1[c] * W2[c * 64 + t];
        h2[t] = fmaxf(a, 0.f);
    }
    __syncthreads();
    if (t < 10) {
        float a = b3[t];
        for (int c = 0; c < 64; c++) a += h2[c] * W3[c * 10 + t];
        lg[t] = a;
    }
    __syncthreads();
    if (t < 10) {
        float m = lg[0];
        for (int i = 1; i < 10; i++) m = fmaxf(m, lg[i]);
        float s = 0.f;
        for (int i = 0; i < 10; i++) s += expf(lg[i] - m);
        out[b * 10 + t] = lg[t] - m - logf(s);
    }
}

// ---------------- host ----------------
extern "C" void kernel_launch(void* const* d_in, const int* in_sizes, int n_in,
                              void* d_out, int out_size, void* d_ws, size_t ws_size,
                              hipStream_t stream) {
    (void)in_sizes; (void)n_in; (void)out_size; (void)ws_size;
    const float* x0 = (const float*)d_in[0];
    const int* es = (const int*)d_in[1];
    const int* ed = (const int*)d_in[2];
    const float* Wroot[3] = {(const float*)d_in[3], (const float*)d_in[7], (const float*)d_in[11]};
    const float* Wrel[3]  = {(const float*)d_in[4], (const float*)d_in[8], (const float*)d_in[12]};
    const float* brel[3]  = {(const float*)d_in[5], (const float*)d_in[9], (const float*)d_in[13]};
    const float* pvec[3]  = {(const float*)d_in[6], (const float*)d_in[10], (const float*)d_in[14]};
    const float* W1 = (const float*)d_in[15];
    const float* b1 = (const float*)d_in[16];
    const float* W2 = (const float*)d_in[17];
    const float* b2 = (const float*)d_in[18];
    const float* W3 = (const float*)d_in[19];
    const float* b3 = (const float*)d_in[20];

    size_t off = 0;
    char* base = (char*)d_ws;
    auto alloc = [&](size_t bytes) -> void* {
        void* p = base + off;
        off += (bytes + 255) & ~(size_t)255;
        return p;
    };
    const size_t FEATP = (size_t)(B_G * N0) * CCH * 4;   // packed uint plane
    uint* xp   = (uint*)alloc(FEATP);    // layer-input features (packed)
    uint* aggp = (uint*)alloc(FEATP);    // aggregation, overwritten by h (packed)
    ushort* Bph = (ushort*)alloc((size_t)3 * 32768 * 2); // packed weights hi
    ushort* Bpl = (ushort*)alloc((size_t)3 * 32768 * 2); // packed weights lo
    int* mapT   = (int*)alloc((size_t)(B_G * N0) * 4);   // orig node -> current id / -1
    int* counts = (int*)alloc((size_t)(B_G * N0) * 4);
    int* indptr = (int*)alloc((size_t)(B_G * N0) * 4);
    int* srclist = (int*)alloc((size_t)E_TOTAL * 4);
    float* score = (float*)alloc((size_t)(B_G * N0) * 4);
    int* invbuf[2] = {(int*)alloc((size_t)(B_G * N0) * 4), (int*)alloc((size_t)(B_G * N0) * 4)};
    int* kglob = (int*)alloc((size_t)(B_G * K1) * 4);
    float* kval = (float*)alloc((size_t)(B_G * K1) * 4);
    float* g = (float*)alloc((size_t)B_G * 256 * 4);

    convert_x<<<(B_G * N0 * CCH / 4 + 255) / 256, 256, 0, stream>>>(x0, xp,
                                                                    B_G * N0 * CCH / 4);
    pack_weights<<<(3 * 32768 + 255) / 256, 256, 0, stream>>>(
        Wrel[0], Wroot[0], Wrel[1], Wroot[1], Wrel[2], Wroot[2], Bph, Bpl);
    init_all<<<(B_G * N0 + 255) / 256, 256, 0, stream>>>(mapT, invbuf[0], g);

    int nper[4] = {N0, K1, K2, K3};
    for (int l = 0; l < 3; l++) {
        int n = nper[l], k = nper[l + 1];
        int n_nodes = B_G * n;
        int nk = B_G * k;
        int* invA = invbuf[l & 1];
        int* invB = invbuf[(l + 1) & 1];
        csr_build<<<B_G, 512, 0, stream>>>(es, ed, mapT, indptr, counts, srclist, n);
        aggregate<<<4 * B_G, 1024, (size_t)n * 32 * 4, stream>>>(
            xp, indptr, counts, srclist, aggp, n);
        // h overwrites agg in place (reads of agg all precede epilogue writes)
        transform_mfma<<<n_nodes / 128, 512, 0, stream>>>(
            aggp, xp, Bph + (size_t)l * 32768, Bpl + (size_t)l * 32768,
            brel[l], pvec[l], aggp, score);
        topk_kernel<<<B_G, 256, 0, stream>>>(score, invA, kglob, kval, n, k);
        gather_kernel<<<(nk + 3) / 4, 256, 0, stream>>>(aggp, kglob, kval, xp, nk);
        readout_kernel<<<B_G, 512, 0, stream>>>(xp, g, k);
        if (l < 2)
            compose_map<<<(B_G * N0 + 255) / 256, 256, 0, stream>>>(mapT, invA, invB, B_G * k);
    }
    mlp_kernel<<<B_G, 128, 0, stream>>>(g, W1, b1, W2, b2, W3, b3, (float*)d_out);
}

// Round 9
// 264.340 us; speedup vs baseline: 1.8734x; 1.2864x over previous
//
#include <hip/hip_runtime.h>
#include <hip/hip_bf16.h>
#include <math.h>

#define B_G   128
#define N0    512
#define DEG   8
#define CCH   128
#define EPG   (N0*DEG)            // 4096 edges per graph (fixed slab)
#define E_TOTAL (B_G*EPG)
#define K1    410
#define K2    328
#define K3    263
#define NCLS  10

using bf16x8 = __attribute__((ext_vector_type(8))) __bf16;
using f32x4  = __attribute__((ext_vector_type(4))) float;
typedef unsigned short ushort;
typedef unsigned int uint;

__device__ __forceinline__ ushort f2b(float f) {
    uint u = __float_as_uint(f);
    u += 0x7fffu + ((u >> 16) & 1u);      // RNE
    return (ushort)(u >> 16);
}
__device__ __forceinline__ float b2f(ushort h) {
    return __uint_as_float(((uint)h) << 16);
}
// split fp32 -> (hi, lo) bf16 pair;  v ~= hi + lo  (error ~2^-17 rel)
__device__ __forceinline__ void split2(float v, ushort& hi, ushort& lo) {
    hi = f2b(v);
    lo = f2b(v - b2f(hi));
}
// packed channel word: hi | lo<<16
__device__ __forceinline__ uint pksplit(float v) {
    ushort h, l; split2(v, h, l);
    return (uint)h | ((uint)l << 16);
}
__device__ __forceinline__ float unpk(uint u) {
    return __uint_as_float(u << 16) + __uint_as_float(u & 0xffff0000u);
}

// ---------------- convert x0 fp32 -> packed uint (hi|lo<<16) per channel ----------------
__global__ void convert_x(const float* __restrict__ x0, uint* __restrict__ xp, int n4) {
    int i = blockIdx.x * 256 + threadIdx.x;   // one float4 per thread
    if (i >= n4) return;
    float4 v = ((const float4*)x0)[i];
    uint4 o;
    o.x = pksplit(v.x); o.y = pksplit(v.y); o.z = pksplit(v.z); o.w = pksplit(v.w);
    ((uint4*)xp)[i] = o;
}

// ---------------- pack weights into per-lane MFMA fragment layout (hi/lo) ----------------
// Bp[layer][ks][cf][lane][j] ; k = ks*32 + (lane>>4)*8 + j ; c = cf*16 + (lane&15)
__global__ void pack_weights(const float* __restrict__ Wrel0, const float* __restrict__ Wroot0,
                             const float* __restrict__ Wrel1, const float* __restrict__ Wroot1,
                             const float* __restrict__ Wrel2, const float* __restrict__ Wroot2,
                             ushort* __restrict__ Bph, ushort* __restrict__ Bpl) {
    int idx = blockIdx.x * 256 + threadIdx.x;
    if (idx >= 3 * 32768) return;
    int layer = idx >> 15, rem = idx & 32767;
    int j = rem & 7, lane = (rem >> 3) & 63, cf = (rem >> 9) & 7, ks = rem >> 12;
    int k = ks * 32 + (lane >> 4) * 8 + j;
    int c = cf * 16 + (lane & 15);
    const float* Wrel  = layer == 0 ? Wrel0  : layer == 1 ? Wrel1  : Wrel2;
    const float* Wroot = layer == 0 ? Wroot0 : layer == 1 ? Wroot1 : Wroot2;
    float v = (k < 128) ? Wrel[k * 128 + c] : Wroot[(k - 128) * 128 + c];
    ushort hi, lo; split2(v, hi, lo);
    Bph[idx] = hi; Bpl[idx] = lo;
}

// ---------------- init: mapT identity, g = 0 ----------------
__global__ void init_all(int* __restrict__ mapT, float* __restrict__ g) {
    int i = blockIdx.x * 256 + threadIdx.x;
    if (i < B_G * N0) mapT[i] = i;
    if (i < B_G * 256) g[i] = 0.f;
}

// ---------------- per-graph CSR build (count+scan+fill, all in LDS, mapT-remapped) ----------------
__global__ __launch_bounds__(512) void csr_build(
        const int* __restrict__ es, const int* __restrict__ ed, const int* __restrict__ mapT,
        int* __restrict__ indptr, int* __restrict__ counts, int* __restrict__ srclist,
        int n_cur) {
    int b = blockIdx.x, tid = threadIdx.x;
    __shared__ int mloc[512];
    __shared__ int cnt[512];
    __shared__ int pref[512];
    __shared__ int curs[512];
    __shared__ uint epk[EPG];     // 16 KB packed edges
    mloc[tid] = mapT[b * N0 + tid];
    cnt[tid] = 0;
    __syncthreads();
    int base = b * EPG;
    int nb = b * n_cur;
    for (int i = tid; i < EPG; i += 512) {
        int s = es[base + i] & (N0 - 1);
        int d = ed[base + i] & (N0 - 1);
        int sg = mloc[s], dg = mloc[d];
        uint wv = 0xFFFFFFFFu;
        if ((sg | dg) >= 0) {
            int sl = sg - nb, dl = dg - nb;
            wv = (uint)sl | ((uint)dl << 16);
            atomicAdd(&cnt[dl], 1);
        }
        epk[i] = wv;
    }
    __syncthreads();
    pref[tid] = cnt[tid];
    __syncthreads();
    for (int off = 1; off < 512; off <<= 1) {
        int v = (tid >= off) ? pref[tid - off] : 0;
        __syncthreads();
        pref[tid] += v;
        __syncthreads();
    }
    int excl = tid ? pref[tid - 1] : 0;
    if (tid < n_cur) {
        indptr[nb + tid] = base + excl;
        counts[nb + tid] = cnt[tid];
    }
    curs[tid] = excl;
    __syncthreads();
    for (int i = tid; i < EPG; i += 512) {
        uint wv = epk[i];
        if (wv != 0xFFFFFFFFu) {
            int dl = wv >> 16;
            int pos = atomicAdd(&curs[dl], 1);
            srclist[base + pos] = (int)(wv & 0xFFFFu);
        }
    }
}

// ---------------- aggregation: per-(graph, channel-quarter) LDS-staged fp32 slab ----------------
__global__ __launch_bounds__(1024) void aggregate(
        const uint* __restrict__ xp,
        const int* __restrict__ indptr, const int* __restrict__ counts,
        const int* __restrict__ srclist,
        uint* __restrict__ aggp, int n) {
    extern __shared__ float slab[];            // [n][32] fp32 (hi+lo combined)
    int b = blockIdx.x >> 2, q = blockIdx.x & 3;
    int tid = threadIdx.x;
    for (int t = tid; t < n * 32; t += 1024) {
        int nd = t >> 5, ch = t & 31;
        uint u = xp[(size_t)(b * n + nd) * CCH + q * 32 + ch];
        slab[nd * 32 + ch] = unpk(u);
    }
    __syncthreads();
    int wave = tid >> 6, lane = tid & 63;
    int gl = lane >> 3;           // node slot within wave (0..7)
    int sub = lane & 7;           // float4 slot (4 channels)
    int ngroups = (n + 7) >> 3;
    for (int g = wave; g < ngroups; g += 16) {
        int d = g * 8 + gl;
        bool act = d < n;
        int beg = 0, cnt = 0;
        if (act) { beg = indptr[b * n + d]; cnt = counts[b * n + d]; }
        float4 acc = make_float4(0.f, 0.f, 0.f, 0.f);
        int id_next = (cnt > 0) ? srclist[beg] : 0;
        for (int j = 0; j < cnt; j++) {
            int id = id_next;
            if (j + 1 < cnt) id_next = srclist[beg + j + 1];
            const float4 v = *(const float4*)&slab[id * 32 + sub * 4];
            acc.x += v.x; acc.y += v.y; acc.z += v.z; acc.w += v.w;
        }
        if (act) {
            uint4 o;
            o.x = pksplit(acc.x); o.y = pksplit(acc.y);
            o.z = pksplit(acc.z); o.w = pksplit(acc.w);
            *(uint4*)&aggp[(size_t)(b * n + d) * CCH + q * 32 + sub * 4] = o;
        }
    }
}

// ---------------- bf16x3 MFMA transform + fused score (LDS-staged B) ----------------
__global__ __launch_bounds__(512, 4) void transform_mfma(
        const uint* __restrict__ aggp, const uint* __restrict__ xp,
        const ushort* __restrict__ Bph, const ushort* __restrict__ Bpl,
        const float* __restrict__ brel, const float* __restrict__ pvec,
        uint* __restrict__ hp, float* __restrict__ score) {
    __shared__ ushort ldsBh[16384];   // 32 KB: [4 ks][8 cf][64 lane][8]
    __shared__ ushort ldsBl[16384];   // 32 KB
    int tid = threadIdx.x;
    int wave = tid >> 6, lane = tid & 63;
    int r = lane & 15, kb = lane >> 4;
    int rows0 = blockIdx.x * 128 + wave * 16;

    f32x4 acc[8];
#pragma unroll
    for (int cf = 0; cf < 8; cf++) acc[cf] = (f32x4)(0.f);

    union U16 { uint u[4]; bf16x8 v; };

#pragma unroll
    for (int half = 0; half < 2; half++) {
        if (half) __syncthreads();
#pragma unroll
        for (int i = 0; i < 4; i++) {
            int idx = tid + i * 512;
            ((uint4*)ldsBh)[idx] = ((const uint4*)(Bph + half * 16384))[idx];
            ((uint4*)ldsBl)[idx] = ((const uint4*)(Bpl + half * 16384))[idx];
        }
        __syncthreads();
        const uint* A = half ? xp : aggp;
#pragma unroll
        for (int ks4 = 0; ks4 < 4; ks4++) {
            size_t rowbase = (size_t)(rows0 + r) * CCH + ks4 * 32 + kb * 8;
            uint4 ua = *(const uint4*)&A[rowbase];
            uint4 ub = *(const uint4*)&A[rowbase + 4];
            U16 ah, al;
            ah.u[0] = (ua.x & 0xffffu) | (ua.y << 16);
            ah.u[1] = (ua.z & 0xffffu) | (ua.w << 16);
            ah.u[2] = (ub.x & 0xffffu) | (ub.y << 16);
            ah.u[3] = (ub.z & 0xffffu) | (ub.w << 16);
            al.u[0] = (ua.x >> 16) | (ua.y & 0xffff0000u);
            al.u[1] = (ua.z >> 16) | (ua.w & 0xffff0000u);
            al.u[2] = (ub.x >> 16) | (ub.y & 0xffff0000u);
            al.u[3] = (ub.z >> 16) | (ub.w & 0xffff0000u);
#pragma unroll
            for (int cf = 0; cf < 8; cf++) {
                bf16x8 bh = *(const bf16x8*)&ldsBh[((ks4 * 8 + cf) * 64 + lane) * 8];
                bf16x8 bl = *(const bf16x8*)&ldsBl[((ks4 * 8 + cf) * 64 + lane) * 8];
                acc[cf] = __builtin_amdgcn_mfma_f32_16x16x32_bf16(ah.v, bl, acc[cf], 0, 0, 0);
                acc[cf] = __builtin_amdgcn_mfma_f32_16x16x32_bf16(al.v, bh, acc[cf], 0, 0, 0);
                acc[cf] = __builtin_amdgcn_mfma_f32_16x16x32_bf16(ah.v, bh, acc[cf], 0, 0, 0);
            }
        }
    }

    // epilogue: bias+relu (fp32), packed store, fused score
    float pv[8], bb[8], q = 0.f;
#pragma unroll
    for (int cf = 0; cf < 8; cf++) {
        pv[cf] = pvec[cf * 16 + r];
        bb[cf] = brel[cf * 16 + r];
        q += pv[cf] * pv[cf];
    }
    float dots[4] = {0.f, 0.f, 0.f, 0.f};
#pragma unroll
    for (int cf = 0; cf < 8; cf++) {
#pragma unroll
        for (int reg = 0; reg < 4; reg++) {
            float v = acc[cf][reg] + bb[cf];
            v = v > 0.f ? v : 0.f;
            hp[(size_t)(rows0 + kb * 4 + reg) * CCH + cf * 16 + r] = pksplit(v);
            dots[reg] += v * pv[cf];
        }
    }
#pragma unroll
    for (int off = 1; off < 16; off <<= 1) {
        q += __shfl_xor(q, off);
#pragma unroll
        for (int reg = 0; reg < 4; reg++) dots[reg] += __shfl_xor(dots[reg], off);
    }
    if (r == 0) {
        float inv_norm = rsqrtf(q);
#pragma unroll
        for (int reg = 0; reg < 4; reg++)
            score[rows0 + kb * 4 + reg] = tanhf(dots[reg] * inv_norm);
    }
}

// ---------------- fused pool: topk sort + gather/scale + readout + mapT update ----------------
// one block per graph, 512 threads (8 waves)
__global__ __launch_bounds__(512) void pool_kernel(
        const float* __restrict__ score, const uint* __restrict__ hp,
        uint* __restrict__ xp, float* __restrict__ g, int* __restrict__ mapT,
        int n, int k, int last) {
    int b = blockIdx.x, tid = threadIdx.x;
    __shared__ unsigned long long keys[512];
    __shared__ short invl[512];
    __shared__ float wmax[8][128], wsum[8][128];
    // load keys (orderable-transformed score, tie -> lower idx first)
    {
        unsigned long long key = 0ull;   // sorts below all real scores
        if (tid < n) {
            uint u = __float_as_uint(score[b * n + tid]);
            u = (u & 0x80000000u) ? ~u : (u | 0x80000000u);
            key = ((unsigned long long)u << 32) | (uint)(~tid);
        }
        keys[tid] = key;
        invl[tid] = -1;
    }
    __syncthreads();
    // bitonic sort, descending
    for (int kk2 = 2; kk2 <= 512; kk2 <<= 1) {
        for (int j = kk2 >> 1; j > 0; j >>= 1) {
            int s = tid, sxj = s ^ j;
            if (sxj > s) {
                unsigned long long a = keys[s], c = keys[sxj];
                bool doSwap = ((s & kk2) == 0) ? (a < c) : (a > c);
                if (doSwap) { keys[s] = c; keys[sxj] = a; }
            }
            __syncthreads();
        }
    }
    // build local inverse map
    if (tid < k) {
        int node = (int)(~(uint)keys[tid]);
        invl[node] = (short)tid;
    }
    __syncthreads();
    // gather+scale rows, accumulate readout partials per wave
    int wave = tid >> 6, lane = tid & 63;
    float mx0 = -1e30f, mx1 = -1e30f, sm0 = 0.f, sm1 = 0.f;
    for (int j = wave; j < k; j += 8) {
        unsigned long long key = keys[j];
        int node = (int)(~(uint)key);
        uint tu = (uint)(key >> 32);   // decode score (inverse orderable transform)
        uint su = (tu & 0x80000000u) ? (tu & 0x7fffffffu) : ~tu;
        float v = __uint_as_float(su);
        uint2 u = ((const uint2*)(hp + (size_t)(b * n + node) * CCH))[lane];
        float c0 = unpk(u.x) * v;
        float c1 = unpk(u.y) * v;
        ((uint2*)(xp + (size_t)(b * k + j) * CCH))[lane] = make_uint2(pksplit(c0), pksplit(c1));
        mx0 = fmaxf(mx0, c0); sm0 += c0;
        mx1 = fmaxf(mx1, c1); sm1 += c1;
    }
    wmax[wave][2 * lane] = mx0; wmax[wave][2 * lane + 1] = mx1;
    wsum[wave][2 * lane] = sm0; wsum[wave][2 * lane + 1] = sm1;
    __syncthreads();
    if (tid < 128) {
        float m = wmax[0][tid], s = wsum[0][tid];
#pragma unroll
        for (int w = 1; w < 8; w++) { m = fmaxf(m, wmax[w][tid]); s += wsum[w][tid]; }
        g[b * 256 + tid] += m;
        g[b * 256 + 128 + tid] += s / (float)k;
    }
    // compose mapT through this pooling (orig node slots)
    if (!last) {
        int m = mapT[b * N0 + tid];
        int res = -1;
        if (m >= 0) {
            int nl = invl[m - b * n];
            if (nl >= 0) res = b * k + nl;
        }
        mapT[b * N0 + tid] = res;
    }
}

// ---------------- final MLP + log_softmax ----------------
__global__ __launch_bounds__(128) void mlp_kernel(const float* __restrict__ g,
        const float* __restrict__ W1, const float* __restrict__ b1,
        const float* __restrict__ W2, const float* __restrict__ b2,
        const float* __restrict__ W3, const float* __restrict__ b3,
        float* __restrict__ out) {
    int b = blockIdx.x, t = threadIdx.x;
    __shared__ float gs[256], h1[128], h2[64], lg[10];
    gs[t] = g[b * 256 + t];
    gs[128 + t] = g[b * 256 + 128 + t];
    __syncthreads();
    {
        float a = b1[t];
        for (int c = 0; c < 256; c++) a += gs[c] * W1[c * 128 + t];
        h1[t] = fmaxf(a, 0.f);
    }
    __syncthreads();
    if (t < 64) {
        float a = b2[t];
        for (int c = 0; c < 128; c++) a += h1[c] * W2[c * 64 + t];
        h2[t] = fmaxf(a, 0.f);
    }
    __syncthreads();
    if (t < 10) {
        float a = b3[t];
        for (int c = 0; c < 64; c++) a += h2[c] * W3[c * 10 + t];
        lg[t] = a;
    }
    __syncthreads();
    if (t < 10) {
        float m = lg[0];
        for (int i = 1; i < 10; i++) m = fmaxf(m, lg[i]);
        float s = 0.f;
        for (int i = 0; i < 10; i++) s += expf(lg[i] - m);
        out[b * 10 + t] = lg[t] - m - logf(s);
    }
}

// ---------------- host ----------------
extern "C" void kernel_launch(void* const* d_in, const int* in_sizes, int n_in,
                              void* d_out, int out_size, void* d_ws, size_t ws_size,
                              hipStream_t stream) {
    (void)in_sizes; (void)n_in; (void)out_size; (void)ws_size;
    const float* x0 = (const float*)d_in[0];
    const int* es = (const int*)d_in[1];
    const int* ed = (const int*)d_in[2];
    const float* Wroot[3] = {(const float*)d_in[3], (const float*)d_in[7], (const float*)d_in[11]};
    const float* Wrel[3]  = {(const float*)d_in[4], (const float*)d_in[8], (const float*)d_in[12]};
    const float* brel[3]  = {(const float*)d_in[5], (const float*)d_in[9], (const float*)d_in[13]};
    const float* pvec[3]  = {(const float*)d_in[6], (const float*)d_in[10], (const float*)d_in[14]};
    const float* W1 = (const float*)d_in[15];
    const float* b1 = (const float*)d_in[16];
    const float* W2 = (const float*)d_in[17];
    const float* b2 = (const float*)d_in[18];
    const float* W3 = (const float*)d_in[19];
    const float* b3 = (const float*)d_in[20];

    size_t off = 0;
    char* base = (char*)d_ws;
    auto alloc = [&](size_t bytes) -> void* {
        void* p = base + off;
        off += (bytes + 255) & ~(size_t)255;
        return p;
    };
    const size_t FEATP = (size_t)(B_G * N0) * CCH * 4;   // packed uint plane
    uint* xp   = (uint*)alloc(FEATP);    // layer-input features (packed)
    uint* aggp = (uint*)alloc(FEATP);    // aggregation, overwritten by h (packed)
    ushort* Bph = (ushort*)alloc((size_t)3 * 32768 * 2); // packed weights hi
    ushort* Bpl = (ushort*)alloc((size_t)3 * 32768 * 2); // packed weights lo
    int* mapT   = (int*)alloc((size_t)(B_G * N0) * 4);   // orig node -> current id / -1
    int* counts = (int*)alloc((size_t)(B_G * N0) * 4);
    int* indptr = (int*)alloc((size_t)(B_G * N0) * 4);
    int* srclist = (int*)alloc((size_t)E_TOTAL * 4);
    float* score = (float*)alloc((size_t)(B_G * N0) * 4);
    float* g = (float*)alloc((size_t)B_G * 256 * 4);

    convert_x<<<(B_G * N0 * CCH / 4 + 255) / 256, 256, 0, stream>>>(x0, xp,
                                                                    B_G * N0 * CCH / 4);
    pack_weights<<<(3 * 32768 + 255) / 256, 256, 0, stream>>>(
        Wrel[0], Wroot[0], Wrel[1], Wroot[1], Wrel[2], Wroot[2], Bph, Bpl);
    init_all<<<(B_G * N0 + 255) / 256, 256, 0, stream>>>(mapT, g);

    int nper[4] = {N0, K1, K2, K3};
    for (int l = 0; l < 3; l++) {
        int n = nper[l], k = nper[l + 1];
        int n_nodes = B_G * n;
        csr_build<<<B_G, 512, 0, stream>>>(es, ed, mapT, indptr, counts, srclist, n);
        aggregate<<<4 * B_G, 1024, (size_t)n * 32 * 4, stream>>>(
            xp, indptr, counts, srclist, aggp, n);
        transform_mfma<<<n_nodes / 128, 512, 0, stream>>>(
            aggp, xp, Bph + (size_t)l * 32768, Bpl + (size_t)l * 32768,
            brel[l], pvec[l], aggp, score);
        pool_kernel<<<B_G, 512, 0, stream>>>(score, aggp, xp, g, mapT, n, k, l == 2);
    }
    mlp_kernel<<<B_G, 128, 0, stream>>>(g, W1, b1, W2, b2, W3, b3, (float*)d_out);
}

// Round 10
// 234.525 us; speedup vs baseline: 2.1116x; 1.1271x over previous
//
#include <hip/hip_runtime.h>
#include <hip/hip_bf16.h>
#include <math.h>

#define B_G   128
#define N0    512
#define DEG   8
#define CCH   128
#define EPG   (N0*DEG)            // 4096 edges per graph (fixed slab)
#define E_TOTAL (B_G*EPG)
#define K1    410
#define K2    328
#define K3    263
#define NCLS  10

using bf16x8 = __attribute__((ext_vector_type(8))) __bf16;
using f32x4  = __attribute__((ext_vector_type(4))) float;
typedef unsigned short ushort;
typedef unsigned int uint;

__device__ __forceinline__ ushort f2b(float f) {
    uint u = __float_as_uint(f);
    u += 0x7fffu + ((u >> 16) & 1u);      // RNE
    return (ushort)(u >> 16);
}
__device__ __forceinline__ float b2f(ushort h) {
    return __uint_as_float(((uint)h) << 16);
}
// split fp32 -> (hi, lo) bf16 pair;  v ~= hi + lo  (error ~2^-17 rel)
__device__ __forceinline__ void split2(float v, ushort& hi, ushort& lo) {
    hi = f2b(v);
    lo = f2b(v - b2f(hi));
}
// packed channel word: hi | lo<<16
__device__ __forceinline__ uint pksplit(float v) {
    ushort h, l; split2(v, h, l);
    return (uint)h | ((uint)l << 16);
}
__device__ __forceinline__ float unpk(uint u) {
    return __uint_as_float(u << 16) + __uint_as_float(u & 0xffff0000u);
}

// ---------------- convert x0 fp32 -> packed uint (hi|lo<<16) per channel ----------------
__global__ void convert_x(const float* __restrict__ x0, uint* __restrict__ xp, int n4) {
    int i = blockIdx.x * 256 + threadIdx.x;   // one float4 per thread
    if (i >= n4) return;
    float4 v = ((const float4*)x0)[i];
    uint4 o;
    o.x = pksplit(v.x); o.y = pksplit(v.y); o.z = pksplit(v.z); o.w = pksplit(v.w);
    ((uint4*)xp)[i] = o;
}

// ---------------- pack weights into per-lane MFMA fragment layout (hi/lo) ----------------
// Bp[layer][ks][cf][lane][j] ; k = ks*32 + (lane>>4)*8 + j ; c = cf*16 + (lane&15)
__global__ void pack_weights(const float* __restrict__ Wrel0, const float* __restrict__ Wroot0,
                             const float* __restrict__ Wrel1, const float* __restrict__ Wroot1,
                             const float* __restrict__ Wrel2, const float* __restrict__ Wroot2,
                             ushort* __restrict__ Bph, ushort* __restrict__ Bpl) {
    int idx = blockIdx.x * 256 + threadIdx.x;
    if (idx >= 3 * 32768) return;
    int layer = idx >> 15, rem = idx & 32767;
    int j = rem & 7, lane = (rem >> 3) & 63, cf = (rem >> 9) & 7, ks = rem >> 12;
    int k = ks * 32 + (lane >> 4) * 8 + j;
    int c = cf * 16 + (lane & 15);
    const float* Wrel  = layer == 0 ? Wrel0  : layer == 1 ? Wrel1  : Wrel2;
    const float* Wroot = layer == 0 ? Wroot0 : layer == 1 ? Wroot1 : Wroot2;
    float v = (k < 128) ? Wrel[k * 128 + c] : Wroot[(k - 128) * 128 + c];
    ushort hi, lo; split2(v, hi, lo);
    Bph[idx] = hi; Bpl[idx] = lo;
}

// ---------------- init: mapT identity, gpart = 0 ----------------
__global__ void init_all(int* __restrict__ mapT, float* __restrict__ gpart) {
    int i = blockIdx.x * 256 + threadIdx.x;
    if (i < B_G * N0) mapT[i] = i;
    if (i < 3 * 4 * B_G * 256) gpart[i] = 0.f;
}

// ---------------- per-graph CSR build (count+scan+fill, all in LDS, mapT-remapped) ----------------
__global__ __launch_bounds__(512) void csr_build(
        const int* __restrict__ es, const int* __restrict__ ed, const int* __restrict__ mapT,
        int* __restrict__ indptr, int* __restrict__ counts, int* __restrict__ srclist,
        int n_cur) {
    int b = blockIdx.x, tid = threadIdx.x;
    __shared__ int mloc[512];
    __shared__ int cnt[512];
    __shared__ int pref[512];
    __shared__ int curs[512];
    __shared__ uint epk[EPG];     // 16 KB packed edges
    mloc[tid] = mapT[b * N0 + tid];
    cnt[tid] = 0;
    __syncthreads();
    int base = b * EPG;
    int nb = b * n_cur;
    for (int i = tid; i < EPG; i += 512) {
        int s = es[base + i] & (N0 - 1);
        int d = ed[base + i] & (N0 - 1);
        int sg = mloc[s], dg = mloc[d];
        uint wv = 0xFFFFFFFFu;
        if ((sg | dg) >= 0) {
            int sl = sg - nb, dl = dg - nb;
            wv = (uint)sl | ((uint)dl << 16);
            atomicAdd(&cnt[dl], 1);
        }
        epk[i] = wv;
    }
    __syncthreads();
    pref[tid] = cnt[tid];
    __syncthreads();
    for (int off = 1; off < 512; off <<= 1) {
        int v = (tid >= off) ? pref[tid - off] : 0;
        __syncthreads();
        pref[tid] += v;
        __syncthreads();
    }
    int excl = tid ? pref[tid - 1] : 0;
    if (tid < n_cur) {
        indptr[nb + tid] = base + excl;
        counts[nb + tid] = cnt[tid];
    }
    curs[tid] = excl;
    __syncthreads();
    for (int i = tid; i < EPG; i += 512) {
        uint wv = epk[i];
        if (wv != 0xFFFFFFFFu) {
            int dl = wv >> 16;
            int pos = atomicAdd(&curs[dl], 1);
            srclist[base + pos] = (int)(wv & 0xFFFFu);
        }
    }
}

// ---------------- aggregation: per-(graph, channel-quarter) LDS-staged fp32 slab ----------------
__global__ __launch_bounds__(1024) void aggregate(
        const uint* __restrict__ xp,
        const int* __restrict__ indptr, const int* __restrict__ counts,
        const int* __restrict__ srclist,
        uint* __restrict__ aggp, int n) {
    extern __shared__ float slab[];            // [n][32] fp32 (hi+lo combined)
    int b = blockIdx.x >> 2, q = blockIdx.x & 3;
    int tid = threadIdx.x;
    for (int t = tid; t < n * 32; t += 1024) {
        int nd = t >> 5, ch = t & 31;
        uint u = xp[(size_t)(b * n + nd) * CCH + q * 32 + ch];
        slab[nd * 32 + ch] = unpk(u);
    }
    __syncthreads();
    int wave = tid >> 6, lane = tid & 63;
    int gl = lane >> 3;           // node slot within wave (0..7)
    int sub = lane & 7;           // float4 slot (4 channels)
    int ngroups = (n + 7) >> 3;
    for (int g = wave; g < ngroups; g += 16) {
        int d = g * 8 + gl;
        bool act = d < n;
        int beg = 0, cnt = 0;
        if (act) { beg = indptr[b * n + d]; cnt = counts[b * n + d]; }
        float4 acc = make_float4(0.f, 0.f, 0.f, 0.f);
        int id_next = (cnt > 0) ? srclist[beg] : 0;
        for (int j = 0; j < cnt; j++) {
            int id = id_next;
            if (j + 1 < cnt) id_next = srclist[beg + j + 1];
            const float4 v = *(const float4*)&slab[id * 32 + sub * 4];
            acc.x += v.x; acc.y += v.y; acc.z += v.z; acc.w += v.w;
        }
        if (act) {
            uint4 o;
            o.x = pksplit(acc.x); o.y = pksplit(acc.y);
            o.z = pksplit(acc.z); o.w = pksplit(acc.w);
            *(uint4*)&aggp[(size_t)(b * n + d) * CCH + q * 32 + sub * 4] = o;
        }
    }
}

// ---------------- bf16x3 MFMA transform + fused score (LDS-staged B) ----------------
__global__ __launch_bounds__(512, 4) void transform_mfma(
        const uint* __restrict__ aggp, const uint* __restrict__ xp,
        const ushort* __restrict__ Bph, const ushort* __restrict__ Bpl,
        const float* __restrict__ brel, const float* __restrict__ pvec,
        uint* __restrict__ hp, float* __restrict__ score) {
    __shared__ ushort ldsBh[16384];   // 32 KB: [4 ks][8 cf][64 lane][8]
    __shared__ ushort ldsBl[16384];   // 32 KB
    int tid = threadIdx.x;
    int wave = tid >> 6, lane = tid & 63;
    int r = lane & 15, kb = lane >> 4;
    int rows0 = blockIdx.x * 128 + wave * 16;

    f32x4 acc[8];
#pragma unroll
    for (int cf = 0; cf < 8; cf++) acc[cf] = (f32x4)(0.f);

    union U16 { uint u[4]; bf16x8 v; };

#pragma unroll
    for (int half = 0; half < 2; half++) {
        if (half) __syncthreads();
#pragma unroll
        for (int i = 0; i < 4; i++) {
            int idx = tid + i * 512;
            ((uint4*)ldsBh)[idx] = ((const uint4*)(Bph + half * 16384))[idx];
            ((uint4*)ldsBl)[idx] = ((const uint4*)(Bpl + half * 16384))[idx];
        }
        __syncthreads();
        const uint* A = half ? xp : aggp;
#pragma unroll
        for (int ks4 = 0; ks4 < 4; ks4++) {
            size_t rowbase = (size_t)(rows0 + r) * CCH + ks4 * 32 + kb * 8;
            uint4 ua = *(const uint4*)&A[rowbase];
            uint4 ub = *(const uint4*)&A[rowbase + 4];
            U16 ah, al;
            ah.u[0] = (ua.x & 0xffffu) | (ua.y << 16);
            ah.u[1] = (ua.z & 0xffffu) | (ua.w << 16);
            ah.u[2] = (ub.x & 0xffffu) | (ub.y << 16);
            ah.u[3] = (ub.z & 0xffffu) | (ub.w << 16);
            al.u[0] = (ua.x >> 16) | (ua.y & 0xffff0000u);
            al.u[1] = (ua.z >> 16) | (ua.w & 0xffff0000u);
            al.u[2] = (ub.x >> 16) | (ub.y & 0xffff0000u);
            al.u[3] = (ub.z >> 16) | (ub.w & 0xffff0000u);
#pragma unroll
            for (int cf = 0; cf < 8; cf++) {
                bf16x8 bh = *(const bf16x8*)&ldsBh[((ks4 * 8 + cf) * 64 + lane) * 8];
                bf16x8 bl = *(const bf16x8*)&ldsBl[((ks4 * 8 + cf) * 64 + lane) * 8];
                acc[cf] = __builtin_amdgcn_mfma_f32_16x16x32_bf16(ah.v, bl, acc[cf], 0, 0, 0);
                acc[cf] = __builtin_amdgcn_mfma_f32_16x16x32_bf16(al.v, bh, acc[cf], 0, 0, 0);
                acc[cf] = __builtin_amdgcn_mfma_f32_16x16x32_bf16(ah.v, bh, acc[cf], 0, 0, 0);
            }
        }
    }

    // epilogue: bias+relu (fp32), packed store, fused score
    float pv[8], bb[8], q = 0.f;
#pragma unroll
    for (int cf = 0; cf < 8; cf++) {
        pv[cf] = pvec[cf * 16 + r];
        bb[cf] = brel[cf * 16 + r];
        q += pv[cf] * pv[cf];
    }
    float dots[4] = {0.f, 0.f, 0.f, 0.f};
#pragma unroll
    for (int cf = 0; cf < 8; cf++) {
#pragma unroll
        for (int reg = 0; reg < 4; reg++) {
            float v = acc[cf][reg] + bb[cf];
            v = v > 0.f ? v : 0.f;
            hp[(size_t)(rows0 + kb * 4 + reg) * CCH + cf * 16 + r] = pksplit(v);
            dots[reg] += v * pv[cf];
        }
    }
#pragma unroll
    for (int off = 1; off < 16; off <<= 1) {
        q += __shfl_xor(q, off);
#pragma unroll
        for (int reg = 0; reg < 4; reg++) dots[reg] += __shfl_xor(dots[reg], off);
    }
    if (r == 0) {
        float inv_norm = rsqrtf(q);
#pragma unroll
        for (int reg = 0; reg < 4; reg++)
            score[rows0 + kb * 4 + reg] = tanhf(dots[reg] * inv_norm);
    }
}

// ---------------- fused pool (4 blocks/graph, redundant sort): ----------------
// topk bitonic sort (identical in all 4 blocks) + quarter gather/scale + readout partials
// + mapT update (q==0 block). gpart[layer][q][b][256] combined in mlp_kernel.
__global__ __launch_bounds__(512) void pool_kernel(
        const float* __restrict__ score, const uint* __restrict__ hp,
        uint* __restrict__ xp, float* __restrict__ gpart, int* __restrict__ mapT,
        int n, int k, int layer, int last) {
    int b = blockIdx.x >> 2, q = blockIdx.x & 3;
    int tid = threadIdx.x;
    __shared__ unsigned long long keys[512];
    __shared__ short invl[512];
    __shared__ float wmax[8][128], wsum[8][128];
    // load keys (orderable-transformed score, tie -> lower idx first)
    {
        unsigned long long key = 0ull;   // sorts below all real scores
        if (tid < n) {
            uint u = __float_as_uint(score[b * n + tid]);
            u = (u & 0x80000000u) ? ~u : (u | 0x80000000u);
            key = ((unsigned long long)u << 32) | (uint)(~tid);
        }
        keys[tid] = key;
        invl[tid] = -1;
    }
    __syncthreads();
    // bitonic sort, descending (deterministic -> identical across the 4 blocks)
    for (int kk2 = 2; kk2 <= 512; kk2 <<= 1) {
        for (int j = kk2 >> 1; j > 0; j >>= 1) {
            int s = tid, sxj = s ^ j;
            if (sxj > s) {
                unsigned long long a = keys[s], c = keys[sxj];
                bool doSwap = ((s & kk2) == 0) ? (a < c) : (a > c);
                if (doSwap) { keys[s] = c; keys[sxj] = a; }
            }
            __syncthreads();
        }
    }
    if (tid < k) {
        int node = (int)(~(uint)keys[tid]);
        invl[node] = (short)tid;
    }
    __syncthreads();
    // gather+scale rows j === q (mod 4), accumulate readout partials per wave
    int wave = tid >> 6, lane = tid & 63;
    float mx0 = -1e30f, mx1 = -1e30f, sm0 = 0.f, sm1 = 0.f;
    for (int j = q + 4 * wave; j < k; j += 32) {
        unsigned long long key = keys[j];
        int node = (int)(~(uint)key);
        uint tu = (uint)(key >> 32);   // decode score (inverse orderable transform)
        uint su = (tu & 0x80000000u) ? (tu & 0x7fffffffu) : ~tu;
        float v = __uint_as_float(su);
        uint2 u = ((const uint2*)(hp + (size_t)(b * n + node) * CCH))[lane];
        float c0 = unpk(u.x) * v;
        float c1 = unpk(u.y) * v;
        ((uint2*)(xp + (size_t)(b * k + j) * CCH))[lane] = make_uint2(pksplit(c0), pksplit(c1));
        mx0 = fmaxf(mx0, c0); sm0 += c0;
        mx1 = fmaxf(mx1, c1); sm1 += c1;
    }
    wmax[wave][2 * lane] = mx0; wmax[wave][2 * lane + 1] = mx1;
    wsum[wave][2 * lane] = sm0; wsum[wave][2 * lane + 1] = sm1;
    __syncthreads();
    if (tid < 128) {
        float m = wmax[0][tid], s = wsum[0][tid];
#pragma unroll
        for (int w = 1; w < 8; w++) { m = fmaxf(m, wmax[w][tid]); s += wsum[w][tid]; }
        float* gp = gpart + ((size_t)(layer * 4 + q) * B_G + b) * 256;
        gp[tid] = m;
        gp[128 + tid] = s;
    }
    // compose mapT through this pooling (orig node slots) -- q==0 block only
    if (!last && q == 0) {
        int m = mapT[b * N0 + tid];
        int res = -1;
        if (m >= 0) {
            int nl = invl[m - b * n];
            if (nl >= 0) res = b * k + nl;
        }
        mapT[b * N0 + tid] = res;
    }
}

// ---------------- final MLP + log_softmax (combines gpart quarters) ----------------
__global__ __launch_bounds__(128) void mlp_kernel(const float* __restrict__ gpart,
        const float* __restrict__ W1, const float* __restrict__ b1,
        const float* __restrict__ W2, const float* __restrict__ b2,
        const float* __restrict__ W3, const float* __restrict__ b3,
        float* __restrict__ out) {
    int b = blockIdx.x, t = threadIdx.x;
    __shared__ float gs[256], h1[128], h2[64], lg[10];
    const float kdiv[3] = {(float)K1, (float)K2, (float)K3};
    float a0 = 0.f, a1 = 0.f;
#pragma unroll
    for (int l = 0; l < 3; l++) {
        float m = -1e30f, s = 0.f;
#pragma unroll
        for (int q = 0; q < 4; q++) {
            const float* gp = gpart + ((size_t)(l * 4 + q) * B_G + b) * 256;
            m = fmaxf(m, gp[t]);
            s += gp[128 + t];
        }
        a0 += m;
        a1 += s / kdiv[l];
    }
    gs[t] = a0;
    gs[128 + t] = a1;
    __syncthreads();
    {
        float a = b1[t];
        for (int c = 0; c < 256; c++) a += gs[c] * W1[c * 128 + t];
        h1[t] = fmaxf(a, 0.f);
    }
    __syncthreads();
    if (t < 64) {
        float a = b2[t];
        for (int c = 0; c < 128; c++) a += h1[c] * W2[c * 64 + t];
        h2[t] = fmaxf(a, 0.f);
    }
    __syncthreads();
    if (t < 10) {
        float a = b3[t];
        for (int c = 0; c < 64; c++) a += h2[c] * W3[c * 10 + t];
        lg[t] = a;
    }
    __syncthreads();
    if (t < 10) {
        float m = lg[0];
        for (int i = 1; i < 10; i++) m = fmaxf(m, lg[i]);
        float s = 0.f;
        for (int i = 0; i < 10; i++) s += expf(lg[i] - m);
        out[b * 10 + t] = lg[t] - m - logf(s);
    }
}

// ---------------- host ----------------
extern "C" void kernel_launch(void* const* d_in, const int* in_sizes, int n_in,
                              void* d_out, int out_size, void* d_ws, size_t ws_size,
                              hipStream_t stream) {
    (void)in_sizes; (void)n_in; (void)out_size; (void)ws_size;
    const float* x0 = (const float*)d_in[0];
    const int* es = (const int*)d_in[1];
    const int* ed = (const int*)d_in[2];
    const float* Wroot[3] = {(const float*)d_in[3], (const float*)d_in[7], (const float*)d_in[11]};
    const float* Wrel[3]  = {(const float*)d_in[4], (const float*)d_in[8], (const float*)d_in[12]};
    const float* brel[3]  = {(const float*)d_in[5], (const float*)d_in[9], (const float*)d_in[13]};
    const float* pvec[3]  = {(const float*)d_in[6], (const float*)d_in[10], (const float*)d_in[14]};
    const float* W1 = (const float*)d_in[15];
    const float* b1 = (const float*)d_in[16];
    const float* W2 = (const float*)d_in[17];
    const float* b2 = (const float*)d_in[18];
    const float* W3 = (const float*)d_in[19];
    const float* b3 = (const float*)d_in[20];

    size_t off = 0;
    char* base = (char*)d_ws;
    auto alloc = [&](size_t bytes) -> void* {
        void* p = base + off;
        off += (bytes + 255) & ~(size_t)255;
        return p;
    };
    const size_t FEATP = (size_t)(B_G * N0) * CCH * 4;   // packed uint plane
    uint* xp   = (uint*)alloc(FEATP);    // layer-input features (packed)
    uint* aggp = (uint*)alloc(FEATP);    // aggregation, overwritten by h (packed)
    ushort* Bph = (ushort*)alloc((size_t)3 * 32768 * 2); // packed weights hi
    ushort* Bpl = (ushort*)alloc((size_t)3 * 32768 * 2); // packed weights lo
    int* mapT   = (int*)alloc((size_t)(B_G * N0) * 4);   // orig node -> current id / -1
    int* counts = (int*)alloc((size_t)(B_G * N0) * 4);
    int* indptr = (int*)alloc((size_t)(B_G * N0) * 4);
    int* srclist = (int*)alloc((size_t)E_TOTAL * 4);
    float* score = (float*)alloc((size_t)(B_G * N0) * 4);
    float* gpart = (float*)alloc((size_t)3 * 4 * B_G * 256 * 4);

    convert_x<<<(B_G * N0 * CCH / 4 + 255) / 256, 256, 0, stream>>>(x0, xp,
                                                                    B_G * N0 * CCH / 4);
    pack_weights<<<(3 * 32768 + 255) / 256, 256, 0, stream>>>(
        Wrel[0], Wroot[0], Wrel[1], Wroot[1], Wrel[2], Wroot[2], Bph, Bpl);
    init_all<<<(3 * 4 * B_G * 256 + 255) / 256, 256, 0, stream>>>(mapT, gpart);

    int nper[4] = {N0, K1, K2, K3};
    for (int l = 0; l < 3; l++) {
        int n = nper[l], k = nper[l + 1];
        int n_nodes = B_G * n;
        csr_build<<<B_G, 512, 0, stream>>>(es, ed, mapT, indptr, counts, srclist, n);
        aggregate<<<4 * B_G, 1024, (size_t)n * 32 * 4, stream>>>(
            xp, indptr, counts, srclist, aggp, n);
        transform_mfma<<<n_nodes / 128, 512, 0, stream>>>(
            aggp, xp, Bph + (size_t)l * 32768, Bpl + (size_t)l * 32768,
            brel[l], pvec[l], aggp, score);
        pool_kernel<<<4 * B_G, 512, 0, stream>>>(score, aggp, xp, gpart, mapT, n, k, l, l == 2);
    }
    mlp_kernel<<<B_G, 128, 0, stream>>>(gpart, W1, b1, W2, b2, W3, b3, (float*)d_out);
}

// Round 11
// 219.463 us; speedup vs baseline: 2.2565x; 1.0686x over previous
//
#include <hip/hip_runtime.h>
#include <hip/hip_bf16.h>
#include <math.h>

#define B_G   128
#define N0    512
#define DEG   8
#define CCH   128
#define EPG   (N0*DEG)            // 4096 edges per graph (fixed slab)
#define E_TOTAL (B_G*EPG)
#define K1    410
#define K2    328
#define K3    263
#define NCLS  10

using bf16x8 = __attribute__((ext_vector_type(8))) __bf16;
using f32x4  = __attribute__((ext_vector_type(4))) float;
typedef unsigned short ushort;
typedef unsigned int uint;

__device__ __forceinline__ ushort f2b(float f) {
    uint u = __float_as_uint(f);
    u += 0x7fffu + ((u >> 16) & 1u);      // RNE
    return (ushort)(u >> 16);
}
__device__ __forceinline__ float b2f(ushort h) {
    return __uint_as_float(((uint)h) << 16);
}
// split fp32 -> (hi, lo) bf16 pair;  v ~= hi + lo  (error ~2^-17 rel)
__device__ __forceinline__ void split2(float v, ushort& hi, ushort& lo) {
    hi = f2b(v);
    lo = f2b(v - b2f(hi));
}
// packed channel word: hi | lo<<16
__device__ __forceinline__ uint pksplit(float v) {
    ushort h, l; split2(v, h, l);
    return (uint)h | ((uint)l << 16);
}
__device__ __forceinline__ float unpk(uint u) {
    return __uint_as_float(u << 16) + __uint_as_float(u & 0xffff0000u);
}

// ---------------- prep: convert x0 -> packed plane; pack weights (fragment layout) ----------------
__global__ void prep_kernel(const float* __restrict__ x0, uint* __restrict__ xp, int n4,
                            const float* __restrict__ Wrel0, const float* __restrict__ Wroot0,
                            const float* __restrict__ Wrel1, const float* __restrict__ Wroot1,
                            const float* __restrict__ Wrel2, const float* __restrict__ Wroot2,
                            ushort* __restrict__ Bph, ushort* __restrict__ Bpl) {
    int i = blockIdx.x * 256 + threadIdx.x;
    if (i < n4) {
        float4 v = ((const float4*)x0)[i];
        uint4 o;
        o.x = pksplit(v.x); o.y = pksplit(v.y); o.z = pksplit(v.z); o.w = pksplit(v.w);
        ((uint4*)xp)[i] = o;
    }
    if (i < 3 * 32768) {
        int layer = i >> 15, rem = i & 32767;
        int j = rem & 7, lane = (rem >> 3) & 63, cf = (rem >> 9) & 7, ks = rem >> 12;
        int k = ks * 32 + (lane >> 4) * 8 + j;
        int c = cf * 16 + (lane & 15);
        const float* Wrel  = layer == 0 ? Wrel0  : layer == 1 ? Wrel1  : Wrel2;
        const float* Wroot = layer == 0 ? Wroot0 : layer == 1 ? Wroot1 : Wroot2;
        float v = (k < 128) ? Wrel[k * 128 + c] : Wroot[(k - 128) * 128 + c];
        ushort hi, lo; split2(v, hi, lo);
        Bph[i] = hi; Bpl[i] = lo;
    }
}

// ---------------- layer-0 CSR (identity map) + mapT identity init ----------------
__global__ __launch_bounds__(1024) void csr0_kernel(
        const int* __restrict__ es, const int* __restrict__ ed, int* __restrict__ mapT,
        int* __restrict__ indptr, int* __restrict__ counts, int* __restrict__ srclist) {
    int b = blockIdx.x, tid = threadIdx.x;
    __shared__ uint epk[EPG];     // 16 KB
    __shared__ int cnt[512], pref[512], curs[512];
    if (tid < 512) { cnt[tid] = 0; mapT[b * N0 + tid] = b * N0 + tid; }
    __syncthreads();
    int base = b * EPG;
    for (int i = tid; i < EPG; i += 1024) {
        int s = es[base + i] & (N0 - 1);
        int d = ed[base + i] & (N0 - 1);
        epk[i] = (uint)s | ((uint)d << 16);
        atomicAdd(&cnt[d], 1);
    }
    __syncthreads();
    if (tid < 512) pref[tid] = cnt[tid];
    __syncthreads();
    for (int off = 1; off < 512; off <<= 1) {
        int v = (tid >= off && tid < 512) ? pref[tid - off] : 0;
        __syncthreads();
        if (tid < 512) pref[tid] += v;
        __syncthreads();
    }
    if (tid < 512) {
        int excl = tid ? pref[tid - 1] : 0;
        indptr[b * N0 + tid] = base + excl;
        counts[b * N0 + tid] = cnt[tid];
        curs[tid] = excl;
    }
    __syncthreads();
    for (int i = tid; i < EPG; i += 1024) {
        uint wv = epk[i];
        int dl = wv >> 16;
        int pos = atomicAdd(&curs[dl], 1);
        srclist[base + pos] = (int)(wv & 0xFFFFu);
    }
}

// ---------------- aggregation: per-(graph, channel-quarter) LDS-staged fp32 slab ----------------
__global__ __launch_bounds__(1024) void aggregate(
        const uint* __restrict__ xp,
        const int* __restrict__ indptr, const int* __restrict__ counts,
        const int* __restrict__ srclist,
        uint* __restrict__ aggp, int n) {
    extern __shared__ float slab[];            // [n][32] fp32 (hi+lo combined)
    int b = blockIdx.x >> 2, q = blockIdx.x & 3;
    int tid = threadIdx.x;
    for (int t = tid; t < n * 8; t += 1024) {
        int nd = t >> 3, c4 = t & 7;
        uint4 u = *(const uint4*)&xp[(size_t)(b * n + nd) * CCH + q * 32 + c4 * 4];
        *(float4*)&slab[nd * 32 + c4 * 4] =
            make_float4(unpk(u.x), unpk(u.y), unpk(u.z), unpk(u.w));
    }
    __syncthreads();
    int wave = tid >> 6, lane = tid & 63;
    int gl = lane >> 3;           // node slot within wave (0..7)
    int sub = lane & 7;           // float4 slot (4 channels)
    int ngroups = (n + 7) >> 3;
    for (int g = wave; g < ngroups; g += 16) {
        int d = g * 8 + gl;
        bool act = d < n;
        int beg = 0, cnt = 0;
        if (act) { beg = indptr[b * n + d]; cnt = counts[b * n + d]; }
        float4 acc = make_float4(0.f, 0.f, 0.f, 0.f);
        int id_next = (cnt > 0) ? srclist[beg] : 0;
        for (int j = 0; j < cnt; j++) {
            int id = id_next;
            if (j + 1 < cnt) id_next = srclist[beg + j + 1];
            const float4 v = *(const float4*)&slab[id * 32 + sub * 4];
            acc.x += v.x; acc.y += v.y; acc.z += v.z; acc.w += v.w;
        }
        if (act) {
            uint4 o;
            o.x = pksplit(acc.x); o.y = pksplit(acc.y);
            o.z = pksplit(acc.z); o.w = pksplit(acc.w);
            *(uint4*)&aggp[(size_t)(b * n + d) * CCH + q * 32 + sub * 4] = o;
        }
    }
}

// ---------------- bf16x3 MFMA transform + fused score (LDS-staged B) ----------------
__global__ __launch_bounds__(512, 4) void transform_mfma(
        const uint* __restrict__ aggp, const uint* __restrict__ xp,
        const ushort* __restrict__ Bph, const ushort* __restrict__ Bpl,
        const float* __restrict__ brel, const float* __restrict__ pvec,
        uint* __restrict__ hp, float* __restrict__ score) {
    __shared__ ushort ldsBh[16384];   // 32 KB: [4 ks][8 cf][64 lane][8]
    __shared__ ushort ldsBl[16384];   // 32 KB
    int tid = threadIdx.x;
    int wave = tid >> 6, lane = tid & 63;
    int r = lane & 15, kb = lane >> 4;
    int rows0 = blockIdx.x * 128 + wave * 16;

    f32x4 acc[8];
#pragma unroll
    for (int cf = 0; cf < 8; cf++) acc[cf] = (f32x4)(0.f);

    union U16 { uint u[4]; bf16x8 v; };

#pragma unroll
    for (int half = 0; half < 2; half++) {
        if (half) __syncthreads();
#pragma unroll
        for (int i = 0; i < 4; i++) {
            int idx = tid + i * 512;
            ((uint4*)ldsBh)[idx] = ((const uint4*)(Bph + half * 16384))[idx];
            ((uint4*)ldsBl)[idx] = ((const uint4*)(Bpl + half * 16384))[idx];
        }
        __syncthreads();
        const uint* A = half ? xp : aggp;
#pragma unroll
        for (int ks4 = 0; ks4 < 4; ks4++) {
            size_t rowbase = (size_t)(rows0 + r) * CCH + ks4 * 32 + kb * 8;
            uint4 ua = *(const uint4*)&A[rowbase];
            uint4 ub = *(const uint4*)&A[rowbase + 4];
            U16 ah, al;
            ah.u[0] = (ua.x & 0xffffu) | (ua.y << 16);
            ah.u[1] = (ua.z & 0xffffu) | (ua.w << 16);
            ah.u[2] = (ub.x & 0xffffu) | (ub.y << 16);
            ah.u[3] = (ub.z & 0xffffu) | (ub.w << 16);
            al.u[0] = (ua.x >> 16) | (ua.y & 0xffff0000u);
            al.u[1] = (ua.z >> 16) | (ua.w & 0xffff0000u);
            al.u[2] = (ub.x >> 16) | (ub.y & 0xffff0000u);
            al.u[3] = (ub.z >> 16) | (ub.w & 0xffff0000u);
#pragma unroll
            for (int cf = 0; cf < 8; cf++) {
                bf16x8 bh = *(const bf16x8*)&ldsBh[((ks4 * 8 + cf) * 64 + lane) * 8];
                bf16x8 bl = *(const bf16x8*)&ldsBl[((ks4 * 8 + cf) * 64 + lane) * 8];
                acc[cf] = __builtin_amdgcn_mfma_f32_16x16x32_bf16(ah.v, bl, acc[cf], 0, 0, 0);
                acc[cf] = __builtin_amdgcn_mfma_f32_16x16x32_bf16(al.v, bh, acc[cf], 0, 0, 0);
                acc[cf] = __builtin_amdgcn_mfma_f32_16x16x32_bf16(ah.v, bh, acc[cf], 0, 0, 0);
            }
        }
    }

    // epilogue: bias+relu (fp32), packed store, fused score
    float pv[8], bb[8], q = 0.f;
#pragma unroll
    for (int cf = 0; cf < 8; cf++) {
        pv[cf] = pvec[cf * 16 + r];
        bb[cf] = brel[cf * 16 + r];
        q += pv[cf] * pv[cf];
    }
    float dots[4] = {0.f, 0.f, 0.f, 0.f};
#pragma unroll
    for (int cf = 0; cf < 8; cf++) {
#pragma unroll
        for (int reg = 0; reg < 4; reg++) {
            float v = acc[cf][reg] + bb[cf];
            v = v > 0.f ? v : 0.f;
            hp[(size_t)(rows0 + kb * 4 + reg) * CCH + cf * 16 + r] = pksplit(v);
            dots[reg] += v * pv[cf];
        }
    }
#pragma unroll
    for (int off = 1; off < 16; off <<= 1) {
        q += __shfl_xor(q, off);
#pragma unroll
        for (int reg = 0; reg < 4; reg++) dots[reg] += __shfl_xor(dots[reg], off);
    }
    if (r == 0) {
        float inv_norm = rsqrtf(q);
#pragma unroll
        for (int reg = 0; reg < 4; reg++)
            score[rows0 + kb * 4 + reg] = tanhf(dots[reg] * inv_norm);
    }
}

// ---------------- fused pool (4 blocks/graph, redundant sort) + next-layer CSR ----------------
// all blocks: bitonic sort of this graph's scores (deterministic -> identical).
// q==0: compose mapT and build next layer's CSR entirely in LDS.
// q==1..3: gather third of kept rows + readout partials -> gpart[layer][q-1][b][256].
__global__ __launch_bounds__(512) void pool_kernel(
        const float* __restrict__ score, const uint* __restrict__ hp,
        uint* __restrict__ xp, float* __restrict__ gpart, int* __restrict__ mapT,
        const int* __restrict__ es, const int* __restrict__ ed,
        int* __restrict__ indptr, int* __restrict__ counts, int* __restrict__ srclist,
        int n, int k, int layer, int last) {
    int b = blockIdx.x >> 2, q = blockIdx.x & 3;
    int tid = threadIdx.x;
    __shared__ unsigned long long keys[512];
    __shared__ short invl[512];
    __shared__ float wmax[8][128], wsum[8][128];
    __shared__ int newmap[512];
    __shared__ uint epk[EPG];          // 16 KB (q==0 only)
    __shared__ int cnt[512], pref[512], curs[512];
    // load keys (orderable-transformed score, tie -> lower idx first)
    {
        unsigned long long key = 0ull;   // sorts below all real scores
        if (tid < n) {
            uint u = __float_as_uint(score[b * n + tid]);
            u = (u & 0x80000000u) ? ~u : (u | 0x80000000u);
            key = ((unsigned long long)u << 32) | (uint)(~tid);
        }
        keys[tid] = key;
        invl[tid] = -1;
    }
    __syncthreads();
    // bitonic sort, descending (deterministic -> identical across the 4 blocks)
    for (int kk2 = 2; kk2 <= 512; kk2 <<= 1) {
        for (int j = kk2 >> 1; j > 0; j >>= 1) {
            int s = tid, sxj = s ^ j;
            if (sxj > s) {
                unsigned long long a = keys[s], c = keys[sxj];
                bool doSwap = ((s & kk2) == 0) ? (a < c) : (a > c);
                if (doSwap) { keys[s] = c; keys[sxj] = a; }
            }
            __syncthreads();
        }
    }
    if (tid < k) {
        int node = (int)(~(uint)keys[tid]);
        invl[node] = (short)tid;
    }
    __syncthreads();

    if (q == 0) {
        if (last) return;
        // compose mapT through this pooling, keep in LDS for CSR
        int m = mapT[b * N0 + tid];
        int res = -1;
        if (m >= 0) {
            int nl = invl[m - b * n];
            if (nl >= 0) res = b * k + nl;
        }
        mapT[b * N0 + tid] = res;
        newmap[tid] = res;
        cnt[tid] = 0;
        __syncthreads();
        // CSR build for next layer (n_next = k)
        int base = b * EPG;
        int nb = b * k;
        for (int i = tid; i < EPG; i += 512) {
            int s = es[base + i] & (N0 - 1);
            int d = ed[base + i] & (N0 - 1);
            int sg = newmap[s], dg = newmap[d];
            uint wv = 0xFFFFFFFFu;
            if ((sg | dg) >= 0) {
                int sl = sg - nb, dl = dg - nb;
                wv = (uint)sl | ((uint)dl << 16);
                atomicAdd(&cnt[dl], 1);
            }
            epk[i] = wv;
        }
        __syncthreads();
        pref[tid] = cnt[tid];
        __syncthreads();
        for (int off = 1; off < 512; off <<= 1) {
            int v = (tid >= off) ? pref[tid - off] : 0;
            __syncthreads();
            pref[tid] += v;
            __syncthreads();
        }
        int excl = tid ? pref[tid - 1] : 0;
        if (tid < k) {
            indptr[nb + tid] = base + excl;
            counts[nb + tid] = cnt[tid];
        }
        curs[tid] = excl;
        __syncthreads();
        for (int i = tid; i < EPG; i += 512) {
            uint wv = epk[i];
            if (wv != 0xFFFFFFFFu) {
                int dl = wv >> 16;
                int pos = atomicAdd(&curs[dl], 1);
                srclist[base + pos] = (int)(wv & 0xFFFFu);
            }
        }
    } else {
        // gather+scale rows j === (q-1) (mod 3), accumulate readout partials per wave
        int p = q - 1;
        int wave = tid >> 6, lane = tid & 63;
        float mx0 = -1e30f, mx1 = -1e30f, sm0 = 0.f, sm1 = 0.f;
        for (int j = p + 3 * wave; j < k; j += 24) {
            unsigned long long key = keys[j];
            int node = (int)(~(uint)key);
            uint tu = (uint)(key >> 32);   // decode score (inverse orderable transform)
            uint su = (tu & 0x80000000u) ? (tu & 0x7fffffffu) : ~tu;
            float v = __uint_as_float(su);
            uint2 u = ((const uint2*)(hp + (size_t)(b * n + node) * CCH))[lane];
            float c0 = unpk(u.x) * v;
            float c1 = unpk(u.y) * v;
            ((uint2*)(xp + (size_t)(b * k + j) * CCH))[lane] =
                make_uint2(pksplit(c0), pksplit(c1));
            mx0 = fmaxf(mx0, c0); sm0 += c0;
            mx1 = fmaxf(mx1, c1); sm1 += c1;
        }
        wmax[wave][2 * lane] = mx0; wmax[wave][2 * lane + 1] = mx1;
        wsum[wave][2 * lane] = sm0; wsum[wave][2 * lane + 1] = sm1;
        __syncthreads();
        if (tid < 128) {
            float m = wmax[0][tid], s = wsum[0][tid];
#pragma unroll
            for (int w = 1; w < 8; w++) { m = fmaxf(m, wmax[w][tid]); s += wsum[w][tid]; }
            float* gp = gpart + ((size_t)(layer * 3 + p) * B_G + b) * 256;
            gp[tid] = m;
            gp[128 + tid] = s;
        }
    }
}

// ---------------- final MLP + log_softmax (combines gpart thirds) ----------------
__global__ __launch_bounds__(128) void mlp_kernel(const float* __restrict__ gpart,
        const float* __restrict__ W1, const float* __restrict__ b1,
        const float* __restrict__ W2, const float* __restrict__ b2,
        const float* __restrict__ W3, const float* __restrict__ b3,
        float* __restrict__ out) {
    int b = blockIdx.x, t = threadIdx.x;
    __shared__ float gs[256], h1[128], h2[64], lg[10];
    const float kdiv[3] = {(float)K1, (float)K2, (float)K3};
    float a0 = 0.f, a1 = 0.f;
#pragma unroll
    for (int l = 0; l < 3; l++) {
        float m = -1e30f, s = 0.f;
#pragma unroll
        for (int p = 0; p < 3; p++) {
            const float* gp = gpart + ((size_t)(l * 3 + p) * B_G + b) * 256;
            m = fmaxf(m, gp[t]);
            s += gp[128 + t];
        }
        a0 += m;
        a1 += s / kdiv[l];
    }
    gs[t] = a0;
    gs[128 + t] = a1;
    __syncthreads();
    {
        float a = b1[t];
        for (int c = 0; c < 256; c++) a += gs[c] * W1[c * 128 + t];
        h1[t] = fmaxf(a, 0.f);
    }
    __syncthreads();
    if (t < 64) {
        float a = b2[t];
        for (int c = 0; c < 128; c++) a += h1[c] * W2[c * 64 + t];
        h2[t] = fmaxf(a, 0.f);
    }
    __syncthreads();
    if (t < 10) {
        float a = b3[t];
        for (int c = 0; c < 64; c++) a += h2[c] * W3[c * 10 + t];
        lg[t] = a;
    }
    __syncthreads();
    if (t < 10) {
        float m = lg[0];
        for (int i = 1; i < 10; i++) m = fmaxf(m, lg[i]);
        float s = 0.f;
        for (int i = 0; i < 10; i++) s += expf(lg[i] - m);
        out[b * 10 + t] = lg[t] - m - logf(s);
    }
}

// ---------------- host ----------------
extern "C" void kernel_launch(void* const* d_in, const int* in_sizes, int n_in,
                              void* d_out, int out_size, void* d_ws, size_t ws_size,
                              hipStream_t stream) {
    (void)in_sizes; (void)n_in; (void)out_size; (void)ws_size;
    const float* x0 = (const float*)d_in[0];
    const int* es = (const int*)d_in[1];
    const int* ed = (const int*)d_in[2];
    const float* Wroot[3] = {(const float*)d_in[3], (const float*)d_in[7], (const float*)d_in[11]};
    const float* Wrel[3]  = {(const float*)d_in[4], (const float*)d_in[8], (const float*)d_in[12]};
    const float* brel[3]  = {(const float*)d_in[5], (const float*)d_in[9], (const float*)d_in[13]};
    const float* pvec[3]  = {(const float*)d_in[6], (const float*)d_in[10], (const float*)d_in[14]};
    const float* W1 = (const float*)d_in[15];
    const float* b1 = (const float*)d_in[16];
    const float* W2 = (const float*)d_in[17];
    const float* b2 = (const float*)d_in[18];
    const float* W3 = (const float*)d_in[19];
    const float* b3 = (const float*)d_in[20];

    size_t off = 0;
    char* base = (char*)d_ws;
    auto alloc = [&](size_t bytes) -> void* {
        void* p = base + off;
        off += (bytes + 255) & ~(size_t)255;
        return p;
    };
    const size_t FEATP = (size_t)(B_G * N0) * CCH * 4;   // packed uint plane
    uint* xp   = (uint*)alloc(FEATP);    // layer-input features (packed)
    uint* aggp = (uint*)alloc(FEATP);    // aggregation, overwritten by h (packed)
    ushort* Bph = (ushort*)alloc((size_t)3 * 32768 * 2); // packed weights hi
    ushort* Bpl = (ushort*)alloc((size_t)3 * 32768 * 2); // packed weights lo
    int* mapT   = (int*)alloc((size_t)(B_G * N0) * 4);   // orig node -> current id / -1
    int* counts = (int*)alloc((size_t)(B_G * N0) * 4);
    int* indptr = (int*)alloc((size_t)(B_G * N0) * 4);
    int* srclist = (int*)alloc((size_t)E_TOTAL * 4);
    float* score = (float*)alloc((size_t)(B_G * N0) * 4);
    float* gpart = (float*)alloc((size_t)3 * 3 * B_G * 256 * 4);

    const int N4 = B_G * N0 * CCH / 4;
    prep_kernel<<<(N4 + 255) / 256, 256, 0, stream>>>(
        x0, xp, N4, Wrel[0], Wroot[0], Wrel[1], Wroot[1], Wrel[2], Wroot[2], Bph, Bpl);
    csr0_kernel<<<B_G, 1024, 0, stream>>>(es, ed, mapT, indptr, counts, srclist);

    int nper[4] = {N0, K1, K2, K3};
    for (int l = 0; l < 3; l++) {
        int n = nper[l], k = nper[l + 1];
        int n_nodes = B_G * n;
        aggregate<<<4 * B_G, 1024, (size_t)n * 32 * 4, stream>>>(
            xp, indptr, counts, srclist, aggp, n);
        transform_mfma<<<n_nodes / 128, 512, 0, stream>>>(
            aggp, xp, Bph + (size_t)l * 32768, Bpl + (size_t)l * 32768,
            brel[l], pvec[l], aggp, score);
        pool_kernel<<<4 * B_G, 512, 0, stream>>>(
            score, aggp, xp, gpart, mapT, es, ed, indptr, counts, srclist,
            n, k, l, l == 2);
    }
    mlp_kernel<<<B_G, 128, 0, stream>>>(gpart, W1, b1, W2, b2, W3, b3, (float*)d_out);
}

// Round 12
// 203.194 us; speedup vs baseline: 2.4372x; 1.0801x over previous
//
#include <hip/hip_runtime.h>
#include <hip/hip_bf16.h>
#include <math.h>

#define B_G   128
#define N0    512
#define DEG   8
#define CCH   128
#define EPG   (N0*DEG)            // 4096 edges per graph (fixed slab)
#define E_TOTAL (B_G*EPG)
#define K1    410
#define K2    328
#define K3    263
#define NCLS  10

using bf16x8 = __attribute__((ext_vector_type(8))) __bf16;
using f32x4  = __attribute__((ext_vector_type(4))) float;
typedef unsigned short ushort;
typedef unsigned int uint;

__device__ __forceinline__ ushort f2b(float f) {
    uint u = __float_as_uint(f);
    u += 0x7fffu + ((u >> 16) & 1u);      // RNE
    return (ushort)(u >> 16);
}
__device__ __forceinline__ float b2f(ushort h) {
    return __uint_as_float(((uint)h) << 16);
}
// split fp32 -> (hi, lo) bf16 pair;  v ~= hi + lo  (error ~2^-17 rel)
__device__ __forceinline__ void split2(float v, ushort& hi, ushort& lo) {
    hi = f2b(v);
    lo = f2b(v - b2f(hi));
}
// packed channel word: hi | lo<<16
__device__ __forceinline__ uint pksplit(float v) {
    ushort h, l; split2(v, h, l);
    return (uint)h | ((uint)l << 16);
}
__device__ __forceinline__ float unpk(uint u) {
    return __uint_as_float(u << 16) + __uint_as_float(u & 0xffff0000u);
}

// ---------------- setup: layer-0 CSR (blocks 0..B_G-1) | convert x0 + pack weights ----------------
__global__ __launch_bounds__(512) void setup_kernel(
        const float* __restrict__ x0, uint* __restrict__ xp, int n4,
        const float* __restrict__ Wrel0, const float* __restrict__ Wroot0,
        const float* __restrict__ Wrel1, const float* __restrict__ Wroot1,
        const float* __restrict__ Wrel2, const float* __restrict__ Wroot2,
        ushort* __restrict__ Bph, ushort* __restrict__ Bpl,
        const int* __restrict__ es, const int* __restrict__ ed,
        int* __restrict__ indptr0, int* __restrict__ counts0, ushort* __restrict__ srclist0) {
    __shared__ uint epk[EPG];     // 16 KB
    __shared__ int cnt[512], pref[512], curs[512];
    if (blockIdx.x < B_G) {
        int b = blockIdx.x, tid = threadIdx.x;
        cnt[tid] = 0;
        __syncthreads();
        int base = b * EPG;
        for (int i = tid; i < EPG; i += 512) {
            int s = es[base + i] & (N0 - 1);
            int d = ed[base + i] & (N0 - 1);
            epk[i] = (uint)s | ((uint)d << 16);
            atomicAdd(&cnt[d], 1);
        }
        __syncthreads();
        pref[tid] = cnt[tid];
        __syncthreads();
        for (int off = 1; off < 512; off <<= 1) {
            int v = (tid >= off) ? pref[tid - off] : 0;
            __syncthreads();
            pref[tid] += v;
            __syncthreads();
        }
        int excl = tid ? pref[tid - 1] : 0;
        indptr0[b * N0 + tid] = base + excl;
        counts0[b * N0 + tid] = cnt[tid];
        curs[tid] = excl;
        __syncthreads();
        for (int i = tid; i < EPG; i += 512) {
            uint wv = epk[i];
            int dl = wv >> 16;
            int pos = atomicAdd(&curs[dl], 1);
            srclist0[base + pos] = (ushort)(wv & 0xFFFFu);
        }
    } else {
        int i = (blockIdx.x - B_G) * 512 + threadIdx.x;
        if (i < n4) {
            float4 v = ((const float4*)x0)[i];
            uint4 o;
            o.x = pksplit(v.x); o.y = pksplit(v.y); o.z = pksplit(v.z); o.w = pksplit(v.w);
            ((uint4*)xp)[i] = o;
        }
        if (i < 3 * 32768) {
            int layer = i >> 15, rem = i & 32767;
            int j = rem & 7, lane = (rem >> 3) & 63, cf = (rem >> 9) & 7, ks = rem >> 12;
            int k = ks * 32 + (lane >> 4) * 8 + j;
            int c = cf * 16 + (lane & 15);
            const float* Wrel  = layer == 0 ? Wrel0  : layer == 1 ? Wrel1  : Wrel2;
            const float* Wroot = layer == 0 ? Wroot0 : layer == 1 ? Wroot1 : Wroot2;
            float v = (k < 128) ? Wrel[k * 128 + c] : Wroot[(k - 128) * 128 + c];
            ushort hi, lo; split2(v, hi, lo);
            Bph[i] = hi; Bpl[i] = lo;
        }
    }
}

// ---------------- aggregation: per-(graph, channel-quarter) LDS slab, perm+scale applied on load --
__global__ __launch_bounds__(1024) void aggregate(
        const uint* __restrict__ hin, const int* __restrict__ perm,
        const float* __restrict__ pval,
        const int* __restrict__ indptr, const int* __restrict__ counts,
        const ushort* __restrict__ srclist,
        uint* __restrict__ aggp, int n) {
    extern __shared__ float slab[];            // [n][32] fp32 (scaled features)
    int b = blockIdx.x >> 2, q = blockIdx.x & 3;
    int tid = threadIdx.x;
    for (int t = tid; t < n * 8; t += 1024) {
        int nd = t >> 3, c4 = t & 7;
        int gid = b * n + nd;
        size_t old = perm ? (size_t)perm[gid] : (size_t)gid;
        float v = perm ? pval[gid] : 1.f;
        uint4 u = *(const uint4*)&hin[old * CCH + q * 32 + c4 * 4];
        *(float4*)&slab[nd * 32 + c4 * 4] =
            make_float4(unpk(u.x) * v, unpk(u.y) * v, unpk(u.z) * v, unpk(u.w) * v);
    }
    __syncthreads();
    int wave = tid >> 6, lane = tid & 63;
    int gl = lane >> 3;           // node slot within wave (0..7)
    int sub = lane & 7;           // float4 slot (4 channels)
    int ngroups = (n + 7) >> 3;
    for (int g = wave; g < ngroups; g += 16) {
        int d = g * 8 + gl;
        bool act = d < n;
        int beg = 0, cnt = 0;
        if (act) { beg = indptr[b * n + d]; cnt = counts[b * n + d]; }
        float4 acc = make_float4(0.f, 0.f, 0.f, 0.f);
        int id_next = (cnt > 0) ? (int)srclist[beg] : 0;
        for (int j = 0; j < cnt; j++) {
            int id = id_next;
            if (j + 1 < cnt) id_next = (int)srclist[beg + j + 1];
            const float4 v = *(const float4*)&slab[id * 32 + sub * 4];
            acc.x += v.x; acc.y += v.y; acc.z += v.z; acc.w += v.w;
        }
        if (act) {
            uint4 o;
            o.x = pksplit(acc.x); o.y = pksplit(acc.y);
            o.z = pksplit(acc.z); o.w = pksplit(acc.w);
            *(uint4*)&aggp[(size_t)(b * n + d) * CCH + q * 32 + sub * 4] = o;
        }
    }
}

// ---------------- bf16x3 MFMA transform + fused score (LDS-staged B, perm+scale root) ----------------
__global__ __launch_bounds__(512, 4) void transform_mfma(
        const uint* __restrict__ aggp, const uint* __restrict__ hin,
        const int* __restrict__ perm, const float* __restrict__ pval,
        const ushort* __restrict__ Bph, const ushort* __restrict__ Bpl,
        const float* __restrict__ brel, const float* __restrict__ pvec,
        uint* __restrict__ hout, float* __restrict__ score) {
    __shared__ ushort ldsBh[16384];   // 32 KB: [4 ks][8 cf][64 lane][8]
    __shared__ ushort ldsBl[16384];   // 32 KB
    int tid = threadIdx.x;
    int wave = tid >> 6, lane = tid & 63;
    int r = lane & 15, kb = lane >> 4;
    int rows0 = blockIdx.x * 128 + wave * 16;
    int gid = rows0 + r;
    size_t oldrow = perm ? (size_t)perm[gid] : (size_t)gid;
    float rv = perm ? pval[gid] : 1.f;

    f32x4 acc[8];
#pragma unroll
    for (int cf = 0; cf < 8; cf++) acc[cf] = (f32x4)(0.f);

    union U16 { uint u[4]; bf16x8 v; };

#pragma unroll
    for (int half = 0; half < 2; half++) {
        if (half) __syncthreads();
#pragma unroll
        for (int i = 0; i < 4; i++) {
            int idx = tid + i * 512;
            ((uint4*)ldsBh)[idx] = ((const uint4*)(Bph + half * 16384))[idx];
            ((uint4*)ldsBl)[idx] = ((const uint4*)(Bpl + half * 16384))[idx];
        }
        __syncthreads();
        const uint* A = half ? hin : aggp;
        size_t abase = half ? oldrow * CCH : (size_t)gid * CCH;
#pragma unroll
        for (int ks4 = 0; ks4 < 4; ks4++) {
            size_t rowbase = abase + ks4 * 32 + kb * 8;
            uint4 ua = *(const uint4*)&A[rowbase];
            uint4 ub = *(const uint4*)&A[rowbase + 4];
            U16 ah, al;
            if (half && perm) {
                // scaled root: unpack, scale, re-split
                float c[8] = {unpk(ua.x) * rv, unpk(ua.y) * rv, unpk(ua.z) * rv,
                              unpk(ua.w) * rv, unpk(ub.x) * rv, unpk(ub.y) * rv,
                              unpk(ub.z) * rv, unpk(ub.w) * rv};
#pragma unroll
                for (int p2 = 0; p2 < 4; p2++) {
                    ushort h0, l0, h1, l1;
                    split2(c[2 * p2], h0, l0);
                    split2(c[2 * p2 + 1], h1, l1);
                    ah.u[p2] = (uint)h0 | ((uint)h1 << 16);
                    al.u[p2] = (uint)l0 | ((uint)l1 << 16);
                }
            } else {
                ah.u[0] = (ua.x & 0xffffu) | (ua.y << 16);
                ah.u[1] = (ua.z & 0xffffu) | (ua.w << 16);
                ah.u[2] = (ub.x & 0xffffu) | (ub.y << 16);
                ah.u[3] = (ub.z & 0xffffu) | (ub.w << 16);
                al.u[0] = (ua.x >> 16) | (ua.y & 0xffff0000u);
                al.u[1] = (ua.z >> 16) | (ua.w & 0xffff0000u);
                al.u[2] = (ub.x >> 16) | (ub.y & 0xffff0000u);
                al.u[3] = (ub.z >> 16) | (ub.w & 0xffff0000u);
            }
#pragma unroll
            for (int cf = 0; cf < 8; cf++) {
                bf16x8 bh = *(const bf16x8*)&ldsBh[((ks4 * 8 + cf) * 64 + lane) * 8];
                bf16x8 bl = *(const bf16x8*)&ldsBl[((ks4 * 8 + cf) * 64 + lane) * 8];
                acc[cf] = __builtin_amdgcn_mfma_f32_16x16x32_bf16(ah.v, bl, acc[cf], 0, 0, 0);
                acc[cf] = __builtin_amdgcn_mfma_f32_16x16x32_bf16(al.v, bh, acc[cf], 0, 0, 0);
                acc[cf] = __builtin_amdgcn_mfma_f32_16x16x32_bf16(ah.v, bh, acc[cf], 0, 0, 0);
            }
        }
    }

    // epilogue: bias+relu (fp32), packed store, fused score
    float pv[8], bb[8], q = 0.f;
#pragma unroll
    for (int cf = 0; cf < 8; cf++) {
        pv[cf] = pvec[cf * 16 + r];
        bb[cf] = brel[cf * 16 + r];
        q += pv[cf] * pv[cf];
    }
    float dots[4] = {0.f, 0.f, 0.f, 0.f};
#pragma unroll
    for (int cf = 0; cf < 8; cf++) {
#pragma unroll
        for (int reg = 0; reg < 4; reg++) {
            float v = acc[cf][reg] + bb[cf];
            v = v > 0.f ? v : 0.f;
            hout[(size_t)(rows0 + kb * 4 + reg) * CCH + cf * 16 + r] = pksplit(v);
            dots[reg] += v * pv[cf];
        }
    }
#pragma unroll
    for (int off = 1; off < 16; off <<= 1) {
        q += __shfl_xor(q, off);
#pragma unroll
        for (int reg = 0; reg < 4; reg++) dots[reg] += __shfl_xor(dots[reg], off);
    }
    if (r == 0) {
        float inv_norm = rsqrtf(q);
#pragma unroll
        for (int reg = 0; reg < 4; reg++)
            score[rows0 + kb * 4 + reg] = tanhf(dots[reg] * inv_norm);
    }
}

// ---------------- pool (4 blocks/graph, redundant sort; NO gather materialization) ----------------
// q==0: write perm/pval; compact old CSR -> new CSR (deterministic, no atomics).
// q==1..3: readout thirds directly from hp rows with on-the-fly scale.
__global__ __launch_bounds__(512) void pool_kernel(
        const float* __restrict__ score, const uint* __restrict__ hp,
        int* __restrict__ perm_out, float* __restrict__ pval_out,
        float* __restrict__ gpart,
        const int* __restrict__ indptr_in, const int* __restrict__ counts_in,
        const ushort* __restrict__ srclist_in,
        int* __restrict__ indptr_out, int* __restrict__ counts_out,
        ushort* __restrict__ srclist_out,
        int n, int k, int layer, int last) {
    int b = blockIdx.x >> 2, q = blockIdx.x & 3;
    int tid = threadIdx.x;
    __shared__ unsigned long long keys[512];
    __shared__ short invl[512];
    __shared__ float wmax[8][128], wsum[8][128];
    __shared__ int cnt[512], pref[512];
    // load keys (orderable-transformed score, tie -> lower idx first)
    {
        unsigned long long key = 0ull;   // sorts below all real scores
        if (tid < n) {
            uint u = __float_as_uint(score[b * n + tid]);
            u = (u & 0x80000000u) ? ~u : (u | 0x80000000u);
            key = ((unsigned long long)u << 32) | (uint)(~tid);
        }
        keys[tid] = key;
        invl[tid] = -1;
    }
    __syncthreads();
    // bitonic sort, descending (deterministic -> identical across the 4 blocks)
    for (int kk2 = 2; kk2 <= 512; kk2 <<= 1) {
        for (int j = kk2 >> 1; j > 0; j >>= 1) {
            int s = tid, sxj = s ^ j;
            if (sxj > s) {
                unsigned long long a = keys[s], c = keys[sxj];
                bool doSwap = ((s & kk2) == 0) ? (a < c) : (a > c);
                if (doSwap) { keys[s] = c; keys[sxj] = a; }
            }
            __syncthreads();
        }
    }
    if (tid < k) {
        int node = (int)(~(uint)keys[tid]);
        invl[node] = (short)tid;
    }
    __syncthreads();

    if (q == 0) {
        if (last) return;
        int node = -1, beg = 0, c = 0, nk = 0;
        if (tid < k) {
            unsigned long long key = keys[tid];
            node = (int)(~(uint)key);
            uint tu = (uint)(key >> 32);
            uint su = (tu & 0x80000000u) ? (tu & 0x7fffffffu) : ~tu;
            perm_out[b * k + tid] = b * n + node;
            pval_out[b * k + tid] = __uint_as_float(su);
            beg = indptr_in[b * n + node];
            c = counts_in[b * n + node];
            for (int t = 0; t < c; t++)
                if (invl[srclist_in[beg + t]] >= 0) nk++;
        }
        cnt[tid] = (tid < k) ? nk : 0;
        __syncthreads();
        pref[tid] = cnt[tid];
        __syncthreads();
        for (int off = 1; off < 512; off <<= 1) {
            int v = (tid >= off) ? pref[tid - off] : 0;
            __syncthreads();
            pref[tid] += v;
            __syncthreads();
        }
        if (tid < k) {
            int excl = tid ? pref[tid - 1] : 0;
            indptr_out[b * k + tid] = b * EPG + excl;
            counts_out[b * k + tid] = nk;
            int pos = b * EPG + excl;
            for (int t = 0; t < c; t++) {
                int ns = invl[srclist_in[beg + t]];
                if (ns >= 0) srclist_out[pos++] = (ushort)ns;
            }
        }
    } else {
        // readout thirds: j === (q-1) (mod 3), direct hp reads with scale
        int p = q - 1;
        int wave = tid >> 6, lane = tid & 63;
        float mx0 = -1e30f, mx1 = -1e30f, sm0 = 0.f, sm1 = 0.f;
        for (int j = p + 3 * wave; j < k; j += 24) {
            unsigned long long key = keys[j];
            int node = (int)(~(uint)key);
            uint tu = (uint)(key >> 32);
            uint su = (tu & 0x80000000u) ? (tu & 0x7fffffffu) : ~tu;
            float v = __uint_as_float(su);
            uint2 u = ((const uint2*)(hp + (size_t)(b * n + node) * CCH))[lane];
            float c0 = unpk(u.x) * v;
            float c1 = unpk(u.y) * v;
            mx0 = fmaxf(mx0, c0); sm0 += c0;
            mx1 = fmaxf(mx1, c1); sm1 += c1;
        }
        wmax[wave][2 * lane] = mx0; wmax[wave][2 * lane + 1] = mx1;
        wsum[wave][2 * lane] = sm0; wsum[wave][2 * lane + 1] = sm1;
        __syncthreads();
        if (tid < 128) {
            float m = wmax[0][tid], s = wsum[0][tid];
#pragma unroll
            for (int w = 1; w < 8; w++) { m = fmaxf(m, wmax[w][tid]); s += wsum[w][tid]; }
            float* gp = gpart + ((size_t)(layer * 3 + p) * B_G + b) * 256;
            gp[tid] = m;
            gp[128 + tid] = s;
        }
    }
}

// ---------------- final MLP + log_softmax (combines gpart thirds) ----------------
__global__ __launch_bounds__(128) void mlp_kernel(const float* __restrict__ gpart,
        const float* __restrict__ W1, const float* __restrict__ b1,
        const float* __restrict__ W2, const float* __restrict__ b2,
        const float* __restrict__ W3, const float* __restrict__ b3,
        float* __restrict__ out) {
    int b = blockIdx.x, t = threadIdx.x;
    __shared__ float gs[256], h1[128], h2[64], lg[10];
    const float kdiv[3] = {(float)K1, (float)K2, (float)K3};
    float a0 = 0.f, a1 = 0.f;
#pragma unroll
    for (int l = 0; l < 3; l++) {
        float m = -1e30f, s = 0.f;
#pragma unroll
        for (int p = 0; p < 3; p++) {
            const float* gp = gpart + ((size_t)(l * 3 + p) * B_G + b) * 256;
            m = fmaxf(m, gp[t]);
            s += gp[128 + t];
        }
        a0 += m;
        a1 += s / kdiv[l];
    }
    gs[t] = a0;
    gs[128 + t] = a1;
    __syncthreads();
    {
        float a = b1[t];
        for (int c = 0; c < 256; c++) a += gs[c] * W1[c * 128 + t];
        h1[t] = fmaxf(a, 0.f);
    }
    __syncthreads();
    if (t < 64) {
        float a = b2[t];
        for (int c = 0; c < 128; c++) a += h1[c] * W2[c * 64 + t];
        h2[t] = fmaxf(a, 0.f);
    }
    __syncthreads();
    if (t < 10) {
        float a = b3[t];
        for (int c = 0; c < 64; c++) a += h2[c] * W3[c * 10 + t];
        lg[t] = a;
    }
    __syncthreads();
    if (t < 10) {
        float m = lg[0];
        for (int i = 1; i < 10; i++) m = fmaxf(m, lg[i]);
        float s = 0.f;
        for (int i = 0; i < 10; i++) s += expf(lg[i] - m);
        out[b * 10 + t] = lg[t] - m - logf(s);
    }
}

// ---------------- host ----------------
extern "C" void kernel_launch(void* const* d_in, const int* in_sizes, int n_in,
                              void* d_out, int out_size, void* d_ws, size_t ws_size,
                              hipStream_t stream) {
    (void)in_sizes; (void)n_in; (void)out_size; (void)ws_size;
    const float* x0 = (const float*)d_in[0];
    const int* es = (const int*)d_in[1];
    const int* ed = (const int*)d_in[2];
    const float* Wroot[3] = {(const float*)d_in[3], (const float*)d_in[7], (const float*)d_in[11]};
    const float* Wrel[3]  = {(const float*)d_in[4], (const float*)d_in[8], (const float*)d_in[12]};
    const float* brel[3]  = {(const float*)d_in[5], (const float*)d_in[9], (const float*)d_in[13]};
    const float* pvec[3]  = {(const float*)d_in[6], (const float*)d_in[10], (const float*)d_in[14]};
    const float* W1 = (const float*)d_in[15];
    const float* b1 = (const float*)d_in[16];
    const float* W2 = (const float*)d_in[17];
    const float* b2 = (const float*)d_in[18];
    const float* W3 = (const float*)d_in[19];
    const float* b3 = (const float*)d_in[20];

    size_t off = 0;
    char* base = (char*)d_ws;
    auto alloc = [&](size_t bytes) -> void* {
        void* p = base + off;
        off += (bytes + 255) & ~(size_t)255;
        return p;
    };
    const size_t FEATP = (size_t)(B_G * N0) * CCH * 4;   // packed uint plane
    uint* P0 = (uint*)alloc(FEATP);
    uint* P1 = (uint*)alloc(FEATP);
    uint* P2 = (uint*)alloc(FEATP);
    ushort* Bph = (ushort*)alloc((size_t)3 * 32768 * 2);
    ushort* Bpl = (ushort*)alloc((size_t)3 * 32768 * 2);
    int* iptA = (int*)alloc((size_t)(B_G * N0) * 4);
    int* cntA = (int*)alloc((size_t)(B_G * N0) * 4);
    ushort* srcA = (ushort*)alloc((size_t)E_TOTAL * 2);
    int* iptB = (int*)alloc((size_t)(B_G * N0) * 4);
    int* cntB = (int*)alloc((size_t)(B_G * N0) * 4);
    ushort* srcB = (ushort*)alloc((size_t)E_TOTAL * 2);
    int* permA = (int*)alloc((size_t)(B_G * K1) * 4);
    float* pvalA = (float*)alloc((size_t)(B_G * K1) * 4);
    int* permB = (int*)alloc((size_t)(B_G * K1) * 4);
    float* pvalB = (float*)alloc((size_t)(B_G * K1) * 4);
    float* score = (float*)alloc((size_t)(B_G * N0) * 4);
    float* gpart = (float*)alloc((size_t)3 * 3 * B_G * 256 * 4);

    const int N4 = B_G * N0 * CCH / 4;
    setup_kernel<<<B_G + (N4 + 511) / 512, 512, 0, stream>>>(
        x0, P2, N4, Wrel[0], Wroot[0], Wrel[1], Wroot[1], Wrel[2], Wroot[2],
        Bph, Bpl, es, ed, iptA, cntA, srcA);

    // layer 0: hin=P2 (identity), agg->P1, h->P0 ; CSR A -> B
    aggregate<<<4 * B_G, 1024, (size_t)N0 * 32 * 4, stream>>>(
        P2, nullptr, nullptr, iptA, cntA, srcA, P1, N0);
    transform_mfma<<<B_G * N0 / 128, 512, 0, stream>>>(
        P1, P2, nullptr, nullptr, Bph, Bpl, brel[0], pvec[0], P0, score);
    pool_kernel<<<4 * B_G, 512, 0, stream>>>(
        score, P0, permA, pvalA, gpart, iptA, cntA, srcA, iptB, cntB, srcB,
        N0, K1, 0, 0);

    // layer 1: hin=P0 via permA, agg->P1, h->P2 ; CSR B -> A
    aggregate<<<4 * B_G, 1024, (size_t)K1 * 32 * 4, stream>>>(
        P0, permA, pvalA, iptB, cntB, srcB, P1, K1);
    transform_mfma<<<B_G * K1 / 128, 512, 0, stream>>>(
        P1, P0, permA, pvalA, Bph + 32768, Bpl + 32768, brel[1], pvec[1], P2, score);
    pool_kernel<<<4 * B_G, 512, 0, stream>>>(
        score, P2, permB, pvalB, gpart, iptB, cntB, srcB, iptA, cntA, srcA,
        K1, K2, 1, 0);

    // layer 2: hin=P2 via permB, agg->P1, h->P0 ; last
    aggregate<<<4 * B_G, 1024, (size_t)K2 * 32 * 4, stream>>>(
        P2, permB, pvalB, iptA, cntA, srcA, P1, K2);
    transform_mfma<<<B_G * K2 / 128, 512, 0, stream>>>(
        P1, P2, permB, pvalB, Bph + 2 * 32768, Bpl + 2 * 32768, brel[2], pvec[2], P0, score);
    pool_kernel<<<4 * B_G, 512, 0, stream>>>(
        score, P0, nullptr, nullptr, gpart, iptA, cntA, srcA, iptB, cntB, srcB,
        K2, K3, 2, 1);

    mlp_kernel<<<B_G, 128, 0, stream>>>(gpart, W1, b1, W2, b2, W3, b3, (float*)d_out);
}

// Round 13
// 195.465 us; speedup vs baseline: 2.5336x; 1.0395x over previous
//
#include <hip/hip_runtime.h>
#include <hip/hip_bf16.h>
#include <math.h>

#define B_G   128
#define N0    512
#define DEG   8
#define CCH   128
#define EPG   (N0*DEG)            // 4096 edges per graph (fixed slab)
#define E_TOTAL (B_G*EPG)
#define K1    410
#define K2    328
#define K3    263
#define NCLS  10

using bf16x8 = __attribute__((ext_vector_type(8))) __bf16;
using f32x4  = __attribute__((ext_vector_type(4))) float;
typedef unsigned short ushort;
typedef unsigned int uint;

__device__ __forceinline__ ushort f2b(float f) {
    uint u = __float_as_uint(f);
    u += 0x7fffu + ((u >> 16) & 1u);      // RNE
    return (ushort)(u >> 16);
}
__device__ __forceinline__ float b2f(ushort h) {
    return __uint_as_float(((uint)h) << 16);
}
// split fp32 -> (hi, lo) bf16 pair;  v ~= hi + lo  (error ~2^-17 rel)
__device__ __forceinline__ void split2(float v, ushort& hi, ushort& lo) {
    hi = f2b(v);
    lo = f2b(v - b2f(hi));
}
// packed channel word: hi | lo<<16
__device__ __forceinline__ uint pksplit(float v) {
    ushort h, l; split2(v, h, l);
    return (uint)h | ((uint)l << 16);
}
__device__ __forceinline__ float unpk(uint u) {
    return __uint_as_float(u << 16) + __uint_as_float(u & 0xffff0000u);
}
__device__ __forceinline__ float keyval(unsigned long long key) {
    uint tu = (uint)(key >> 32);
    uint su = (tu & 0x80000000u) ? (tu & 0x7fffffffu) : ~tu;
    return __uint_as_float(su);
}

// ---------------- setup: layer-0 CSR (blocks 0..B_G-1) | pack weights ----------------
__global__ __launch_bounds__(512) void setup_kernel(
        const float* __restrict__ Wrel0, const float* __restrict__ Wroot0,
        const float* __restrict__ Wrel1, const float* __restrict__ Wroot1,
        const float* __restrict__ Wrel2, const float* __restrict__ Wroot2,
        ushort* __restrict__ Bph, ushort* __restrict__ Bpl,
        const int* __restrict__ es, const int* __restrict__ ed,
        int* __restrict__ indptr0, int* __restrict__ counts0, ushort* __restrict__ srclist0) {
    __shared__ uint epk[EPG];     // 16 KB
    __shared__ int cnt[512], pref[512], curs[512];
    if (blockIdx.x < B_G) {
        int b = blockIdx.x, tid = threadIdx.x;
        cnt[tid] = 0;
        __syncthreads();
        int base = b * EPG;
        for (int i = tid; i < EPG; i += 512) {
            int s = es[base + i] & (N0 - 1);
            int d = ed[base + i] & (N0 - 1);
            epk[i] = (uint)s | ((uint)d << 16);
            atomicAdd(&cnt[d], 1);
        }
        __syncthreads();
        pref[tid] = cnt[tid];
        __syncthreads();
        for (int off = 1; off < 512; off <<= 1) {
            int v = (tid >= off) ? pref[tid - off] : 0;
            __syncthreads();
            pref[tid] += v;
            __syncthreads();
        }
        int excl = tid ? pref[tid - 1] : 0;
        indptr0[b * N0 + tid] = base + excl;
        counts0[b * N0 + tid] = cnt[tid];
        curs[tid] = excl;
        __syncthreads();
        for (int i = tid; i < EPG; i += 512) {
            uint wv = epk[i];
            int dl = wv >> 16;
            int pos = atomicAdd(&curs[dl], 1);
            srclist0[base + pos] = (ushort)(wv & 0xFFFFu);
        }
    } else {
        int i = (blockIdx.x - B_G) * 512 + threadIdx.x;
        if (i < 3 * 32768) {
            int layer = i >> 15, rem = i & 32767;
            int j = rem & 7, lane = (rem >> 3) & 63, cf = (rem >> 9) & 7, ks = rem >> 12;
            int k = ks * 32 + (lane >> 4) * 8 + j;
            int c = cf * 16 + (lane & 15);
            const float* Wrel  = layer == 0 ? Wrel0  : layer == 1 ? Wrel1  : Wrel2;
            const float* Wroot = layer == 0 ? Wroot0 : layer == 1 ? Wroot1 : Wroot2;
            float v = (k < 128) ? Wrel[k * 128 + c] : Wroot[(k - 128) * 128 + c];
            ushort hi, lo; split2(v, hi, lo);
            Bph[i] = hi; Bpl[i] = lo;
        }
    }
}

// ---------------- layer-0 aggregation: fp32 x0 direct, LDS slab stride 36 ----------------
__global__ __launch_bounds__(1024) void aggregate0(
        const float* __restrict__ xf,
        const int* __restrict__ indptr, const int* __restrict__ counts,
        const ushort* __restrict__ srclist,
        uint* __restrict__ aggp) {
    extern __shared__ float slab[];            // [512][36] fp32
    int b = blockIdx.x >> 2, q = blockIdx.x & 3;
    int tid = threadIdx.x;
    const float4* xf4 = (const float4*)xf;     // row = 32 float4s
    for (int t = tid; t < N0 * 8; t += 1024) {
        int nd = t >> 3, c4 = t & 7;
        float4 u = xf4[(size_t)(b * N0 + nd) * 32 + q * 8 + c4];
        *(float4*)&slab[nd * 36 + c4 * 4] = u;
    }
    __syncthreads();
    int wave = tid >> 6, lane = tid & 63;
    int gl = lane >> 3, sub = lane & 7;
    for (int g = wave; g < N0 / 8; g += 16) {
        int d = g * 8 + gl;
        int beg = indptr[b * N0 + d];
        int cnt = counts[b * N0 + d];
        float4 acc = make_float4(0.f, 0.f, 0.f, 0.f);
        int id_next = (cnt > 0) ? (int)srclist[beg] : 0;
        for (int j = 0; j < cnt; j++) {
            int id = id_next;
            if (j + 1 < cnt) id_next = (int)srclist[beg + j + 1];
            const float4 v = *(const float4*)&slab[id * 36 + sub * 4];
            acc.x += v.x; acc.y += v.y; acc.z += v.z; acc.w += v.w;
        }
        uint4 o;
        o.x = pksplit(acc.x); o.y = pksplit(acc.y);
        o.z = pksplit(acc.z); o.w = pksplit(acc.w);
        *(uint4*)&aggp[(size_t)(b * N0 + d) * CCH + q * 32 + sub * 4] = o;
    }
}

// ---------------- bf16x3 MFMA transform + fused score (LDS-staged B) ----------------
// root operand: rootf (fp32, layer 0) OR hin packed with perm+pval (layers 1,2)
__global__ __launch_bounds__(512, 4) void transform_mfma(
        const uint* __restrict__ aggp, const uint* __restrict__ hin,
        const float* __restrict__ rootf,
        const int* __restrict__ perm, const float* __restrict__ pval,
        const ushort* __restrict__ Bph, const ushort* __restrict__ Bpl,
        const float* __restrict__ brel, const float* __restrict__ pvec,
        uint* __restrict__ hout, float* __restrict__ score) {
    __shared__ ushort ldsBh[16384];   // 32 KB: [4 ks][8 cf][64 lane][8]
    __shared__ ushort ldsBl[16384];   // 32 KB
    int tid = threadIdx.x;
    int wave = tid >> 6, lane = tid & 63;
    int r = lane & 15, kb = lane >> 4;
    int rows0 = blockIdx.x * 128 + wave * 16;
    int gid = rows0 + r;
    size_t oldrow = perm ? (size_t)perm[gid] : (size_t)gid;
    float rv = perm ? pval[gid] : 1.f;

    f32x4 acc[8];
#pragma unroll
    for (int cf = 0; cf < 8; cf++) acc[cf] = (f32x4)(0.f);

    union U16 { uint u[4]; bf16x8 v; };

#pragma unroll
    for (int half = 0; half < 2; half++) {
        if (half) __syncthreads();
#pragma unroll
        for (int i = 0; i < 4; i++) {
            int idx = tid + i * 512;
            ((uint4*)ldsBh)[idx] = ((const uint4*)(Bph + half * 16384))[idx];
            ((uint4*)ldsBl)[idx] = ((const uint4*)(Bpl + half * 16384))[idx];
        }
        __syncthreads();
#pragma unroll
        for (int ks4 = 0; ks4 < 4; ks4++) {
            U16 ah, al;
            if (half && rootf) {
                // layer-0 root: fp32 direct, split in-register (identical operands)
                const float* R = rootf + (size_t)gid * CCH + ks4 * 32 + kb * 8;
                float4 f0 = *(const float4*)R;
                float4 f1 = *(const float4*)(R + 4);
                float c[8] = {f0.x, f0.y, f0.z, f0.w, f1.x, f1.y, f1.z, f1.w};
#pragma unroll
                for (int p2 = 0; p2 < 4; p2++) {
                    ushort h0, l0, h1, l1;
                    split2(c[2 * p2], h0, l0);
                    split2(c[2 * p2 + 1], h1, l1);
                    ah.u[p2] = (uint)h0 | ((uint)h1 << 16);
                    al.u[p2] = (uint)l0 | ((uint)l1 << 16);
                }
            } else {
                const uint* A = half ? hin : aggp;
                size_t abase = half ? oldrow * CCH : (size_t)gid * CCH;
                size_t rowbase = abase + ks4 * 32 + kb * 8;
                uint4 ua = *(const uint4*)&A[rowbase];
                uint4 ub = *(const uint4*)&A[rowbase + 4];
                if (half && perm) {
                    float c[8] = {unpk(ua.x) * rv, unpk(ua.y) * rv, unpk(ua.z) * rv,
                                  unpk(ua.w) * rv, unpk(ub.x) * rv, unpk(ub.y) * rv,
                                  unpk(ub.z) * rv, unpk(ub.w) * rv};
#pragma unroll
                    for (int p2 = 0; p2 < 4; p2++) {
                        ushort h0, l0, h1, l1;
                        split2(c[2 * p2], h0, l0);
                        split2(c[2 * p2 + 1], h1, l1);
                        ah.u[p2] = (uint)h0 | ((uint)h1 << 16);
                        al.u[p2] = (uint)l0 | ((uint)l1 << 16);
                    }
                } else {
                    ah.u[0] = (ua.x & 0xffffu) | (ua.y << 16);
                    ah.u[1] = (ua.z & 0xffffu) | (ua.w << 16);
                    ah.u[2] = (ub.x & 0xffffu) | (ub.y << 16);
                    ah.u[3] = (ub.z & 0xffffu) | (ub.w << 16);
                    al.u[0] = (ua.x >> 16) | (ua.y & 0xffff0000u);
                    al.u[1] = (ua.z >> 16) | (ua.w & 0xffff0000u);
                    al.u[2] = (ub.x >> 16) | (ub.y & 0xffff0000u);
                    al.u[3] = (ub.z >> 16) | (ub.w & 0xffff0000u);
                }
            }
#pragma unroll
            for (int cf = 0; cf < 8; cf++) {
                bf16x8 bh = *(const bf16x8*)&ldsBh[((ks4 * 8 + cf) * 64 + lane) * 8];
                bf16x8 bl = *(const bf16x8*)&ldsBl[((ks4 * 8 + cf) * 64 + lane) * 8];
                acc[cf] = __builtin_amdgcn_mfma_f32_16x16x32_bf16(ah.v, bl, acc[cf], 0, 0, 0);
                acc[cf] = __builtin_amdgcn_mfma_f32_16x16x32_bf16(al.v, bh, acc[cf], 0, 0, 0);
                acc[cf] = __builtin_amdgcn_mfma_f32_16x16x32_bf16(ah.v, bh, acc[cf], 0, 0, 0);
            }
        }
    }

    // epilogue: bias+relu (fp32), packed store, fused score
    float pv[8], bb[8], q = 0.f;
#pragma unroll
    for (int cf = 0; cf < 8; cf++) {
        pv[cf] = pvec[cf * 16 + r];
        bb[cf] = brel[cf * 16 + r];
        q += pv[cf] * pv[cf];
    }
    float dots[4] = {0.f, 0.f, 0.f, 0.f};
#pragma unroll
    for (int cf = 0; cf < 8; cf++) {
#pragma unroll
        for (int reg = 0; reg < 4; reg++) {
            float v = acc[cf][reg] + bb[cf];
            v = v > 0.f ? v : 0.f;
            hout[(size_t)(rows0 + kb * 4 + reg) * CCH + cf * 16 + r] = pksplit(v);
            dots[reg] += v * pv[cf];
        }
    }
#pragma unroll
    for (int off = 1; off < 16; off <<= 1) {
        q += __shfl_xor(q, off);
#pragma unroll
        for (int reg = 0; reg < 4; reg++) dots[reg] += __shfl_xor(dots[reg], off);
    }
    if (r == 0) {
        float inv_norm = rsqrtf(q);
#pragma unroll
        for (int reg = 0; reg < 4; reg++)
            score[rows0 + kb * 4 + reg] = tanhf(dots[reg] * inv_norm);
    }
}

// ---------------- fused pool + next-layer aggregation (4 blocks/graph) ----------------
// All blocks: sort scores (redundant, deterministic), build invl, stage scaled slab
// (quarter channels of all k kept rows), readout from slab -> gpart[layer][b][256] slice.
// If do_agg: redundant LDS CSR compaction; q==0 also writes global CSR + perm/pval;
// then edge-aggregate from slab -> aggout.
__global__ __launch_bounds__(512) void poolagg_kernel(
        const float* __restrict__ score, const uint* __restrict__ hp,
        int* __restrict__ perm_out, float* __restrict__ pval_out,
        float* __restrict__ gpart,           // this layer's [B_G][256] slice
        const int* __restrict__ ipt_in, const int* __restrict__ cnt_in,
        const ushort* __restrict__ src_in,
        int* __restrict__ ipt_out, int* __restrict__ cnt_out,
        ushort* __restrict__ src_out,
        uint* __restrict__ aggout,
        int n, int k, int do_agg) {
    int b = blockIdx.x >> 2, q = blockIdx.x & 3;
    int tid = threadIdx.x;
    __shared__ unsigned long long keys[512];
    __shared__ short invl[512];
    __shared__ int cntL[512], prefL[512], iptL[512];
    __shared__ ushort srcL[EPG];               // 8 KB
    extern __shared__ float slab[];            // [k][36] fp32, scaled pooled features
    // load + sort
    {
        unsigned long long key = 0ull;
        if (tid < n) {
            uint u = __float_as_uint(score[b * n + tid]);
            u = (u & 0x80000000u) ? ~u : (u | 0x80000000u);
            key = ((unsigned long long)u << 32) | (uint)(~tid);
        }
        keys[tid] = key;
        invl[tid] = -1;
    }
    __syncthreads();
    for (int kk2 = 2; kk2 <= 512; kk2 <<= 1) {
        for (int j = kk2 >> 1; j > 0; j >>= 1) {
            int s = tid, sxj = s ^ j;
            if (sxj > s) {
                unsigned long long a = keys[s], c = keys[sxj];
                bool doSwap = ((s & kk2) == 0) ? (a < c) : (a > c);
                if (doSwap) { keys[s] = c; keys[sxj] = a; }
            }
            __syncthreads();
        }
    }
    if (tid < k) {
        int node = (int)(~(uint)keys[tid]);
        invl[node] = (short)tid;
    }
    __syncthreads();
    // stage slab: scaled pooled rows, quarter channels
    for (int t = tid; t < k * 8; t += 512) {
        int nd = t >> 3, c4 = t & 7;
        unsigned long long key = keys[nd];
        int node = (int)(~(uint)key);
        float v = keyval(key);
        uint4 u = *(const uint4*)&hp[(size_t)(b * n + node) * CCH + q * 32 + c4 * 4];
        *(float4*)&slab[nd * 36 + c4 * 4] =
            make_float4(unpk(u.x) * v, unpk(u.y) * v, unpk(u.z) * v, unpk(u.w) * v);
    }
    __syncthreads();
    // readout from slab: 32 channels x 16 workers
    {
        int ch = tid >> 4, w = tid & 15;
        float mx = -1e30f, sm = 0.f;
        for (int r2 = w; r2 < k; r2 += 16) {
            float v = slab[r2 * 36 + ch];
            mx = fmaxf(mx, v); sm += v;
        }
#pragma unroll
        for (int off = 1; off < 16; off <<= 1) {
            mx = fmaxf(mx, __shfl_xor(mx, off));
            sm += __shfl_xor(sm, off);
        }
        if (w == 0) {
            gpart[b * 256 + q * 32 + ch] = mx;
            gpart[b * 256 + 128 + q * 32 + ch] = sm / (float)k;
        }
    }
    if (!do_agg) return;
    // redundant LDS CSR compaction: new dst tid -> filtered+renamed sources
    int node = -1, beg = 0, c = 0, nk = 0;
    if (tid < k) {
        node = (int)(~(uint)keys[tid]);
        beg = ipt_in[b * n + node];
        c = cnt_in[b * n + node];
        for (int t = 0; t < c; t++)
            if (invl[src_in[beg + t]] >= 0) nk++;
    }
    cntL[tid] = (tid < k) ? nk : 0;
    __syncthreads();
    prefL[tid] = cntL[tid];
    __syncthreads();
    for (int off = 1; off < 512; off <<= 1) {
        int v = (tid >= off) ? prefL[tid - off] : 0;
        __syncthreads();
        prefL[tid] += v;
        __syncthreads();
    }
    int excl = tid ? prefL[tid - 1] : 0;
    iptL[tid] = excl;
    if (tid < k) {
        int pos = excl;
        for (int t = 0; t < c; t++) {
            int ns = invl[src_in[beg + t]];
            if (ns >= 0) srcL[pos++] = (ushort)ns;
        }
    }
    __syncthreads();
    if (q == 0) {
        int tot = prefL[511];
        if (tid < k) {
            ipt_out[b * k + tid] = b * EPG + excl;
            cnt_out[b * k + tid] = nk;
            perm_out[b * k + tid] = b * n + node;
            pval_out[b * k + tid] = keyval(keys[tid]);
        }
        for (int i = tid; i < tot; i += 512) src_out[b * EPG + i] = srcL[i];
    }
    // edge-aggregate next layer from slab (LDS CSR)
    {
        int wave = tid >> 6, lane = tid & 63;
        int gl = lane >> 3, sub = lane & 7;
        int ngroups = (k + 7) >> 3;
        for (int g = wave; g < ngroups; g += 8) {
            int d = g * 8 + gl;
            bool act = d < k;
            int bg = 0, cc = 0;
            if (act) { bg = iptL[d]; cc = cntL[d]; }
            float4 acc = make_float4(0.f, 0.f, 0.f, 0.f);
            for (int j = 0; j < cc; j++) {
                int id = (int)srcL[bg + j];
                const float4 v = *(const float4*)&slab[id * 36 + sub * 4];
                acc.x += v.x; acc.y += v.y; acc.z += v.z; acc.w += v.w;
            }
            if (act) {
                uint4 o;
                o.x = pksplit(acc.x); o.y = pksplit(acc.y);
                o.z = pksplit(acc.z); o.w = pksplit(acc.w);
                *(uint4*)&aggout[(size_t)(b * k + d) * CCH + q * 32 + sub * 4] = o;
            }
        }
    }
}

// ---------------- final MLP + log_softmax ----------------
__global__ __launch_bounds__(128) void mlp_kernel(const float* __restrict__ gpart,
        const float* __restrict__ W1, const float* __restrict__ b1,
        const float* __restrict__ W2, const float* __restrict__ b2,
        const float* __restrict__ W3, const float* __restrict__ b3,
        float* __restrict__ out) {
    int b = blockIdx.x, t = threadIdx.x;
    __shared__ float gs[256], h1[128], h2[64], lg[10];
    const float* g0 = gpart + ((size_t)0 * B_G + b) * 256;
    const float* g1 = gpart + ((size_t)1 * B_G + b) * 256;
    const float* g2 = gpart + ((size_t)2 * B_G + b) * 256;
    gs[t] = g0[t] + g1[t] + g2[t];
    gs[128 + t] = g0[128 + t] + g1[128 + t] + g2[128 + t];
    __syncthreads();
    {
        float a = b1[t];
        for (int c = 0; c < 256; c++) a += gs[c] * W1[c * 128 + t];
        h1[t] = fmaxf(a, 0.f);
    }
    __syncthreads();
    if (t < 64) {
        float a = b2[t];
        for (int c = 0; c < 128; c++) a += h1[c] * W2[c * 64 + t];
        h2[t] = fmaxf(a, 0.f);
    }
    __syncthreads();
    if (t < 10) {
        float a = b3[t];
        for (int c = 0; c < 64; c++) a += h2[c] * W3[c * 10 + t];
        lg[t] = a;
    }
    __syncthreads();
    if (t < 10) {
        float m = lg[0];
        for (int i = 1; i < 10; i++) m = fmaxf(m, lg[i]);
        float s = 0.f;
        for (int i = 0; i < 10; i++) s += expf(lg[i] - m);
        out[b * 10 + t] = lg[t] - m - logf(s);
    }
}

// ---------------- host ----------------
extern "C" void kernel_launch(void* const* d_in, const int* in_sizes, int n_in,
                              void* d_out, int out_size, void* d_ws, size_t ws_size,
                              hipStream_t stream) {
    (void)in_sizes; (void)n_in; (void)out_size; (void)ws_size;
    const float* x0 = (const float*)d_in[0];
    const int* es = (const int*)d_in[1];
    const int* ed = (const int*)d_in[2];
    const float* Wroot[3] = {(const float*)d_in[3], (const float*)d_in[7], (const float*)d_in[11]};
    const float* Wrel[3]  = {(const float*)d_in[4], (const float*)d_in[8], (const float*)d_in[12]};
    const float* brel[3]  = {(const float*)d_in[5], (const float*)d_in[9], (const float*)d_in[13]};
    const float* pvec[3]  = {(const float*)d_in[6], (const float*)d_in[10], (const float*)d_in[14]};
    const float* W1 = (const float*)d_in[15];
    const float* b1 = (const float*)d_in[16];
    const float* W2 = (const float*)d_in[17];
    const float* b2 = (const float*)d_in[18];
    const float* W3 = (const float*)d_in[19];
    const float* b3 = (const float*)d_in[20];

    size_t off = 0;
    char* base = (char*)d_ws;
    auto alloc = [&](size_t bytes) -> void* {
        void* p = base + off;
        off += (bytes + 255) & ~(size_t)255;
        return p;
    };
    const size_t FEATP = (size_t)(B_G * N0) * CCH * 4;   // packed uint plane
    uint* P0 = (uint*)alloc(FEATP);          // h planes / agg plane rotate
    uint* P1 = (uint*)alloc(FEATP);
    uint* P2 = (uint*)alloc(FEATP);
    ushort* Bph = (ushort*)alloc((size_t)3 * 32768 * 2);
    ushort* Bpl = (ushort*)alloc((size_t)3 * 32768 * 2);
    int* iptA = (int*)alloc((size_t)(B_G * N0) * 4);
    int* cntA = (int*)alloc((size_t)(B_G * N0) * 4);
    ushort* srcA = (ushort*)alloc((size_t)E_TOTAL * 2);
    int* iptB = (int*)alloc((size_t)(B_G * N0) * 4);
    int* cntB = (int*)alloc((size_t)(B_G * N0) * 4);
    ushort* srcB = (ushort*)alloc((size_t)E_TOTAL * 2);
    int* permA = (int*)alloc((size_t)(B_G * K1) * 4);
    float* pvalA = (float*)alloc((size_t)(B_G * K1) * 4);
    int* permB = (int*)alloc((size_t)(B_G * K1) * 4);
    float* pvalB = (float*)alloc((size_t)(B_G * K1) * 4);
    float* score = (float*)alloc((size_t)(B_G * N0) * 4);
    float* gpart = (float*)alloc((size_t)3 * B_G * 256 * 4);

    // setup: CSR0 + weight pack
    setup_kernel<<<B_G + (3 * 32768 + 511) / 512, 512, 0, stream>>>(
        Wrel[0], Wroot[0], Wrel[1], Wroot[1], Wrel[2], Wroot[2],
        Bph, Bpl, es, ed, iptA, cntA, srcA);

    // L0: agg from fp32 x0 -> P1 ; tf (root = fp32 x0) -> h0 in P0, score
    aggregate0<<<4 * B_G, 1024, (size_t)N0 * 36 * 4, stream>>>(
        x0, iptA, cntA, srcA, P1);
    transform_mfma<<<B_G * N0 / 128, 512, 0, stream>>>(
        P1, nullptr, x0, nullptr, nullptr, Bph, Bpl, brel[0], pvec[0], P0, score);
    // pool L0 + agg L1 -> P1 ; CSR A->B ; perm/pval A
    poolagg_kernel<<<4 * B_G, 512, (size_t)K1 * 36 * 4, stream>>>(
        score, P0, permA, pvalA, gpart + (size_t)0 * B_G * 256,
        iptA, cntA, srcA, iptB, cntB, srcB, P1, N0, K1, 1);

    // L1: tf (A=P1, root=P0 via permA) -> h1 in P2, score
    transform_mfma<<<B_G * K1 / 128, 512, 0, stream>>>(
        P1, P0, nullptr, permA, pvalA, Bph + 32768, Bpl + 32768,
        brel[1], pvec[1], P2, score);
    // pool L1 + agg L2 -> P1 ; CSR B->A ; perm/pval B
    poolagg_kernel<<<4 * B_G, 512, (size_t)K2 * 36 * 4, stream>>>(
        score, P2, permB, pvalB, gpart + (size_t)1 * B_G * 256,
        iptB, cntB, srcB, iptA, cntA, srcA, P1, K1, K2, 1);

    // L2: tf (A=P1, root=P2 via permB) -> h2 in P0, score
    transform_mfma<<<B_G * K2 / 128, 512, 0, stream>>>(
        P1, P2, nullptr, permB, pvalB, Bph + 2 * 32768, Bpl + 2 * 32768,
        brel[2], pvec[2], P0, score);
    // final pool: readout only
    poolagg_kernel<<<4 * B_G, 512, (size_t)K3 * 36 * 4, stream>>>(
        score, P0, nullptr, nullptr, gpart + (size_t)2 * B_G * 256,
        iptA, cntA, srcA, nullptr, nullptr, nullptr, nullptr, K2, K3, 0);

    mlp_kernel<<<B_G, 128, 0, stream>>>(gpart, W1, b1, W2, b2, W3, b3, (float*)d_out);
}